// Round 4
// baseline (309.713 us; speedup 1.0000x reference)
//
#include <hip/hip_runtime.h>
#include <hip/hip_bf16.h>

// EuclideanAttention: B=2, S=2048, D=1024, H=16, Hd=64. fp32 in/out.
#define NUM_B   2
#define SEQ     2048
#define DMODEL  1024
#define NH      16
#define HD      64
#define M_TOT   (NUM_B * SEQ)      // 4096
#define N_QKV   (3 * DMODEL)       // 3072
#define LOG2E   1.4426950408889634f
#define EXP_BIAS 96.0f             // round-7 verified softmax bias

typedef __attribute__((ext_vector_type(8))) short short8v;
typedef __attribute__((ext_vector_type(4))) float float4v;
typedef unsigned short ushort_t;

__device__ __forceinline__ ushort_t f2bf(float x) {
    unsigned u = __builtin_bit_cast(unsigned, x);
    u = u + 0x7FFFu + ((u >> 16) & 1u);
    return (ushort_t)(u >> 16);
}
__device__ __forceinline__ float bf2f(ushort_t h) {
    unsigned u = ((unsigned)h) << 16;
    return __builtin_bit_cast(float, u);
}
__device__ __forceinline__ void gll16(const void* g, void* l) {
    __builtin_amdgcn_global_load_lds(
        (const __attribute__((address_space(1))) unsigned int*)g,
        (__attribute__((address_space(3))) unsigned int*)l, 16, 0, 0);
}
__device__ __forceinline__ int sw4(int r) { return (r & 3) ^ ((r >> 2) & 3); }

// ---------------------------------------------------------------------------
// Prep: W_qkv -> WqT hi/lo; W_o -> WoT; (PRE) X -> Xhi/Xlo bf16 split.
// ---------------------------------------------------------------------------
__global__ __launch_bounds__(256) void prep_kernel(
    const float* __restrict__ Wq, const float* __restrict__ Wo,
    const float* __restrict__ Xf,
    ushort_t* __restrict__ WqT_hi, ushort_t* __restrict__ WqT_lo,
    ushort_t* __restrict__ WoT,
    ushort_t* __restrict__ Xhi, ushort_t* __restrict__ Xlo)
{
    const int bid = blockIdx.x;
    const int t = threadIdx.x;

    if (bid >= 1024) {             // X split: 1024 blocks x 4096 elements
        size_t base = (size_t)(bid - 1024) * 4096 + t * 16;
        float xs[16];
        *(float4v*)&xs[0]  = *(const float4v*)(Xf + base);
        *(float4v*)&xs[4]  = *(const float4v*)(Xf + base + 4);
        *(float4v*)&xs[8]  = *(const float4v*)(Xf + base + 8);
        *(float4v*)&xs[12] = *(const float4v*)(Xf + base + 12);
        short8v h0, h1, l0, l1;
        #pragma unroll
        for (int e = 0; e < 8; e++) {
            ushort_t a = f2bf(xs[e]), b = f2bf(xs[8 + e]);
            h0[e] = (short)a; h1[e] = (short)b;
            l0[e] = (short)f2bf(xs[e] - bf2f(a));
            l1[e] = (short)f2bf(xs[8 + e] - bf2f(b));
        }
        *(short8v*)(Xhi + base) = h0; *(short8v*)(Xhi + base + 8) = h1;
        *(short8v*)(Xlo + base) = l0; *(short8v*)(Xlo + base + 8) = l1;
        return;
    }

    __shared__ float Tf[64][65];
    const float* src; ushort_t *dhi, *dlo; int N, k0, n0;
    if (bid < 768) {
        int kt = bid / 48, nt = bid % 48;
        src = Wq; N = N_QKV; dhi = WqT_hi; dlo = WqT_lo;
        k0 = kt * 64; n0 = nt * 64;
    } else {
        int tid = bid - 768;
        int kt = tid >> 4, nt = tid & 15;
        src = Wo; N = DMODEL; dhi = WoT; dlo = nullptr;
        k0 = kt * 64; n0 = nt * 64;
    }
    {
        int r = t >> 2, c0 = (t & 3) * 16;
        const float* srow = src + (size_t)(k0 + r) * N + n0 + c0;
        #pragma unroll
        for (int u = 0; u < 4; u++) {
            float4v f = *(const float4v*)(srow + 4 * u);
            #pragma unroll
            for (int e = 0; e < 4; e++) Tf[r][c0 + 4 * u + e] = f[e];
        }
    }
    __syncthreads();
    {
        int nl = t >> 2, kc = (t & 3) * 16;
        short8v h0, h1, l0, l1;
        #pragma unroll
        for (int e = 0; e < 8; e++) {
            float x0 = Tf[kc + e][nl];
            float x1 = Tf[kc + 8 + e][nl];
            ushort_t a = f2bf(x0), b = f2bf(x1);
            h0[e] = (short)a; h1[e] = (short)b;
            l0[e] = (short)f2bf(x0 - bf2f(a));
            l1[e] = (short)f2bf(x1 - bf2f(b));
        }
        ushort_t* o = dhi + (size_t)(n0 + nl) * 1024 + k0 + kc;
        *(short8v*)o = h0; *(short8v*)(o + 8) = h1;
        if (dlo) {
            ushort_t* o2 = dlo + (size_t)(n0 + nl) * 1024 + k0 + kc;
            *(short8v*)o2 = l0; *(short8v*)(o2 + 8) = l1;
        }
    }
}

// ---------------------------------------------------------------------------
// QKV GEMM, round 14: 256x256 + 2-deep counted-vmcnt prefetch (round 13,
// correct but NULL alone) + 4-PHASE per-K-step interleave (m201 template).
// Round-13 post-mortem: coarse schedule pinned at 8.2K cyc/K-step vs 3.7K
// MFMA floor, MfmaUtil 22% -> the missing piece is the per-phase
// {ds_read -> barrier -> lgkmcnt(0) -> MFMA -> barrier} interleave that
// lets phase p+1 reads overlap phase p MFMA (guide: T2/T5 gate on T3).
// Phase p (p=0..3): A-frags mt=2p,2p+1 (hi+lo) [+ all B frags in p=0,
// register-cached]; 24 MFMA (qk) / 8 (v). sched_barrier(0) after lgkm
// (rule #18: hipcc hoists reg-only MFMA past inline-asm waits).
// ---------------------------------------------------------------------------
__global__ __launch_bounds__(512, 2) void qkv_mfma256_kernel(
    const ushort_t* __restrict__ Xhi, const ushort_t* __restrict__ Xlo,
    const ushort_t* __restrict__ WqT_hi, const ushort_t* __restrict__ WqT_lo,
    const float* __restrict__ bias,
    ushort_t* __restrict__ Qhi, ushort_t* __restrict__ Qlo,
    ushort_t* __restrict__ Khi, ushort_t* __restrict__ Klo,
    ushort_t* __restrict__ Vout,
    float* __restrict__ Qsq, float* __restrict__ Ksq)
{
    // [buf][hi/lo][8192 halves]: 2*2*8192*2B = 64KB each for A and B.
    __shared__ ushort_t AS [2 * 2 * 8192];
    __shared__ ushort_t BSh[2 * 2 * 8192];
    const int SLAB = 8192;          // halves per hi or lo slab
    const int BUFS = 2 * SLAB;      // halves per buffer (hi+lo)

    const int t    = threadIdx.x;          // 0..511
    const int w    = t >> 6;               // 8 waves
    const int quad = (t >> 4) & 3, ln = t & 15;
    const int wr = w >> 2, wc = w & 3;     // 2 (M) x 4 (N group)
    const int bx = blockIdx.x, by = blockIdx.y;
    const int p  = bx >> 2, bq = bx & 3;   // part 0/1/2, part-block 0..3
    const int m0 = by * 256;
    const bool qk = (p != 2);
    const int h  = 4 * bq + wc;            // this wave's head
    const int g  = p + 3 * h;              // this wave's 64-col group

    // ---- staging pointers: per-pass i, chunk index c = 512*i + t ----
    const ushort_t* gA[2]; const ushort_t* gB[2]; int lOff[2];
    #pragma unroll
    for (int i = 0; i < 2; i++) {
        int c = 512 * i + t;
        int r = c >> 2, kb = c & 3;        // LDS row 0..255, 16B chunk 0..3
        gA[i] = Xhi + (size_t)(m0 + r) * 1024 + 8 * (kb ^ sw4(r));
        int hj = 4 * bq + (r >> 6);        // head of this LDS n-row
        int ng = 192 * hj + 64 * p + (r & 63);
        gB[i] = WqT_hi + (size_t)ng * 1024 + 8 * (kb ^ sw4(r));
        lOff[i] = (512 * i + 64 * w) * 8;  // wave-uniform LDS base (halves)
    }
    const size_t xlo_off = (size_t)(Xlo - Xhi);
    const size_t wlo_off = (size_t)(WqT_lo - WqT_hi);

    // ---- fragment read offsets (within a hi/lo slab) ----
    int aoff[8], boff[4];
    #pragma unroll
    for (int mt = 0; mt < 8; mt++) {
        int m_l = 128 * wr + 16 * mt + ln;
        aoff[mt] = m_l * 32 + ((quad ^ sw4(m_l)) << 3);
    }
    #pragma unroll
    for (int nt = 0; nt < 4; nt++) {
        int n_l = 64 * wc + 16 * nt + ln;
        boff[nt] = n_l * 32 + ((quad ^ sw4(n_l)) << 3);
    }

    float4v acc[8][4];
    #pragma unroll
    for (int i = 0; i < 8; i++)
        #pragma unroll
        for (int j = 0; j < 4; j++) acc[i][j] = (float4v){0.f, 0.f, 0.f, 0.f};

    auto stage = [&](int ks, int buf) {
        const int kk = 32 * ks;
        ushort_t* Ab = &AS [buf * BUFS];
        ushort_t* Bb = &BSh[buf * BUFS];
        #pragma unroll
        for (int i = 0; i < 2; i++) {
            gll16(gA[i] + kk, Ab + lOff[i]);
            gll16(gB[i] + kk, Bb + lOff[i]);
        }
        if (qk) {
            #pragma unroll
            for (int i = 0; i < 2; i++) {
                gll16(gA[i] + kk + xlo_off, Ab + SLAB + lOff[i]);
                gll16(gB[i] + kk + wlo_off, Bb + SLAB + lOff[i]);
            }
        }
    };

    const int NKS = DMODEL / 32;   // 32 k-steps
    stage(0, 0);                   // 8 (qk) / 4 (v) vmem ops
    stage(1, 1);                   // + 8 / 4 more

    for (int ks = 0; ks < NKS; ks++) {
        const int buf = ks & 1;
        // Counted wait: retire stage(ks)'s loads; keep stage(ks+1) in flight.
        if (ks + 1 < NKS) {
            if (qk) asm volatile("s_waitcnt vmcnt(8)" ::: "memory");
            else    asm volatile("s_waitcnt vmcnt(4)" ::: "memory");
        } else {
            asm volatile("s_waitcnt vmcnt(0)" ::: "memory");
        }
        __builtin_amdgcn_s_barrier();          // B1: buf ready for all waves
        asm volatile("" ::: "memory");

        const ushort_t* Ab = &AS [buf * BUFS];
        const ushort_t* Bb = &BSh[buf * BUFS];

        short8v bh4[4], bl4[4];
        #pragma unroll
        for (int ph = 0; ph < 4; ph++) {
            // --- ds-read cluster for this phase ---
            if (ph == 0) {
                #pragma unroll
                for (int nt = 0; nt < 4; nt++) {
                    bh4[nt] = *(const short8v*)(Bb + boff[nt]);
                    if (qk) bl4[nt] = *(const short8v*)(Bb + SLAB + boff[nt]);
                }
            }
            short8v a_h[2], a_l[2];
            #pragma unroll
            for (int j = 0; j < 2; j++) {
                int mt = 2 * ph + j;
                a_h[j] = *(const short8v*)(Ab + aoff[mt]);
                if (qk) a_l[j] = *(const short8v*)(Ab + SLAB + aoff[mt]);
            }
            __builtin_amdgcn_s_barrier();      // phase gate: reads issued
            asm volatile("s_waitcnt lgkmcnt(0)" ::: "memory");
            __builtin_amdgcn_sched_barrier(0); // rule #18: pin MFMA after wait
            __builtin_amdgcn_s_setprio(1);
            #pragma unroll
            for (int j = 0; j < 2; j++) {
                int mt = 2 * ph + j;
                if (qk) {
                    #pragma unroll
                    for (int nt = 0; nt < 4; nt++) {
                        acc[mt][nt] = __builtin_amdgcn_mfma_f32_16x16x32_bf16(a_h[j], bh4[nt], acc[mt][nt], 0, 0, 0);
                        acc[mt][nt] = __builtin_amdgcn_mfma_f32_16x16x32_bf16(a_h[j], bl4[nt], acc[mt][nt], 0, 0, 0);
                        acc[mt][nt] = __builtin_amdgcn_mfma_f32_16x16x32_bf16(a_l[j], bh4[nt], acc[mt][nt], 0, 0, 0);
                    }
                } else {
                    #pragma unroll
                    for (int nt = 0; nt < 4; nt++)
                        acc[mt][nt] = __builtin_amdgcn_mfma_f32_16x16x32_bf16(a_h[j], bh4[nt], acc[mt][nt], 0, 0, 0);
                }
            }
            __builtin_amdgcn_s_setprio(0);
            __builtin_amdgcn_sched_barrier(0);
            asm volatile("" ::: "memory");
            __builtin_amdgcn_s_barrier();      // phase done
        }
        asm volatile("" ::: "memory");
        if (ks + 2 < NKS) stage(ks + 2, buf);  // re-stage into buf; no wait
    }

    // ---- epilogue: wave owns head h, part p, rows m0+128*wr .. +127 ----
    float bvv[4];
    #pragma unroll
    for (int nt = 0; nt < 4; nt++) bvv[nt] = bias[64 * g + 16 * nt + ln];

    #pragma unroll
    for (int mt = 0; mt < 8; mt++) {
        #pragma unroll
        for (int r = 0; r < 4; r++) {
            int m = m0 + 128 * wr + 16 * mt + 4 * quad + r;
            int bb = m >> 11, s = m & (SEQ - 1);
            size_t hsrow = (size_t)(bb * NH + h) * SEQ + s;
            size_t rowbase = hsrow * HD;
            float vv[4];
            #pragma unroll
            for (int nt = 0; nt < 4; nt++) vv[nt] = acc[mt][nt][r] + bvv[nt];
            if (p == 0) {
                float sq = 0.f;
                #pragma unroll
                for (int nt = 0; nt < 4; nt++) {
                    float v = vv[nt];
                    sq += v * v;
                    float v2 = v * (2.0f * LOG2E);
                    ushort_t hb = f2bf(v2);
                    Qhi[rowbase + 16 * nt + ln] = hb;
                    Qlo[rowbase + 16 * nt + ln] = f2bf(v2 - bf2f(hb));
                }
                sq += __shfl_xor(sq, 1); sq += __shfl_xor(sq, 2);
                sq += __shfl_xor(sq, 4); sq += __shfl_xor(sq, 8);
                if (ln == 0) Qsq[hsrow] = sq * LOG2E - EXP_BIAS;
            } else if (p == 1) {
                float sq = 0.f;
                #pragma unroll
                for (int nt = 0; nt < 4; nt++) {
                    float v = vv[nt];
                    sq += v * v;
                    ushort_t hb = f2bf(v);
                    Khi[rowbase + 16 * nt + ln] = hb;
                    Klo[rowbase + 16 * nt + ln] = f2bf(v - bf2f(hb));
                }
                sq += __shfl_xor(sq, 1); sq += __shfl_xor(sq, 2);
                sq += __shfl_xor(sq, 4); sq += __shfl_xor(sq, 8);
                if (ln == 0) Ksq[hsrow] = sq * LOG2E;
            } else {
                #pragma unroll
                for (int nt = 0; nt < 4; nt++)
                    Vout[((size_t)(bb * NH + h) * 64 + 16 * nt + ln) * SEQ + s] = f2bf(vv[nt]);
            }
        }
    }
}

// ---------------------------------------------------------------------------
// QKV MFMA GEMM 128^2 (round-8 verified) — kept ONLY as !PRE fallback.
// ---------------------------------------------------------------------------
template<bool PRE>
__global__ __launch_bounds__(256) void qkv_mfma_kernel(
    const float* __restrict__ X,
    const ushort_t* __restrict__ Xhi, const ushort_t* __restrict__ Xlo,
    const ushort_t* __restrict__ WqT_hi, const ushort_t* __restrict__ WqT_lo,
    const float* __restrict__ bias,
    ushort_t* __restrict__ Qhi, ushort_t* __restrict__ Qlo,
    ushort_t* __restrict__ Khi, ushort_t* __restrict__ Klo,
    ushort_t* __restrict__ Vout,
    float* __restrict__ Qsq, float* __restrict__ Ksq)
{
    __shared__ ushort_t AS2[2 * 128 * 32];
    __shared__ ushort_t BS [2 * 128 * 32];
    const int LO = 128 * 32;
    const int t = threadIdx.x;
    const int w = t >> 6, lane = t & 63;
    const int quad = (t >> 4) & 3, ln = t & 15;
    const int wr = w >> 1, wc = w & 1;
    const int m0 = blockIdx.y * 128, n0 = blockIdx.x * 128;
    const int g = blockIdx.x * 2 + wc;
    const int h = g / 3, part = g % 3;

    const ushort_t* gA[2]; ushort_t* lA[2];
    const float* aptr = nullptr;
    ushort_t *ast_hi0, *ast_hi1, *ast_lo0, *ast_lo1;
    size_t xlo_off = 0;
    if constexpr (PRE) {
        #pragma unroll
        for (int i = 0; i < 2; i++) {
            int c = 256 * i + 64 * w + lane;
            int r = c >> 2, kbp = c & 3;
            gA[i] = Xhi + (size_t)(m0 + r) * 1024 + 8 * (kbp ^ sw4(r));
            lA[i] = &AS2[(256 * i + 64 * w) * 8];
        }
        xlo_off = (size_t)(Xlo - Xhi);
    } else {
        const int arow = t >> 1, akh = t & 1;
        aptr = X + (size_t)(m0 + arow) * DMODEL + 16 * akh;
        const int asw = sw4(arow);
        ast_hi0 = &AS2[arow * 32 + (((2 * akh) ^ asw) << 3)];
        ast_hi1 = &AS2[arow * 32 + (((2 * akh + 1) ^ asw) << 3)];
        ast_lo0 = &AS2[LO + arow * 32 + (((2 * akh) ^ asw) << 3)];
        ast_lo1 = &AS2[LO + arow * 32 + (((2 * akh + 1) ^ asw) << 3)];
    }

    const ushort_t* gB[2]; ushort_t* lB[2];
    #pragma unroll
    for (int i = 0; i < 2; i++) {
        int c = 256 * i + 64 * w + lane;
        int n = c >> 2, kbp = c & 3;
        gB[i] = WqT_hi + (size_t)(n0 + n) * 1024 + 8 * (kbp ^ sw4(n));
        lB[i] = &BS[(256 * i + 64 * w) * 8];
    }
    const size_t lo_goff = (size_t)(WqT_lo - WqT_hi);

    int aoff[4], boff[4];
    #pragma unroll
    for (int i = 0; i < 4; i++) {
        int m_l = 64 * wr + 16 * i + ln;
        aoff[i] = m_l * 32 + ((quad ^ sw4(m_l)) << 3);
        int n_l = 64 * wc + 16 * i + ln;
        boff[i] = n_l * 32 + ((quad ^ sw4(n_l)) << 3);
    }

    float4v acc[4][4];
    #pragma unroll
    for (int i = 0; i < 4; i++)
        #pragma unroll
        for (int j = 0; j < 4; j++) acc[i][j] = (float4v){0.f, 0.f, 0.f, 0.f};

    for (int k0 = 0; k0 < DMODEL; k0 += 32) {
        __syncthreads();
        #pragma unroll
        for (int i = 0; i < 2; i++) {
            gll16(gB[i] + k0, lB[i]);
            gll16(gB[i] + k0 + lo_goff, lB[i] + LO);
        }
        if constexpr (PRE) {
            #pragma unroll
            for (int i = 0; i < 2; i++) {
                gll16(gA[i] + k0, lA[i]);
                gll16(gA[i] + k0 + xlo_off, lA[i] + LO);
            }
        } else {
            float xs[16];
            *(float4v*)&xs[0]  = *(const float4v*)(aptr + k0);
            *(float4v*)&xs[4]  = *(const float4v*)(aptr + k0 + 4);
            *(float4v*)&xs[8]  = *(const float4v*)(aptr + k0 + 8);
            *(float4v*)&xs[12] = *(const float4v*)(aptr + k0 + 12);
            short8v h0, h1, l0, l1;
            #pragma unroll
            for (int e = 0; e < 8; e++) {
                ushort_t a = f2bf(xs[e]), b = f2bf(xs[8 + e]);
                h0[e] = (short)a; h1[e] = (short)b;
                l0[e] = (short)f2bf(xs[e] - bf2f(a));
                l1[e] = (short)f2bf(xs[8 + e] - bf2f(b));
            }
            *(short8v*)ast_hi0 = h0; *(short8v*)ast_hi1 = h1;
            *(short8v*)ast_lo0 = l0; *(short8v*)ast_lo1 = l1;
        }
        __syncthreads();

        short8v ah[4], al[4], bh[4], bl[4];
        #pragma unroll
        for (int i = 0; i < 4; i++) {
            ah[i] = *(short8v*)&AS2[aoff[i]];
            al[i] = *(short8v*)&AS2[LO + aoff[i]];
            bh[i] = *(short8v*)&BS[boff[i]];
            bl[i] = *(short8v*)&BS[LO + boff[i]];
        }
        if (part != 2) {
            #pragma unroll
            for (int mt = 0; mt < 4; mt++)
                #pragma unroll
                for (int nt = 0; nt < 4; nt++) {
                    acc[mt][nt] = __builtin_amdgcn_mfma_f32_16x16x32_bf16(ah[mt], bh[nt], acc[mt][nt], 0, 0, 0);
                    acc[mt][nt] = __builtin_amdgcn_mfma_f32_16x16x32_bf16(ah[mt], bl[nt], acc[mt][nt], 0, 0, 0);
                    acc[mt][nt] = __builtin_amdgcn_mfma_f32_16x16x32_bf16(al[mt], bh[nt], acc[mt][nt], 0, 0, 0);
                }
        } else {
            #pragma unroll
            for (int mt = 0; mt < 4; mt++)
                #pragma unroll
                for (int nt = 0; nt < 4; nt++)
                    acc[mt][nt] = __builtin_amdgcn_mfma_f32_16x16x32_bf16(ah[mt], bh[nt], acc[mt][nt], 0, 0, 0);
        }
    }

    float bvv[4];
    #pragma unroll
    for (int nt = 0; nt < 4; nt++) bvv[nt] = bias[64 * g + 16 * nt + ln];

    #pragma unroll
    for (int mt = 0; mt < 4; mt++) {
        #pragma unroll
        for (int r = 0; r < 4; r++) {
            int m = m0 + 64 * wr + 16 * mt + 4 * quad + r;
            int bb = m >> 11, s = m & (SEQ - 1);
            size_t hsrow = (size_t)(bb * NH + h) * SEQ + s;
            size_t rowbase = hsrow * HD;
            float vv[4];
            #pragma unroll
            for (int nt = 0; nt < 4; nt++) vv[nt] = acc[mt][nt][r] + bvv[nt];
            if (part == 0) {
                float sq = 0.f;
                #pragma unroll
                for (int nt = 0; nt < 4; nt++) {
                    float v = vv[nt];
                    sq += v * v;
                    float v2 = v * (2.0f * LOG2E);
                    ushort_t hb = f2bf(v2);
                    Qhi[rowbase + 16 * nt + ln] = hb;
                    Qlo[rowbase + 16 * nt + ln] = f2bf(v2 - bf2f(hb));
                }
                sq += __shfl_xor(sq, 1); sq += __shfl_xor(sq, 2);
                sq += __shfl_xor(sq, 4); sq += __shfl_xor(sq, 8);
                if (ln == 0) Qsq[hsrow] = sq * LOG2E - EXP_BIAS;
            } else if (part == 1) {
                float sq = 0.f;
                #pragma unroll
                for (int nt = 0; nt < 4; nt++) {
                    float v = vv[nt];
                    sq += v * v;
                    ushort_t hb = f2bf(v);
                    Khi[rowbase + 16 * nt + ln] = hb;
                    Klo[rowbase + 16 * nt + ln] = f2bf(v - bf2f(hb));
                }
                sq += __shfl_xor(sq, 1); sq += __shfl_xor(sq, 2);
                sq += __shfl_xor(sq, 4); sq += __shfl_xor(sq, 8);
                if (ln == 0) Ksq[hsrow] = sq * LOG2E;
            } else {
                #pragma unroll
                for (int nt = 0; nt < 4; nt++)
                    Vout[rowbase + 16 * nt + ln] = f2bf(vv[nt]);
            }
        }
    }
}

// ---------------------------------------------------------------------------
// MFMA flash attention (round-11: QBLK=64, 4 blk/CU, cvt_pk pack). Unchanged.
// ---------------------------------------------------------------------------
template<bool PRE>
__global__ __launch_bounds__(256, 4) void attn_mfma_kernel(
    const ushort_t* __restrict__ Qhi, const ushort_t* __restrict__ Qlo,
    const ushort_t* __restrict__ Khi, const ushort_t* __restrict__ Klo,
    const ushort_t* __restrict__ Vsrc,
    const float* __restrict__ Qsq, const float* __restrict__ Ksq,
    ushort_t* __restrict__ vals)
{
    __shared__ ushort_t KS[2 * 64 * 64];           // [hi 4096 | lo 4096]
    __shared__ ushort_t VtS [64 * 64];
    __shared__ ushort_t PsS [64 * 72];
    const int LO = 64 * 64;

    const int t    = threadIdx.x;
    const int w    = t >> 6, lane = t & 63;
    const int quad = (t >> 4) & 3, ln = t & 15;
    const int bh   = blockIdx.y;
    const int q0   = blockIdx.x * 64;
    const size_t base  = (size_t)bh * SEQ * HD;
    const size_t baseS = (size_t)bh * SEQ;

    short8v qhi[2], qlo[2];
    float4v qsq4;
    {
        size_t ro = base + (size_t)(q0 + 16 * w + ln) * HD + quad * 8;
        qhi[0] = *(const short8v*)(Qhi + ro);
        qhi[1] = *(const short8v*)(Qhi + ro + 32);
        qlo[0] = *(const short8v*)(Qlo + ro);
        qlo[1] = *(const short8v*)(Qlo + ro + 32);
        qsq4 = *(const float4v*)(Qsq + baseS + q0 + 16 * w + 4 * quad);
    }

    const ushort_t* gK[2]; ushort_t* lK[2];
    #pragma unroll
    for (int i = 0; i < 2; i++) {
        int c = 256 * i + 64 * w + lane;
        int key = c >> 3, dbp = c & 7;
        gK[i] = Khi + base + (size_t)key * HD + 8 * (dbp ^ (key & 7));
        lK[i] = &KS[(256 * i + 64 * w) * 8];
    }
    const size_t kloff = (size_t)(Klo - Khi);

    const ushort_t* gV[2]; ushort_t* lV[2];
    if constexpr (PRE) {
        #pragma unroll
        for (int i = 0; i < 2; i++) {
            int c = 256 * i + 64 * w + lane;
            int d = c >> 3, kc = c & 7;
            gV[i] = Vsrc + ((size_t)bh * 64 + d) * SEQ + 8 * (kc ^ (d & 7));
            lV[i] = &VtS[(256 * i + 64 * w) * 8];
        }
    }

    float4v accO[4];
    float lsum[4];
    #pragma unroll
    for (int nt = 0; nt < 4; nt++) accO[nt] = (float4v){0.f, 0.f, 0.f, 0.f};
    #pragma unroll
    for (int r = 0; r < 4; r++) lsum[r] = 0.f;

    for (int kt = 0; kt < SEQ; kt += 64) {
        __syncthreads();
        #pragma unroll
        for (int i = 0; i < 2; i++) {
            gll16(gK[i] + (size_t)kt * HD, lK[i]);
            gll16(gK[i] + (size_t)kt * HD + kloff, lK[i] + LO);
        }
        if constexpr (PRE) {
            #pragma unroll
            for (int i = 0; i < 2; i++)
                gll16(gV[i] + kt, lV[i]);
        } else {
            #pragma unroll
            for (int i = 0; i < 2; i++) {
                int c = t + 256 * i;
                int key = c >> 3, db = c & 7;
                short8v v8 = *(const short8v*)(Vsrc + base + (size_t)(kt + key) * HD + 8 * db);
                #pragma unroll
                for (int e = 0; e < 8; e++) {
                    int col = key ^ (e << 3);
                    VtS[(8 * db + e) * 64 + col] = (ushort_t)v8[e];
                }
            }
        }
        float ksq_c[4];
        #pragma unroll
        for (int nt = 0; nt < 4; nt++)
            ksq_c[nt] = Ksq[baseS + kt + 16 * nt + ln];
        __syncthreads();

        float4v accS[4];
        #pragma unroll
        for (int nt = 0; nt < 4; nt++) accS[nt] = (float4v){0.f, 0.f, 0.f, 0.f};

        #pragma unroll
        for (int nt = 0; nt < 4; nt++) {
            int keyrow = 16 * nt + ln;
            #pragma unroll
            for (int c = 0; c < 2; c++) {
                int db  = quad + 4 * c;
                int off = keyrow * 64 + ((db ^ (keyrow & 7)) << 3);
                short8v bh_ = *(short8v*)&KS[off];
                short8v bl_ = *(short8v*)&KS[LO + off];
                accS[nt] = __builtin_amdgcn_mfma_f32_16x16x32_bf16(qhi[c], bh_, accS[nt], 0, 0, 0);
                accS[nt] = __builtin_amdgcn_mfma_f32_16x16x32_bf16(qhi[c], bl_, accS[nt], 0, 0, 0);
                accS[nt] = __builtin_amdgcn_mfma_f32_16x16x32_bf16(qlo[c], bh_, accS[nt], 0, 0, 0);
            }
        }

        #pragma unroll
        for (int nt = 0; nt < 4; nt++) {
            float pv[4];
            #pragma unroll
            for (int r = 0; r < 4; r++) {
                float p = exp2f(accS[nt][r] - ksq_c[nt] - qsq4[r]);
                lsum[r] += p;
                pv[r] = p;
            }
            unsigned int pk01, pk23;
            asm("v_cvt_pk_bf16_f32 %0, %1, %2" : "=v"(pk01) : "v"(pv[0]), "v"(pv[1]));
            asm("v_cvt_pk_bf16_f32 %0, %1, %2" : "=v"(pk23) : "v"(pv[2]), "v"(pv[3]));
            ushort_t* pp = &PsS[(16 * w + 4 * quad) * 72 + 16 * nt + ln];
            pp[0]       = (ushort_t)(pk01 & 0xffffu);
            pp[72]      = (ushort_t)(pk01 >> 16);
            pp[144]     = (ushort_t)(pk23 & 0xffffu);
            pp[216]     = (ushort_t)(pk23 >> 16);
        }
        __syncthreads();

        #pragma unroll
        for (int c = 0; c < 2; c++) {
            short8v aP = *(short8v*)&PsS[(16 * w + ln) * 72 + quad * 8 + 32 * c];
            #pragma unroll
            for (int nt = 0; nt < 4; nt++) {
                int drow = 16 * nt + ln;
                int db   = quad + 4 * c;
                int off  = drow * 64 + ((db ^ (drow & 7)) << 3);
                short8v bV = *(short8v*)&VtS[off];
                accO[nt] = __builtin_amdgcn_mfma_f32_16x16x32_bf16(aP, bV, accO[nt], 0, 0, 0);
            }
        }
    }

    const int bb = bh >> 4, h = bh & 15;
    float inv[4];
    #pragma unroll
    for (int r = 0; r < 4; r++) {
        float s = lsum[r];
        s += __shfl_xor(s, 1); s += __shfl_xor(s, 2);
        s += __shfl_xor(s, 4); s += __shfl_xor(s, 8);
        inv[r] = 1.f / s;
    }
    #pragma unroll
    for (int nt = 0; nt < 4; nt++)
        #pragma unroll
        for (int r = 0; r < 4; r++) {
            int row = q0 + 16 * w + 4 * quad + r;
            vals[(size_t)(bb * SEQ + row) * DMODEL + h * 64 + 16 * nt + ln] =
                f2bf(accO[nt][r] * inv[r]);
        }
}

// ---------------------------------------------------------------------------
// Out MFMA GEMM (plain bf16): out = vals @ W_o + b_o, fp32 out.
// ---------------------------------------------------------------------------
__global__ __launch_bounds__(256) void out_mfma_kernel(
    const ushort_t* __restrict__ Ab, const ushort_t* __restrict__ BT,
    const float* __restrict__ bias, float* __restrict__ out)
{
    __shared__ ushort_t AS[128 * 32], BSo[128 * 32];
    const int t = threadIdx.x;
    const int w = t >> 6, lane = t & 63;
    const int quad = (t >> 4) & 3, ln = t & 15;
    const int wr = w >> 1, wc = w & 1;
    const int m0 = blockIdx.y * 128, n0 = blockIdx.x * 128;

    const ushort_t* gA[2]; const ushort_t* gB[2];
    ushort_t *lA[2], *lB[2];
    #pragma unroll
    for (int i = 0; i < 2; i++) {
        int c = 256 * i + 64 * w + lane;
        int r = c >> 2, kbp = c & 3;
        gA[i] = Ab + (size_t)(m0 + r) * 1024 + 8 * (kbp ^ sw4(r));
        gB[i] = BT + (size_t)(n0 + r) * 1024 + 8 * (kbp ^ sw4(r));
        lA[i] = &AS[(256 * i + 64 * w) * 8];
        lB[i] = &BSo[(256 * i + 64 * w) * 8];
    }
    int aoff[4], boff[4];
    #pragma unroll
    for (int i = 0; i < 4; i++) {
        int m_l = 64 * wr + 16 * i + ln;
        aoff[i] = m_l * 32 + ((quad ^ sw4(m_l)) << 3);
        int n_l = 64 * wc + 16 * i + ln;
        boff[i] = n_l * 32 + ((quad ^ sw4(n_l)) << 3);
    }

    float4v acc[4][4];
    #pragma unroll
    for (int i = 0; i < 4; i++)
        #pragma unroll
        for (int j = 0; j < 4; j++) acc[i][j] = (float4v){0.f, 0.f, 0.f, 0.f};

    for (int k0 = 0; k0 < DMODEL; k0 += 32) {
        __syncthreads();
        #pragma unroll
        for (int i = 0; i < 2; i++) {
            gll16(gA[i] + k0, lA[i]);
            gll16(gB[i] + k0, lB[i]);
        }
        __syncthreads();
        short8v a[4], b[4];
        #pragma unroll
        for (int i = 0; i < 4; i++) {
            a[i] = *(short8v*)&AS[aoff[i]];
            b[i] = *(short8v*)&BSo[boff[i]];
        }
        #pragma unroll
        for (int mt = 0; mt < 4; mt++)
            #pragma unroll
            for (int nt = 0; nt < 4; nt++)
                acc[mt][nt] = __builtin_amdgcn_mfma_f32_16x16x32_bf16(a[mt], b[nt], acc[mt][nt], 0, 0, 0);
    }

    #pragma unroll
    for (int nt = 0; nt < 4; nt++) {
        int n = n0 + 64 * wc + 16 * nt + ln;
        float bv = bias[n];
        #pragma unroll
        for (int mt = 0; mt < 4; mt++)
            #pragma unroll
            for (int r = 0; r < 4; r++) {
                int m = m0 + 64 * wr + 16 * mt + 4 * quad + r;
                out[(size_t)m * DMODEL + n] = acc[mt][nt][r] + bv;
            }
    }
}

// ---------------------------------------------------------------------------
// Launch (round-8 layout; PRE if ws fits ~70.5 MiB, else round-7 fallback).
// ---------------------------------------------------------------------------
extern "C" void kernel_launch(void* const* d_in, const int* in_sizes, int n_in,
                              void* d_out, int out_size, void* d_ws, size_t ws_size,
                              hipStream_t stream) {
    const float* x     = (const float*)d_in[0];
    const float* W_qkv = (const float*)d_in[1];
    const float* b_qkv = (const float*)d_in[2];
    const float* W_o   = (const float*)d_in[3];
    const float* b_o   = (const float*)d_in[4];
    float* out = (float*)d_out;

    const size_t WQT = (size_t)N_QKV * DMODEL;
    const size_t WO  = (size_t)DMODEL * DMODEL;
    const size_t QE  = (size_t)NUM_B * NH * SEQ * HD;
    const size_t SQN = (size_t)NUM_B * NH * SEQ;

    const size_t NEED = (2 * WQT + WO + 5 * QE + 2 * QE) * 2 + 2 * SQN * 4;
    const bool pre = (ws_size >= NEED);

    ushort_t* ws     = (ushort_t*)d_ws;
    ushort_t* WqT_hi = ws;
    ushort_t* WqT_lo = WqT_hi + WQT;
    ushort_t* WoT    = WqT_lo + WQT;
    ushort_t* Qhi    = WoT + WO;
    ushort_t* Qlo    = Qhi + QE;
    ushort_t* Khi    = Qlo + QE;
    ushort_t* Klo    = Khi + QE;
    ushort_t* Vx     = Klo + QE;
    float*    Qsq; float* Ksq;
    ushort_t* valsb; ushort_t* Xhi = nullptr; ushort_t* Xlo = nullptr;

    if (pre) {
        Qsq   = (float*)(Vx + QE);
        Ksq   = Qsq + SQN;
        Xhi   = (ushort_t*)(Ksq + SQN);
        Xlo   = Xhi + QE;
        valsb = WqT_hi;
    } else {
        valsb = Vx + QE;
        Qsq   = (float*)(valsb + QE);
        Ksq   = Qsq + SQN;
    }

    prep_kernel<<<pre ? 2048 : 1024, 256, 0, stream>>>(
        W_qkv, W_o, x, WqT_hi, WqT_lo, WoT, Xhi, Xlo);
    if (pre) {
        qkv_mfma256_kernel<<<dim3(12, M_TOT / 256), 512, 0, stream>>>(
            Xhi, Xlo, WqT_hi, WqT_lo, b_qkv, Qhi, Qlo, Khi, Klo, Vx, Qsq, Ksq);
        attn_mfma_kernel<true><<<dim3(SEQ / 64, NUM_B * NH), 256, 0, stream>>>(
            Qhi, Qlo, Khi, Klo, Vx, Qsq, Ksq, valsb);
    } else {
        qkv_mfma_kernel<false><<<dim3(N_QKV / 128, M_TOT / 128), 256, 0, stream>>>(
            x, nullptr, nullptr, WqT_hi, WqT_lo, b_qkv, Qhi, Qlo, Khi, Klo, Vx, Qsq, Ksq);
        attn_mfma_kernel<false><<<dim3(SEQ / 64, NUM_B * NH), 256, 0, stream>>>(
            Qhi, Qlo, Khi, Klo, Vx, Qsq, Ksq, valsb);
    }
    out_mfma_kernel<<<dim3(DMODEL / 128, M_TOT / 128), 256, 0, stream>>>(
        valsb, WoT, b_o, out);
}

// Round 7
// 303.036 us; speedup vs baseline: 1.0220x; 1.0220x over previous
//
#include <hip/hip_runtime.h>
#include <hip/hip_bf16.h>

// EuclideanAttention: B=2, S=2048, D=1024, H=16, Hd=64. fp32 in/out.
#define NUM_B   2
#define SEQ     2048
#define DMODEL  1024
#define NH      16
#define HD      64
#define M_TOT   (NUM_B * SEQ)      // 4096
#define N_QKV   (3 * DMODEL)       // 3072
#define LOG2E   1.4426950408889634f
#define EXP_BIAS 96.0f             // round-7 verified softmax bias

typedef __attribute__((ext_vector_type(8))) short short8v;
typedef __attribute__((ext_vector_type(4))) float float4v;
typedef unsigned short ushort_t;

__device__ __forceinline__ ushort_t f2bf(float x) {
    unsigned u = __builtin_bit_cast(unsigned, x);
    u = u + 0x7FFFu + ((u >> 16) & 1u);
    return (ushort_t)(u >> 16);
}
__device__ __forceinline__ float bf2f(ushort_t h) {
    unsigned u = ((unsigned)h) << 16;
    return __builtin_bit_cast(float, u);
}
__device__ __forceinline__ void gll16(const void* g, void* l) {
    __builtin_amdgcn_global_load_lds(
        (const __attribute__((address_space(1))) unsigned int*)g,
        (__attribute__((address_space(3))) unsigned int*)l, 16, 0, 0);
}
__device__ __forceinline__ int sw4(int r) { return (r & 3) ^ ((r >> 2) & 3); }

// ---------------------------------------------------------------------------
// Prep: W_qkv -> WqT hi/lo; W_o -> WoT; (PRE) X -> Xhi/Xlo bf16 split.
// ---------------------------------------------------------------------------
__global__ __launch_bounds__(256) void prep_kernel(
    const float* __restrict__ Wq, const float* __restrict__ Wo,
    const float* __restrict__ Xf,
    ushort_t* __restrict__ WqT_hi, ushort_t* __restrict__ WqT_lo,
    ushort_t* __restrict__ WoT,
    ushort_t* __restrict__ Xhi, ushort_t* __restrict__ Xlo)
{
    const int bid = blockIdx.x;
    const int t = threadIdx.x;

    if (bid >= 1024) {             // X split: 1024 blocks x 4096 elements
        size_t base = (size_t)(bid - 1024) * 4096 + t * 16;
        float xs[16];
        *(float4v*)&xs[0]  = *(const float4v*)(Xf + base);
        *(float4v*)&xs[4]  = *(const float4v*)(Xf + base + 4);
        *(float4v*)&xs[8]  = *(const float4v*)(Xf + base + 8);
        *(float4v*)&xs[12] = *(const float4v*)(Xf + base + 12);
        short8v h0, h1, l0, l1;
        #pragma unroll
        for (int e = 0; e < 8; e++) {
            ushort_t a = f2bf(xs[e]), b = f2bf(xs[8 + e]);
            h0[e] = (short)a; h1[e] = (short)b;
            l0[e] = (short)f2bf(xs[e] - bf2f(a));
            l1[e] = (short)f2bf(xs[8 + e] - bf2f(b));
        }
        *(short8v*)(Xhi + base) = h0; *(short8v*)(Xhi + base + 8) = h1;
        *(short8v*)(Xlo + base) = l0; *(short8v*)(Xlo + base + 8) = l1;
        return;
    }

    __shared__ float Tf[64][65];
    const float* src; ushort_t *dhi, *dlo; int N, k0, n0;
    if (bid < 768) {
        int kt = bid / 48, nt = bid % 48;
        src = Wq; N = N_QKV; dhi = WqT_hi; dlo = WqT_lo;
        k0 = kt * 64; n0 = nt * 64;
    } else {
        int tid = bid - 768;
        int kt = tid >> 4, nt = tid & 15;
        src = Wo; N = DMODEL; dhi = WoT; dlo = nullptr;
        k0 = kt * 64; n0 = nt * 64;
    }
    {
        int r = t >> 2, c0 = (t & 3) * 16;
        const float* srow = src + (size_t)(k0 + r) * N + n0 + c0;
        #pragma unroll
        for (int u = 0; u < 4; u++) {
            float4v f = *(const float4v*)(srow + 4 * u);
            #pragma unroll
            for (int e = 0; e < 4; e++) Tf[r][c0 + 4 * u + e] = f[e];
        }
    }
    __syncthreads();
    {
        int nl = t >> 2, kc = (t & 3) * 16;
        short8v h0, h1, l0, l1;
        #pragma unroll
        for (int e = 0; e < 8; e++) {
            float x0 = Tf[kc + e][nl];
            float x1 = Tf[kc + 8 + e][nl];
            ushort_t a = f2bf(x0), b = f2bf(x1);
            h0[e] = (short)a; h1[e] = (short)b;
            l0[e] = (short)f2bf(x0 - bf2f(a));
            l1[e] = (short)f2bf(x1 - bf2f(b));
        }
        ushort_t* o = dhi + (size_t)(n0 + nl) * 1024 + k0 + kc;
        *(short8v*)o = h0; *(short8v*)(o + 8) = h1;
        if (dlo) {
            ushort_t* o2 = dlo + (size_t)(n0 + nl) * 1024 + k0 + kc;
            *(short8v*)o2 = l0; *(short8v*)(o2 + 8) = l1;
        }
    }
}

// ---------------------------------------------------------------------------
// QKV GEMM (round-2 verified BEST: 108.6 us): 256x256 tile, 8 waves, BK=32,
// double-buffered LDS, one __syncthreads per K-step with prefetch issued
// before compute. Rounds 13/14 (counted-vmcnt, 4-phase) were null/regression
// -> reverted. Busy-CU rate here is ~735 TF raw, above the m230 2-phase
// reference; remaining loss is the 25% idle CUs (192 blocks / 256 CUs).
// ---------------------------------------------------------------------------
__global__ __launch_bounds__(512, 2) void qkv_mfma256_kernel(
    const ushort_t* __restrict__ Xhi, const ushort_t* __restrict__ Xlo,
    const ushort_t* __restrict__ WqT_hi, const ushort_t* __restrict__ WqT_lo,
    const float* __restrict__ bias,
    ushort_t* __restrict__ Qhi, ushort_t* __restrict__ Qlo,
    ushort_t* __restrict__ Khi, ushort_t* __restrict__ Klo,
    ushort_t* __restrict__ Vout,
    float* __restrict__ Qsq, float* __restrict__ Ksq)
{
    // [buf][hi/lo][8192 halves]: 2*2*8192*2B = 64KB each for A and B.
    __shared__ ushort_t AS [2 * 2 * 8192];
    __shared__ ushort_t BSh[2 * 2 * 8192];
    const int SLAB = 8192;          // halves per hi or lo slab
    const int BUFS = 2 * SLAB;      // halves per buffer (hi+lo)

    const int t    = threadIdx.x;          // 0..511
    const int w    = t >> 6;               // 8 waves
    const int quad = (t >> 4) & 3, ln = t & 15;
    const int wr = w >> 2, wc = w & 3;     // 2 (M) x 4 (N group)
    const int bx = blockIdx.x, by = blockIdx.y;
    const int p  = bx >> 2, bq = bx & 3;   // part 0/1/2, part-block 0..3
    const int m0 = by * 256;
    const bool qk = (p != 2);
    const int h  = 4 * bq + wc;            // this wave's head
    const int g  = p + 3 * h;              // this wave's 64-col group

    // ---- staging pointers: per-pass i, chunk index c = 512*i + t ----
    const ushort_t* gA[2]; const ushort_t* gB[2]; int lOff[2];
    #pragma unroll
    for (int i = 0; i < 2; i++) {
        int c = 512 * i + t;
        int r = c >> 2, kb = c & 3;        // LDS row 0..255, 16B chunk 0..3
        gA[i] = Xhi + (size_t)(m0 + r) * 1024 + 8 * (kb ^ sw4(r));
        int hj = 4 * bq + (r >> 6);        // head of this LDS n-row
        int ng = 192 * hj + 64 * p + (r & 63);
        gB[i] = WqT_hi + (size_t)ng * 1024 + 8 * (kb ^ sw4(r));
        lOff[i] = (512 * i + 64 * w) * 8;  // wave-uniform LDS base (halves)
    }
    const size_t xlo_off = (size_t)(Xlo - Xhi);
    const size_t wlo_off = (size_t)(WqT_lo - WqT_hi);

    // ---- fragment read offsets (within a hi/lo slab) ----
    int aoff[8], boff[4];
    #pragma unroll
    for (int mt = 0; mt < 8; mt++) {
        int m_l = 128 * wr + 16 * mt + ln;
        aoff[mt] = m_l * 32 + ((quad ^ sw4(m_l)) << 3);
    }
    #pragma unroll
    for (int nt = 0; nt < 4; nt++) {
        int n_l = 64 * wc + 16 * nt + ln;
        boff[nt] = n_l * 32 + ((quad ^ sw4(n_l)) << 3);
    }

    float4v acc[8][4];
    #pragma unroll
    for (int i = 0; i < 8; i++)
        #pragma unroll
        for (int j = 0; j < 4; j++) acc[i][j] = (float4v){0.f, 0.f, 0.f, 0.f};

    auto stage = [&](int ks, int buf) {
        const int kk = 32 * ks;
        ushort_t* Ab = &AS [buf * BUFS];
        ushort_t* Bb = &BSh[buf * BUFS];
        #pragma unroll
        for (int i = 0; i < 2; i++) {
            gll16(gA[i] + kk, Ab + lOff[i]);
            gll16(gB[i] + kk, Bb + lOff[i]);
        }
        if (qk) {
            #pragma unroll
            for (int i = 0; i < 2; i++) {
                gll16(gA[i] + kk + xlo_off, Ab + SLAB + lOff[i]);
                gll16(gB[i] + kk + wlo_off, Bb + SLAB + lOff[i]);
            }
        }
    };

    const int NKS = DMODEL / 32;   // 32 k-steps
    stage(0, 0);
    __syncthreads();               // buf0 staged (implicit vmcnt(0) drain)

    for (int ks = 0; ks < NKS; ks++) {
        const int buf = ks & 1;
        if (ks + 1 < NKS) stage(ks + 1, buf ^ 1);   // prefetch overlaps compute

        const ushort_t* Ab = &AS [buf * BUFS];
        const ushort_t* Bb = &BSh[buf * BUFS];

        short8v bh4[4], bl4[4];
        #pragma unroll
        for (int nt = 0; nt < 4; nt++) {
            bh4[nt] = *(const short8v*)(Bb + boff[nt]);
            if (qk) bl4[nt] = *(const short8v*)(Bb + SLAB + boff[nt]);
        }
        #pragma unroll
        for (int mt = 0; mt < 8; mt++) {
            short8v ahm = *(const short8v*)(Ab + aoff[mt]);
            if (qk) {
                short8v alm = *(const short8v*)(Ab + SLAB + aoff[mt]);
                #pragma unroll
                for (int nt = 0; nt < 4; nt++) {
                    acc[mt][nt] = __builtin_amdgcn_mfma_f32_16x16x32_bf16(ahm, bh4[nt], acc[mt][nt], 0, 0, 0);
                    acc[mt][nt] = __builtin_amdgcn_mfma_f32_16x16x32_bf16(ahm, bl4[nt], acc[mt][nt], 0, 0, 0);
                    acc[mt][nt] = __builtin_amdgcn_mfma_f32_16x16x32_bf16(alm, bh4[nt], acc[mt][nt], 0, 0, 0);
                }
            } else {
                #pragma unroll
                for (int nt = 0; nt < 4; nt++)
                    acc[mt][nt] = __builtin_amdgcn_mfma_f32_16x16x32_bf16(ahm, bh4[nt], acc[mt][nt], 0, 0, 0);
            }
        }
        __syncthreads();           // drains prefetch vmcnt + this buf's reads
    }

    // ---- epilogue: wave owns head h, part p, rows m0+128*wr .. +127 ----
    float bvv[4];
    #pragma unroll
    for (int nt = 0; nt < 4; nt++) bvv[nt] = bias[64 * g + 16 * nt + ln];

    #pragma unroll
    for (int mt = 0; mt < 8; mt++) {
        #pragma unroll
        for (int r = 0; r < 4; r++) {
            int m = m0 + 128 * wr + 16 * mt + 4 * quad + r;
            int bb = m >> 11, s = m & (SEQ - 1);
            size_t hsrow = (size_t)(bb * NH + h) * SEQ + s;
            size_t rowbase = hsrow * HD;
            float vv[4];
            #pragma unroll
            for (int nt = 0; nt < 4; nt++) vv[nt] = acc[mt][nt][r] + bvv[nt];
            if (p == 0) {
                float sq = 0.f;
                #pragma unroll
                for (int nt = 0; nt < 4; nt++) {
                    float v = vv[nt];
                    sq += v * v;
                    float v2 = v * (2.0f * LOG2E);
                    ushort_t hb = f2bf(v2);
                    Qhi[rowbase + 16 * nt + ln] = hb;
                    Qlo[rowbase + 16 * nt + ln] = f2bf(v2 - bf2f(hb));
                }
                sq += __shfl_xor(sq, 1); sq += __shfl_xor(sq, 2);
                sq += __shfl_xor(sq, 4); sq += __shfl_xor(sq, 8);
                if (ln == 0) Qsq[hsrow] = sq * LOG2E - EXP_BIAS;
            } else if (p == 1) {
                float sq = 0.f;
                #pragma unroll
                for (int nt = 0; nt < 4; nt++) {
                    float v = vv[nt];
                    sq += v * v;
                    ushort_t hb = f2bf(v);
                    Khi[rowbase + 16 * nt + ln] = hb;
                    Klo[rowbase + 16 * nt + ln] = f2bf(v - bf2f(hb));
                }
                sq += __shfl_xor(sq, 1); sq += __shfl_xor(sq, 2);
                sq += __shfl_xor(sq, 4); sq += __shfl_xor(sq, 8);
                if (ln == 0) Ksq[hsrow] = sq * LOG2E;
            } else {
                #pragma unroll
                for (int nt = 0; nt < 4; nt++)
                    Vout[((size_t)(bb * NH + h) * 64 + 16 * nt + ln) * SEQ + s] = f2bf(vv[nt]);
            }
        }
    }
}

// ---------------------------------------------------------------------------
// QKV MFMA GEMM 128^2 (round-8 verified) — kept ONLY as !PRE fallback.
// ---------------------------------------------------------------------------
template<bool PRE>
__global__ __launch_bounds__(256) void qkv_mfma_kernel(
    const float* __restrict__ X,
    const ushort_t* __restrict__ Xhi, const ushort_t* __restrict__ Xlo,
    const ushort_t* __restrict__ WqT_hi, const ushort_t* __restrict__ WqT_lo,
    const float* __restrict__ bias,
    ushort_t* __restrict__ Qhi, ushort_t* __restrict__ Qlo,
    ushort_t* __restrict__ Khi, ushort_t* __restrict__ Klo,
    ushort_t* __restrict__ Vout,
    float* __restrict__ Qsq, float* __restrict__ Ksq)
{
    __shared__ ushort_t AS2[2 * 128 * 32];
    __shared__ ushort_t BS [2 * 128 * 32];
    const int LO = 128 * 32;
    const int t = threadIdx.x;
    const int w = t >> 6, lane = t & 63;
    const int quad = (t >> 4) & 3, ln = t & 15;
    const int wr = w >> 1, wc = w & 1;
    const int m0 = blockIdx.y * 128, n0 = blockIdx.x * 128;
    const int g = blockIdx.x * 2 + wc;
    const int h = g / 3, part = g % 3;

    const ushort_t* gA[2]; ushort_t* lA[2];
    const float* aptr = nullptr;
    ushort_t *ast_hi0, *ast_hi1, *ast_lo0, *ast_lo1;
    size_t xlo_off = 0;
    if constexpr (PRE) {
        #pragma unroll
        for (int i = 0; i < 2; i++) {
            int c = 256 * i + 64 * w + lane;
            int r = c >> 2, kbp = c & 3;
            gA[i] = Xhi + (size_t)(m0 + r) * 1024 + 8 * (kbp ^ sw4(r));
            lA[i] = &AS2[(256 * i + 64 * w) * 8];
        }
        xlo_off = (size_t)(Xlo - Xhi);
    } else {
        const int arow = t >> 1, akh = t & 1;
        aptr = X + (size_t)(m0 + arow) * DMODEL + 16 * akh;
        const int asw = sw4(arow);
        ast_hi0 = &AS2[arow * 32 + (((2 * akh) ^ asw) << 3)];
        ast_hi1 = &AS2[arow * 32 + (((2 * akh + 1) ^ asw) << 3)];
        ast_lo0 = &AS2[LO + arow * 32 + (((2 * akh) ^ asw) << 3)];
        ast_lo1 = &AS2[LO + arow * 32 + (((2 * akh + 1) ^ asw) << 3)];
    }

    const ushort_t* gB[2]; ushort_t* lB[2];
    #pragma unroll
    for (int i = 0; i < 2; i++) {
        int c = 256 * i + 64 * w + lane;
        int n = c >> 2, kbp = c & 3;
        gB[i] = WqT_hi + (size_t)(n0 + n) * 1024 + 8 * (kbp ^ sw4(n));
        lB[i] = &BS[(256 * i + 64 * w) * 8];
    }
    const size_t lo_goff = (size_t)(WqT_lo - WqT_hi);

    int aoff[4], boff[4];
    #pragma unroll
    for (int i = 0; i < 4; i++) {
        int m_l = 64 * wr + 16 * i + ln;
        aoff[i] = m_l * 32 + ((quad ^ sw4(m_l)) << 3);
        int n_l = 64 * wc + 16 * i + ln;
        boff[i] = n_l * 32 + ((quad ^ sw4(n_l)) << 3);
    }

    float4v acc[4][4];
    #pragma unroll
    for (int i = 0; i < 4; i++)
        #pragma unroll
        for (int j = 0; j < 4; j++) acc[i][j] = (float4v){0.f, 0.f, 0.f, 0.f};

    for (int k0 = 0; k0 < DMODEL; k0 += 32) {
        __syncthreads();
        #pragma unroll
        for (int i = 0; i < 2; i++) {
            gll16(gB[i] + k0, lB[i]);
            gll16(gB[i] + k0 + lo_goff, lB[i] + LO);
        }
        if constexpr (PRE) {
            #pragma unroll
            for (int i = 0; i < 2; i++) {
                gll16(gA[i] + k0, lA[i]);
                gll16(gA[i] + k0 + xlo_off, lA[i] + LO);
            }
        } else {
            float xs[16];
            *(float4v*)&xs[0]  = *(const float4v*)(aptr + k0);
            *(float4v*)&xs[4]  = *(const float4v*)(aptr + k0 + 4);
            *(float4v*)&xs[8]  = *(const float4v*)(aptr + k0 + 8);
            *(float4v*)&xs[12] = *(const float4v*)(aptr + k0 + 12);
            short8v h0, h1, l0, l1;
            #pragma unroll
            for (int e = 0; e < 8; e++) {
                ushort_t a = f2bf(xs[e]), b = f2bf(xs[8 + e]);
                h0[e] = (short)a; h1[e] = (short)b;
                l0[e] = (short)f2bf(xs[e] - bf2f(a));
                l1[e] = (short)f2bf(xs[8 + e] - bf2f(b));
            }
            *(short8v*)ast_hi0 = h0; *(short8v*)ast_hi1 = h1;
            *(short8v*)ast_lo0 = l0; *(short8v*)ast_lo1 = l1;
        }
        __syncthreads();

        short8v ah[4], al[4], bh[4], bl[4];
        #pragma unroll
        for (int i = 0; i < 4; i++) {
            ah[i] = *(short8v*)&AS2[aoff[i]];
            al[i] = *(short8v*)&AS2[LO + aoff[i]];
            bh[i] = *(short8v*)&BS[boff[i]];
            bl[i] = *(short8v*)&BS[LO + boff[i]];
        }
        if (part != 2) {
            #pragma unroll
            for (int mt = 0; mt < 4; mt++)
                #pragma unroll
                for (int nt = 0; nt < 4; nt++) {
                    acc[mt][nt] = __builtin_amdgcn_mfma_f32_16x16x32_bf16(ah[mt], bh[nt], acc[mt][nt], 0, 0, 0);
                    acc[mt][nt] = __builtin_amdgcn_mfma_f32_16x16x32_bf16(ah[mt], bl[nt], acc[mt][nt], 0, 0, 0);
                    acc[mt][nt] = __builtin_amdgcn_mfma_f32_16x16x32_bf16(al[mt], bh[nt], acc[mt][nt], 0, 0, 0);
                }
        } else {
            #pragma unroll
            for (int mt = 0; mt < 4; mt++)
                #pragma unroll
                for (int nt = 0; nt < 4; nt++)
                    acc[mt][nt] = __builtin_amdgcn_mfma_f32_16x16x32_bf16(ah[mt], bh[nt], acc[mt][nt], 0, 0, 0);
        }
    }

    float bvv[4];
    #pragma unroll
    for (int nt = 0; nt < 4; nt++) bvv[nt] = bias[64 * g + 16 * nt + ln];

    #pragma unroll
    for (int mt = 0; mt < 4; mt++) {
        #pragma unroll
        for (int r = 0; r < 4; r++) {
            int m = m0 + 64 * wr + 16 * mt + 4 * quad + r;
            int bb = m >> 11, s = m & (SEQ - 1);
            size_t hsrow = (size_t)(bb * NH + h) * SEQ + s;
            size_t rowbase = hsrow * HD;
            float vv[4];
            #pragma unroll
            for (int nt = 0; nt < 4; nt++) vv[nt] = acc[mt][nt][r] + bvv[nt];
            if (part == 0) {
                float sq = 0.f;
                #pragma unroll
                for (int nt = 0; nt < 4; nt++) {
                    float v = vv[nt];
                    sq += v * v;
                    float v2 = v * (2.0f * LOG2E);
                    ushort_t hb = f2bf(v2);
                    Qhi[rowbase + 16 * nt + ln] = hb;
                    Qlo[rowbase + 16 * nt + ln] = f2bf(v2 - bf2f(hb));
                }
                sq += __shfl_xor(sq, 1); sq += __shfl_xor(sq, 2);
                sq += __shfl_xor(sq, 4); sq += __shfl_xor(sq, 8);
                if (ln == 0) Qsq[hsrow] = sq * LOG2E - EXP_BIAS;
            } else if (part == 1) {
                float sq = 0.f;
                #pragma unroll
                for (int nt = 0; nt < 4; nt++) {
                    float v = vv[nt];
                    sq += v * v;
                    ushort_t hb = f2bf(v);
                    Khi[rowbase + 16 * nt + ln] = hb;
                    Klo[rowbase + 16 * nt + ln] = f2bf(v - bf2f(hb));
                }
                sq += __shfl_xor(sq, 1); sq += __shfl_xor(sq, 2);
                sq += __shfl_xor(sq, 4); sq += __shfl_xor(sq, 8);
                if (ln == 0) Ksq[hsrow] = sq * LOG2E;
            } else {
                #pragma unroll
                for (int nt = 0; nt < 4; nt++)
                    Vout[rowbase + 16 * nt + ln] = f2bf(vv[nt]);
            }
        }
    }
}

// ---------------------------------------------------------------------------
// MFMA flash attention (round-11: QBLK=64, 4 blk/CU, cvt_pk pack). Unchanged.
// ---------------------------------------------------------------------------
template<bool PRE>
__global__ __launch_bounds__(256, 4) void attn_mfma_kernel(
    const ushort_t* __restrict__ Qhi, const ushort_t* __restrict__ Qlo,
    const ushort_t* __restrict__ Khi, const ushort_t* __restrict__ Klo,
    const ushort_t* __restrict__ Vsrc,
    const float* __restrict__ Qsq, const float* __restrict__ Ksq,
    ushort_t* __restrict__ vals)
{
    __shared__ ushort_t KS[2 * 64 * 64];           // [hi 4096 | lo 4096]
    __shared__ ushort_t VtS [64 * 64];
    __shared__ ushort_t PsS [64 * 72];
    const int LO = 64 * 64;

    const int t    = threadIdx.x;
    const int w    = t >> 6, lane = t & 63;
    const int quad = (t >> 4) & 3, ln = t & 15;
    const int bh   = blockIdx.y;
    const int q0   = blockIdx.x * 64;
    const size_t base  = (size_t)bh * SEQ * HD;
    const size_t baseS = (size_t)bh * SEQ;

    short8v qhi[2], qlo[2];
    float4v qsq4;
    {
        size_t ro = base + (size_t)(q0 + 16 * w + ln) * HD + quad * 8;
        qhi[0] = *(const short8v*)(Qhi + ro);
        qhi[1] = *(const short8v*)(Qhi + ro + 32);
        qlo[0] = *(const short8v*)(Qlo + ro);
        qlo[1] = *(const short8v*)(Qlo + ro + 32);
        qsq4 = *(const float4v*)(Qsq + baseS + q0 + 16 * w + 4 * quad);
    }

    const ushort_t* gK[2]; ushort_t* lK[2];
    #pragma unroll
    for (int i = 0; i < 2; i++) {
        int c = 256 * i + 64 * w + lane;
        int key = c >> 3, dbp = c & 7;
        gK[i] = Khi + base + (size_t)key * HD + 8 * (dbp ^ (key & 7));
        lK[i] = &KS[(256 * i + 64 * w) * 8];
    }
    const size_t kloff = (size_t)(Klo - Khi);

    const ushort_t* gV[2]; ushort_t* lV[2];
    if constexpr (PRE) {
        #pragma unroll
        for (int i = 0; i < 2; i++) {
            int c = 256 * i + 64 * w + lane;
            int d = c >> 3, kc = c & 7;
            gV[i] = Vsrc + ((size_t)bh * 64 + d) * SEQ + 8 * (kc ^ (d & 7));
            lV[i] = &VtS[(256 * i + 64 * w) * 8];
        }
    }

    float4v accO[4];
    float lsum[4];
    #pragma unroll
    for (int nt = 0; nt < 4; nt++) accO[nt] = (float4v){0.f, 0.f, 0.f, 0.f};
    #pragma unroll
    for (int r = 0; r < 4; r++) lsum[r] = 0.f;

    for (int kt = 0; kt < SEQ; kt += 64) {
        __syncthreads();
        #pragma unroll
        for (int i = 0; i < 2; i++) {
            gll16(gK[i] + (size_t)kt * HD, lK[i]);
            gll16(gK[i] + (size_t)kt * HD + kloff, lK[i] + LO);
        }
        if constexpr (PRE) {
            #pragma unroll
            for (int i = 0; i < 2; i++)
                gll16(gV[i] + kt, lV[i]);
        } else {
            #pragma unroll
            for (int i = 0; i < 2; i++) {
                int c = t + 256 * i;
                int key = c >> 3, db = c & 7;
                short8v v8 = *(const short8v*)(Vsrc + base + (size_t)(kt + key) * HD + 8 * db);
                #pragma unroll
                for (int e = 0; e < 8; e++) {
                    int col = key ^ (e << 3);
                    VtS[(8 * db + e) * 64 + col] = (ushort_t)v8[e];
                }
            }
        }
        float ksq_c[4];
        #pragma unroll
        for (int nt = 0; nt < 4; nt++)
            ksq_c[nt] = Ksq[baseS + kt + 16 * nt + ln];
        __syncthreads();

        float4v accS[4];
        #pragma unroll
        for (int nt = 0; nt < 4; nt++) accS[nt] = (float4v){0.f, 0.f, 0.f, 0.f};

        #pragma unroll
        for (int nt = 0; nt < 4; nt++) {
            int keyrow = 16 * nt + ln;
            #pragma unroll
            for (int c = 0; c < 2; c++) {
                int db  = quad + 4 * c;
                int off = keyrow * 64 + ((db ^ (keyrow & 7)) << 3);
                short8v bh_ = *(short8v*)&KS[off];
                short8v bl_ = *(short8v*)&KS[LO + off];
                accS[nt] = __builtin_amdgcn_mfma_f32_16x16x32_bf16(qhi[c], bh_, accS[nt], 0, 0, 0);
                accS[nt] = __builtin_amdgcn_mfma_f32_16x16x32_bf16(qhi[c], bl_, accS[nt], 0, 0, 0);
                accS[nt] = __builtin_amdgcn_mfma_f32_16x16x32_bf16(qlo[c], bh_, accS[nt], 0, 0, 0);
            }
        }

        #pragma unroll
        for (int nt = 0; nt < 4; nt++) {
            float pv[4];
            #pragma unroll
            for (int r = 0; r < 4; r++) {
                float p = exp2f(accS[nt][r] - ksq_c[nt] - qsq4[r]);
                lsum[r] += p;
                pv[r] = p;
            }
            unsigned int pk01, pk23;
            asm("v_cvt_pk_bf16_f32 %0, %1, %2" : "=v"(pk01) : "v"(pv[0]), "v"(pv[1]));
            asm("v_cvt_pk_bf16_f32 %0, %1, %2" : "=v"(pk23) : "v"(pv[2]), "v"(pv[3]));
            ushort_t* pp = &PsS[(16 * w + 4 * quad) * 72 + 16 * nt + ln];
            pp[0]       = (ushort_t)(pk01 & 0xffffu);
            pp[72]      = (ushort_t)(pk01 >> 16);
            pp[144]     = (ushort_t)(pk23 & 0xffffu);
            pp[216]     = (ushort_t)(pk23 >> 16);
        }
        __syncthreads();

        #pragma unroll
        for (int c = 0; c < 2; c++) {
            short8v aP = *(short8v*)&PsS[(16 * w + ln) * 72 + quad * 8 + 32 * c];
            #pragma unroll
            for (int nt = 0; nt < 4; nt++) {
                int drow = 16 * nt + ln;
                int db   = quad + 4 * c;
                int off  = drow * 64 + ((db ^ (drow & 7)) << 3);
                short8v bV = *(short8v*)&VtS[off];
                accO[nt] = __builtin_amdgcn_mfma_f32_16x16x32_bf16(aP, bV, accO[nt], 0, 0, 0);
            }
        }
    }

    const int bb = bh >> 4, h = bh & 15;
    float inv[4];
    #pragma unroll
    for (int r = 0; r < 4; r++) {
        float s = lsum[r];
        s += __shfl_xor(s, 1); s += __shfl_xor(s, 2);
        s += __shfl_xor(s, 4); s += __shfl_xor(s, 8);
        inv[r] = 1.f / s;
    }
    #pragma unroll
    for (int nt = 0; nt < 4; nt++)
        #pragma unroll
        for (int r = 0; r < 4; r++) {
            int row = q0 + 16 * w + 4 * quad + r;
            vals[(size_t)(bb * SEQ + row) * DMODEL + h * 64 + 16 * nt + ln] =
                f2bf(accO[nt][r] * inv[r]);
        }
}

// ---------------------------------------------------------------------------
// Out MFMA GEMM, round 16: 128^2 tile, DOUBLE-BUFFERED with the round-2
// proven pattern (prefetch-before-compute + one __syncthreads per K-step).
// Round-5/6 used raw-barrier+counted-vmcnt; containers failed twice, and
// round-3 showed counted-vmcnt is perf-null vs this idiom anyway -> use the
// safe, thrice-benched structure. Old single-buffered version exposed a full
// HBM-latency drain every K-step.
// ---------------------------------------------------------------------------
__global__ __launch_bounds__(256) void out_mfma_kernel(
    const ushort_t* __restrict__ Ab, const ushort_t* __restrict__ BT,
    const float* __restrict__ bias, float* __restrict__ out)
{
    __shared__ ushort_t AS[2 * 128 * 32], BSo[2 * 128 * 32];   // 16KB + 16KB
    const int BUF = 128 * 32;
    const int t = threadIdx.x;
    const int w = t >> 6;
    const int quad = (t >> 4) & 3, ln = t & 15;
    const int wr = (w >> 1), wc = w & 1;
    const int m0 = blockIdx.y * 128, n0 = blockIdx.x * 128;

    const ushort_t* gA[2]; const ushort_t* gB[2]; int lOff[2];
    #pragma unroll
    for (int i = 0; i < 2; i++) {
        int c = 256 * i + t;
        int r = c >> 2, kbp = c & 3;
        gA[i] = Ab + (size_t)(m0 + r) * 1024 + 8 * (kbp ^ sw4(r));
        gB[i] = BT + (size_t)(n0 + r) * 1024 + 8 * (kbp ^ sw4(r));
        lOff[i] = (256 * i + 64 * w) * 8;
    }
    int aoff[4], boff[4];
    #pragma unroll
    for (int i = 0; i < 4; i++) {
        int m_l = 64 * wr + 16 * i + ln;
        aoff[i] = m_l * 32 + ((quad ^ sw4(m_l)) << 3);
        int n_l = 64 * wc + 16 * i + ln;
        boff[i] = n_l * 32 + ((quad ^ sw4(n_l)) << 3);
    }

    float4v acc[4][4];
    #pragma unroll
    for (int i = 0; i < 4; i++)
        #pragma unroll
        for (int j = 0; j < 4; j++) acc[i][j] = (float4v){0.f, 0.f, 0.f, 0.f};

    auto stage = [&](int ks, int buf) {
        const int kk = 32 * ks;
        #pragma unroll
        for (int i = 0; i < 2; i++) {
            gll16(gA[i] + kk, &AS [buf * BUF] + lOff[i]);
            gll16(gB[i] + kk, &BSo[buf * BUF] + lOff[i]);
        }
    };

    const int NKS = DMODEL / 32;   // 32
    stage(0, 0);
    __syncthreads();               // buf0 staged (implicit vmcnt(0) drain)

    for (int ks = 0; ks < NKS; ks++) {
        const int buf = ks & 1;
        if (ks + 1 < NKS) stage(ks + 1, buf ^ 1);   // prefetch overlaps compute

        const ushort_t* Abuf = &AS [buf * BUF];
        const ushort_t* Bbuf = &BSo[buf * BUF];
        short8v a[4], b[4];
        #pragma unroll
        for (int i = 0; i < 4; i++) {
            a[i] = *(const short8v*)(Abuf + aoff[i]);
            b[i] = *(const short8v*)(Bbuf + boff[i]);
        }
        #pragma unroll
        for (int mt = 0; mt < 4; mt++)
            #pragma unroll
            for (int nt = 0; nt < 4; nt++)
                acc[mt][nt] = __builtin_amdgcn_mfma_f32_16x16x32_bf16(a[mt], b[nt], acc[mt][nt], 0, 0, 0);

        __syncthreads();           // drains prefetch vmcnt + this buf's reads
    }

    #pragma unroll
    for (int nt = 0; nt < 4; nt++) {
        int n = n0 + 64 * wc + 16 * nt + ln;
        float bv = bias[n];
        #pragma unroll
        for (int mt = 0; mt < 4; mt++)
            #pragma unroll
            for (int r = 0; r < 4; r++) {
                int m = m0 + 64 * wr + 16 * mt + 4 * quad + r;
                out[(size_t)m * DMODEL + n] = acc[mt][nt][r] + bv;
            }
    }
}

// ---------------------------------------------------------------------------
// Launch (round-8 layout; PRE if ws fits ~70.5 MiB, else round-7 fallback).
// ---------------------------------------------------------------------------
extern "C" void kernel_launch(void* const* d_in, const int* in_sizes, int n_in,
                              void* d_out, int out_size, void* d_ws, size_t ws_size,
                              hipStream_t stream) {
    const float* x     = (const float*)d_in[0];
    const float* W_qkv = (const float*)d_in[1];
    const float* b_qkv = (const float*)d_in[2];
    const float* W_o   = (const float*)d_in[3];
    const float* b_o   = (const float*)d_in[4];
    float* out = (float*)d_out;

    const size_t WQT = (size_t)N_QKV * DMODEL;
    const size_t WO  = (size_t)DMODEL * DMODEL;
    const size_t QE  = (size_t)NUM_B * NH * SEQ * HD;
    const size_t SQN = (size_t)NUM_B * NH * SEQ;

    const size_t NEED = (2 * WQT + WO + 5 * QE + 2 * QE) * 2 + 2 * SQN * 4;
    const bool pre = (ws_size >= NEED);

    ushort_t* ws     = (ushort_t*)d_ws;
    ushort_t* WqT_hi = ws;
    ushort_t* WqT_lo = WqT_hi + WQT;
    ushort_t* WoT    = WqT_lo + WQT;
    ushort_t* Qhi    = WoT + WO;
    ushort_t* Qlo    = Qhi + QE;
    ushort_t* Khi    = Qlo + QE;
    ushort_t* Klo    = Khi + QE;
    ushort_t* Vx     = Klo + QE;
    float*    Qsq; float* Ksq;
    ushort_t* valsb; ushort_t* Xhi = nullptr; ushort_t* Xlo = nullptr;

    if (pre) {
        Qsq   = (float*)(Vx + QE);
        Ksq   = Qsq + SQN;
        Xhi   = (ushort_t*)(Ksq + SQN);
        Xlo   = Xhi + QE;
        valsb = WqT_hi;
    } else {
        valsb = Vx + QE;
        Qsq   = (float*)(valsb + QE);
        Ksq   = Qsq + SQN;
    }

    prep_kernel<<<pre ? 2048 : 1024, 256, 0, stream>>>(
        W_qkv, W_o, x, WqT_hi, WqT_lo, WoT, Xhi, Xlo);
    if (pre) {
        qkv_mfma256_kernel<<<dim3(12, M_TOT / 256), 512, 0, stream>>>(
            Xhi, Xlo, WqT_hi, WqT_lo, b_qkv, Qhi, Qlo, Khi, Klo, Vx, Qsq, Ksq);
        attn_mfma_kernel<true><<<dim3(SEQ / 64, NUM_B * NH), 256, 0, stream>>>(
            Qhi, Qlo, Khi, Klo, Vx, Qsq, Ksq, valsb);
    } else {
        qkv_mfma_kernel<false><<<dim3(N_QKV / 128, M_TOT / 128), 256, 0, stream>>>(
            x, nullptr, nullptr, WqT_hi, WqT_lo, b_qkv, Qhi, Qlo, Khi, Klo, Vx, Qsq, Ksq);
        attn_mfma_kernel<false><<<dim3(SEQ / 64, NUM_B * NH), 256, 0, stream>>>(
            Qhi, Qlo, Khi, Klo, Vx, Qsq, Ksq, valsb);
    }
    out_mfma_kernel<<<dim3(DMODEL / 128, M_TOT / 128), 256, 0, stream>>>(
        valsb, WoT, b_o, out);
}

// Round 8
// 272.610 us; speedup vs baseline: 1.1361x; 1.1116x over previous
//
#include <hip/hip_runtime.h>
#include <hip/hip_bf16.h>

// EuclideanAttention: B=2, S=2048, D=1024, H=16, Hd=64. fp32 in/out.
#define NUM_B   2
#define SEQ     2048
#define DMODEL  1024
#define NH      16
#define HD      64
#define M_TOT   (NUM_B * SEQ)      // 4096
#define N_QKV   (3 * DMODEL)       // 3072
#define LOG2E   1.4426950408889634f
#define EXP_BIAS 96.0f             // round-7 verified softmax bias

typedef __attribute__((ext_vector_type(8))) short short8v;
typedef __attribute__((ext_vector_type(4))) float float4v;
typedef unsigned short ushort_t;

#if __has_builtin(__builtin_amdgcn_exp2f)
#define EXP2F(x) __builtin_amdgcn_exp2f(x)
#else
#define EXP2F(x) exp2f(x)
#endif

__device__ __forceinline__ ushort_t f2bf(float x) {
    unsigned u = __builtin_bit_cast(unsigned, x);
    u = u + 0x7FFFu + ((u >> 16) & 1u);
    return (ushort_t)(u >> 16);
}
__device__ __forceinline__ float bf2f(ushort_t h) {
    unsigned u = ((unsigned)h) << 16;
    return __builtin_bit_cast(float, u);
}
__device__ __forceinline__ void gll16(const void* g, void* l) {
    __builtin_amdgcn_global_load_lds(
        (const __attribute__((address_space(1))) unsigned int*)g,
        (__attribute__((address_space(3))) unsigned int*)l, 16, 0, 0);
}
__device__ __forceinline__ int sw4(int r) { return (r & 3) ^ ((r >> 2) & 3); }

// ---------------------------------------------------------------------------
// Prep: W_qkv -> WqT hi/lo; W_o -> WoT; (PRE) X -> Xhi/Xlo bf16 split.
// ---------------------------------------------------------------------------
__global__ __launch_bounds__(256) void prep_kernel(
    const float* __restrict__ Wq, const float* __restrict__ Wo,
    const float* __restrict__ Xf,
    ushort_t* __restrict__ WqT_hi, ushort_t* __restrict__ WqT_lo,
    ushort_t* __restrict__ WoT,
    ushort_t* __restrict__ Xhi, ushort_t* __restrict__ Xlo)
{
    const int bid = blockIdx.x;
    const int t = threadIdx.x;

    if (bid >= 1024) {             // X split: 1024 blocks x 4096 elements
        size_t base = (size_t)(bid - 1024) * 4096 + t * 16;
        float xs[16];
        *(float4v*)&xs[0]  = *(const float4v*)(Xf + base);
        *(float4v*)&xs[4]  = *(const float4v*)(Xf + base + 4);
        *(float4v*)&xs[8]  = *(const float4v*)(Xf + base + 8);
        *(float4v*)&xs[12] = *(const float4v*)(Xf + base + 12);
        short8v h0, h1, l0, l1;
        #pragma unroll
        for (int e = 0; e < 8; e++) {
            ushort_t a = f2bf(xs[e]), b = f2bf(xs[8 + e]);
            h0[e] = (short)a; h1[e] = (short)b;
            l0[e] = (short)f2bf(xs[e] - bf2f(a));
            l1[e] = (short)f2bf(xs[8 + e] - bf2f(b));
        }
        *(short8v*)(Xhi + base) = h0; *(short8v*)(Xhi + base + 8) = h1;
        *(short8v*)(Xlo + base) = l0; *(short8v*)(Xlo + base + 8) = l1;
        return;
    }

    __shared__ float Tf[64][65];
    const float* src; ushort_t *dhi, *dlo; int N, k0, n0;
    if (bid < 768) {
        int kt = bid / 48, nt = bid % 48;
        src = Wq; N = N_QKV; dhi = WqT_hi; dlo = WqT_lo;
        k0 = kt * 64; n0 = nt * 64;
    } else {
        int tid = bid - 768;
        int kt = tid >> 4, nt = tid & 15;
        src = Wo; N = DMODEL; dhi = WoT; dlo = nullptr;
        k0 = kt * 64; n0 = nt * 64;
    }
    {
        int r = t >> 2, c0 = (t & 3) * 16;
        const float* srow = src + (size_t)(k0 + r) * N + n0 + c0;
        #pragma unroll
        for (int u = 0; u < 4; u++) {
            float4v f = *(const float4v*)(srow + 4 * u);
            #pragma unroll
            for (int e = 0; e < 4; e++) Tf[r][c0 + 4 * u + e] = f[e];
        }
    }
    __syncthreads();
    {
        int nl = t >> 2, kc = (t & 3) * 16;
        short8v h0, h1, l0, l1;
        #pragma unroll
        for (int e = 0; e < 8; e++) {
            float x0 = Tf[kc + e][nl];
            float x1 = Tf[kc + 8 + e][nl];
            ushort_t a = f2bf(x0), b = f2bf(x1);
            h0[e] = (short)a; h1[e] = (short)b;
            l0[e] = (short)f2bf(x0 - bf2f(a));
            l1[e] = (short)f2bf(x1 - bf2f(b));
        }
        ushort_t* o = dhi + (size_t)(n0 + nl) * 1024 + k0 + kc;
        *(short8v*)o = h0; *(short8v*)(o + 8) = h1;
        if (dlo) {
            ushort_t* o2 = dlo + (size_t)(n0 + nl) * 1024 + k0 + kc;
            *(short8v*)o2 = l0; *(short8v*)(o2 + 8) = l1;
        }
    }
}

// ---------------------------------------------------------------------------
// QKV GEMM, round 17 "uniform": block = (head, 256-row tile) -> grid 16x16 =
// 256 blocks = exactly 1/CU (old: 192 blocks, 25% CUs idle, qk-blocks 768
// MFMA/step set makespan). Each block computes its head's Q,K,V (192 cols).
// Wave wc owns 16-col chunk wc of EACH part -> uniform 56 MFMA/wave/step
// (3Q+3K+1V per mt). Per-CU MFMA 768->448 cyc-equiv/step, same total FLOPs.
// B LDS: hi[192 rows]+lo[192 rows], dbuf = 48KB; A unchanged 64KB; tot 112KB.
// qsq/ksq row-sums span 4 waves -> LDS cross-wave reduction in epilogue.
// Schedule = round-2 proven: prefetch-before-compute + 1 __syncthreads/step.
// ---------------------------------------------------------------------------
__global__ __launch_bounds__(512, 2) void qkv_uni_kernel(
    const ushort_t* __restrict__ Xhi, const ushort_t* __restrict__ Xlo,
    const ushort_t* __restrict__ WqT_hi, const ushort_t* __restrict__ WqT_lo,
    const float* __restrict__ bias,
    ushort_t* __restrict__ Qhi, ushort_t* __restrict__ Qlo,
    ushort_t* __restrict__ Khi, ushort_t* __restrict__ Klo,
    ushort_t* __restrict__ Vout,
    float* __restrict__ Qsq, float* __restrict__ Ksq)
{
    const int SLAB_A = 8192, BUFA = 16384;   // halves
    const int SLAB_B = 6144, BUFB = 12288;   // halves
    __shared__ ushort_t AS[2 * BUFA];        // 64 KB
    __shared__ ushort_t BS[2 * BUFB];        // 48 KB

    const int t    = threadIdx.x;            // 0..511
    const int w    = t >> 6;                 // 8 waves
    const int quad = (t >> 4) & 3, ln = t & 15;
    const int wr = w >> 2, wc = w & 3;       // 2 (M-half) x 4 (col-chunk)
    const int h  = blockIdx.x;               // head 0..15
    const int m0 = blockIdx.y * 256;

    // ---- A staging (identical to round-2): 4 gll16/thread/step ----
    const ushort_t* gA[2]; int lOffA[2];
    #pragma unroll
    for (int i = 0; i < 2; i++) {
        int c = 512 * i + t;
        int r = c >> 2, kb = c & 3;
        gA[i] = Xhi + (size_t)(m0 + r) * 1024 + 8 * (kb ^ sw4(r));
        lOffA[i] = (512 * i + 64 * w) * 8;
    }
    const size_t xlo_off = (size_t)(Xlo - Xhi);

    // ---- B staging: 1536 chunks = hi[768] then lo[768]; 3 passes x 512 ----
    // B LDS row j = 48*wc + 16*part + jl  <->  global col 192h + 64*part + d,
    // d = 16*wc + jl. Swizzle keyed on j (pre-swizzled global source).
    const ushort_t* gBp[3]; int lOffB[3];
    #pragma unroll
    for (int i = 0; i < 3; i++) {
        int c = 512 * i + t;
        bool hi = c < 768;
        int cc = hi ? c : c - 768;
        int j = cc >> 2, kb = cc & 3;
        int jj = j >> 4, jl = j & 15;
        int wcq = jj / 3, part = jj % 3;
        int ng = 192 * h + 64 * part + 16 * wcq + jl;
        gBp[i] = (hi ? WqT_hi : WqT_lo) + (size_t)ng * 1024 + 8 * (kb ^ sw4(j));
        int cwb = (512 * i + 64 * w) - (hi ? 0 : 768);   // wave-uniform
        lOffB[i] = (hi ? 0 : SLAB_B) + cwb * 8;
    }

    // ---- fragment read offsets ----
    int aoff[8], boff[3];
    #pragma unroll
    for (int mt = 0; mt < 8; mt++) {
        int m_l = 128 * wr + 16 * mt + ln;
        aoff[mt] = m_l * 32 + ((quad ^ sw4(m_l)) << 3);
    }
    #pragma unroll
    for (int p = 0; p < 3; p++) {
        int j = 48 * wc + 16 * p + ln;
        boff[p] = j * 32 + ((quad ^ sw4(j)) << 3);
    }

    float4v acc[8][3];
    #pragma unroll
    for (int i = 0; i < 8; i++)
        #pragma unroll
        for (int j = 0; j < 3; j++) acc[i][j] = (float4v){0.f, 0.f, 0.f, 0.f};

    auto stage = [&](int ks, int buf) {
        const int kk = 32 * ks;
        ushort_t* Ab = &AS[buf * BUFA];
        ushort_t* Bb = &BS[buf * BUFB];
        #pragma unroll
        for (int i = 0; i < 2; i++) {
            gll16(gA[i] + kk, Ab + lOffA[i]);
            gll16(gA[i] + kk + xlo_off, Ab + SLAB_A + lOffA[i]);
        }
        #pragma unroll
        for (int i = 0; i < 3; i++)
            gll16(gBp[i] + kk, Bb + lOffB[i]);
    };

    const int NKS = DMODEL / 32;   // 32 k-steps
    stage(0, 0);
    __syncthreads();               // buf0 staged (implicit vmcnt(0) drain)

    for (int ks = 0; ks < NKS; ks++) {
        const int buf = ks & 1;
        if (ks + 1 < NKS) stage(ks + 1, buf ^ 1);   // prefetch overlaps compute

        const ushort_t* Ab = &AS[buf * BUFA];
        const ushort_t* Bb = &BS[buf * BUFB];

        short8v bh0 = *(const short8v*)(Bb + boff[0]);
        short8v bh1 = *(const short8v*)(Bb + boff[1]);
        short8v bh2 = *(const short8v*)(Bb + boff[2]);
        short8v bl0 = *(const short8v*)(Bb + SLAB_B + boff[0]);
        short8v bl1 = *(const short8v*)(Bb + SLAB_B + boff[1]);

        #pragma unroll
        for (int mt = 0; mt < 8; mt++) {
            short8v aH = *(const short8v*)(Ab + aoff[mt]);
            short8v aL = *(const short8v*)(Ab + SLAB_A + aoff[mt]);
            acc[mt][0] = __builtin_amdgcn_mfma_f32_16x16x32_bf16(aH, bh0, acc[mt][0], 0, 0, 0);
            acc[mt][0] = __builtin_amdgcn_mfma_f32_16x16x32_bf16(aH, bl0, acc[mt][0], 0, 0, 0);
            acc[mt][0] = __builtin_amdgcn_mfma_f32_16x16x32_bf16(aL, bh0, acc[mt][0], 0, 0, 0);
            acc[mt][1] = __builtin_amdgcn_mfma_f32_16x16x32_bf16(aH, bh1, acc[mt][1], 0, 0, 0);
            acc[mt][1] = __builtin_amdgcn_mfma_f32_16x16x32_bf16(aH, bl1, acc[mt][1], 0, 0, 0);
            acc[mt][1] = __builtin_amdgcn_mfma_f32_16x16x32_bf16(aL, bh1, acc[mt][1], 0, 0, 0);
            acc[mt][2] = __builtin_amdgcn_mfma_f32_16x16x32_bf16(aH, bh2, acc[mt][2], 0, 0, 0);
        }
        __syncthreads();           // drains prefetch vmcnt + this buf's reads
    }

    // ---- epilogue ----
    const float bQ = bias[192 * h + 16 * wc + ln];
    const float bK = bias[192 * h + 64 + 16 * wc + ln];
    const float bV = bias[192 * h + 128 + 16 * wc + ln];
    const int d = 16 * wc + ln;
    float* sqbuf = (float*)AS;     // [2 sel][2 wr][4 wc][128] = 8 KB (reuse)

    #pragma unroll
    for (int mt = 0; mt < 8; mt++) {
        #pragma unroll
        for (int r = 0; r < 4; r++) {
            int m = m0 + 128 * wr + 16 * mt + 4 * quad + r;
            int bb = m >> 11, s = m & (SEQ - 1);
            size_t hsrow = (size_t)(bb * NH + h) * SEQ + s;
            size_t rowbase = hsrow * HD;

            float vQ = acc[mt][0][r] + bQ;
            float vK = acc[mt][1][r] + bK;
            float vV = acc[mt][2][r] + bV;

            float v2 = vQ * (2.0f * LOG2E);
            ushort_t hbq = f2bf(v2);
            Qhi[rowbase + d] = hbq;
            Qlo[rowbase + d] = f2bf(v2 - bf2f(hbq));
            float sqq = vQ * vQ;
            sqq += __shfl_xor(sqq, 1); sqq += __shfl_xor(sqq, 2);
            sqq += __shfl_xor(sqq, 4); sqq += __shfl_xor(sqq, 8);

            ushort_t hbk = f2bf(vK);
            Khi[rowbase + d] = hbk;
            Klo[rowbase + d] = f2bf(vK - bf2f(hbk));
            float sqk = vK * vK;
            sqk += __shfl_xor(sqk, 1); sqk += __shfl_xor(sqk, 2);
            sqk += __shfl_xor(sqk, 4); sqk += __shfl_xor(sqk, 8);

            Vout[((size_t)(bb * NH + h) * 64 + d) * SEQ + s] = f2bf(vV);

            if (ln == 0) {
                int rloc = 16 * mt + 4 * quad + r;
                sqbuf[((0 * 2 + wr) * 4 + wc) * 128 + rloc] = sqq;
                sqbuf[((1 * 2 + wr) * 4 + wc) * 128 + rloc] = sqk;
            }
        }
    }
    __syncthreads();
    {
        int sel = t >> 8, rid = t & 255;
        int wrr = rid >> 7, rloc = rid & 127;
        float s4 = sqbuf[((sel * 2 + wrr) * 4 + 0) * 128 + rloc]
                 + sqbuf[((sel * 2 + wrr) * 4 + 1) * 128 + rloc]
                 + sqbuf[((sel * 2 + wrr) * 4 + 2) * 128 + rloc]
                 + sqbuf[((sel * 2 + wrr) * 4 + 3) * 128 + rloc];
        int m = m0 + 128 * wrr + rloc;
        int bb = m >> 11, s = m & (SEQ - 1);
        size_t hsrow = (size_t)(bb * NH + h) * SEQ + s;
        if (sel == 0) Qsq[hsrow] = s4 * LOG2E - EXP_BIAS;
        else          Ksq[hsrow] = s4 * LOG2E;
    }
}

// ---------------------------------------------------------------------------
// QKV MFMA GEMM 128^2 (round-8 verified) — kept ONLY as !PRE fallback.
// ---------------------------------------------------------------------------
template<bool PRE>
__global__ __launch_bounds__(256) void qkv_mfma_kernel(
    const float* __restrict__ X,
    const ushort_t* __restrict__ Xhi, const ushort_t* __restrict__ Xlo,
    const ushort_t* __restrict__ WqT_hi, const ushort_t* __restrict__ WqT_lo,
    const float* __restrict__ bias,
    ushort_t* __restrict__ Qhi, ushort_t* __restrict__ Qlo,
    ushort_t* __restrict__ Khi, ushort_t* __restrict__ Klo,
    ushort_t* __restrict__ Vout,
    float* __restrict__ Qsq, float* __restrict__ Ksq)
{
    __shared__ ushort_t AS2[2 * 128 * 32];
    __shared__ ushort_t BS [2 * 128 * 32];
    const int LO = 128 * 32;
    const int t = threadIdx.x;
    const int w = t >> 6, lane = t & 63;
    const int quad = (t >> 4) & 3, ln = t & 15;
    const int wr = w >> 1, wc = w & 1;
    const int m0 = blockIdx.y * 128, n0 = blockIdx.x * 128;
    const int g = blockIdx.x * 2 + wc;
    const int h = g / 3, part = g % 3;

    const ushort_t* gA[2]; ushort_t* lA[2];
    const float* aptr = nullptr;
    ushort_t *ast_hi0, *ast_hi1, *ast_lo0, *ast_lo1;
    size_t xlo_off = 0;
    if constexpr (PRE) {
        #pragma unroll
        for (int i = 0; i < 2; i++) {
            int c = 256 * i + 64 * w + lane;
            int r = c >> 2, kbp = c & 3;
            gA[i] = Xhi + (size_t)(m0 + r) * 1024 + 8 * (kbp ^ sw4(r));
            lA[i] = &AS2[(256 * i + 64 * w) * 8];
        }
        xlo_off = (size_t)(Xlo - Xhi);
    } else {
        const int arow = t >> 1, akh = t & 1;
        aptr = X + (size_t)(m0 + arow) * DMODEL + 16 * akh;
        const int asw = sw4(arow);
        ast_hi0 = &AS2[arow * 32 + (((2 * akh) ^ asw) << 3)];
        ast_hi1 = &AS2[arow * 32 + (((2 * akh + 1) ^ asw) << 3)];
        ast_lo0 = &AS2[LO + arow * 32 + (((2 * akh) ^ asw) << 3)];
        ast_lo1 = &AS2[LO + arow * 32 + (((2 * akh + 1) ^ asw) << 3)];
    }

    const ushort_t* gB[2]; ushort_t* lB[2];
    #pragma unroll
    for (int i = 0; i < 2; i++) {
        int c = 256 * i + 64 * w + lane;
        int n = c >> 2, kbp = c & 3;
        gB[i] = WqT_hi + (size_t)(n0 + n) * 1024 + 8 * (kbp ^ sw4(n));
        lB[i] = &BS[(256 * i + 64 * w) * 8];
    }
    const size_t lo_goff = (size_t)(WqT_lo - WqT_hi);

    int aoff[4], boff[4];
    #pragma unroll
    for (int i = 0; i < 4; i++) {
        int m_l = 64 * wr + 16 * i + ln;
        aoff[i] = m_l * 32 + ((quad ^ sw4(m_l)) << 3);
        int n_l = 64 * wc + 16 * i + ln;
        boff[i] = n_l * 32 + ((quad ^ sw4(n_l)) << 3);
    }

    float4v acc[4][4];
    #pragma unroll
    for (int i = 0; i < 4; i++)
        #pragma unroll
        for (int j = 0; j < 4; j++) acc[i][j] = (float4v){0.f, 0.f, 0.f, 0.f};

    for (int k0 = 0; k0 < DMODEL; k0 += 32) {
        __syncthreads();
        #pragma unroll
        for (int i = 0; i < 2; i++) {
            gll16(gB[i] + k0, lB[i]);
            gll16(gB[i] + k0 + lo_goff, lB[i] + LO);
        }
        if constexpr (PRE) {
            #pragma unroll
            for (int i = 0; i < 2; i++) {
                gll16(gA[i] + k0, lA[i]);
                gll16(gA[i] + k0 + xlo_off, lA[i] + LO);
            }
        } else {
            float xs[16];
            *(float4v*)&xs[0]  = *(const float4v*)(aptr + k0);
            *(float4v*)&xs[4]  = *(const float4v*)(aptr + k0 + 4);
            *(float4v*)&xs[8]  = *(const float4v*)(aptr + k0 + 8);
            *(float4v*)&xs[12] = *(const float4v*)(aptr + k0 + 12);
            short8v h0, h1, l0, l1;
            #pragma unroll
            for (int e = 0; e < 8; e++) {
                ushort_t a = f2bf(xs[e]), b = f2bf(xs[8 + e]);
                h0[e] = (short)a; h1[e] = (short)b;
                l0[e] = (short)f2bf(xs[e] - bf2f(a));
                l1[e] = (short)f2bf(xs[8 + e] - bf2f(b));
            }
            *(short8v*)ast_hi0 = h0; *(short8v*)ast_hi1 = h1;
            *(short8v*)ast_lo0 = l0; *(short8v*)ast_lo1 = l1;
        }
        __syncthreads();

        short8v ah[4], al[4], bh[4], bl[4];
        #pragma unroll
        for (int i = 0; i < 4; i++) {
            ah[i] = *(short8v*)&AS2[aoff[i]];
            al[i] = *(short8v*)&AS2[LO + aoff[i]];
            bh[i] = *(short8v*)&BS[boff[i]];
            bl[i] = *(short8v*)&BS[LO + boff[i]];
        }
        if (part != 2) {
            #pragma unroll
            for (int mt = 0; mt < 4; mt++)
                #pragma unroll
                for (int nt = 0; nt < 4; nt++) {
                    acc[mt][nt] = __builtin_amdgcn_mfma_f32_16x16x32_bf16(ah[mt], bh[nt], acc[mt][nt], 0, 0, 0);
                    acc[mt][nt] = __builtin_amdgcn_mfma_f32_16x16x32_bf16(ah[mt], bl[nt], acc[mt][nt], 0, 0, 0);
                    acc[mt][nt] = __builtin_amdgcn_mfma_f32_16x16x32_bf16(al[mt], bh[nt], acc[mt][nt], 0, 0, 0);
                }
        } else {
            #pragma unroll
            for (int mt = 0; mt < 4; mt++)
                #pragma unroll
                for (int nt = 0; nt < 4; nt++)
                    acc[mt][nt] = __builtin_amdgcn_mfma_f32_16x16x32_bf16(ah[mt], bh[nt], acc[mt][nt], 0, 0, 0);
        }
    }

    float bvv[4];
    #pragma unroll
    for (int nt = 0; nt < 4; nt++) bvv[nt] = bias[64 * g + 16 * nt + ln];

    #pragma unroll
    for (int mt = 0; mt < 4; mt++) {
        #pragma unroll
        for (int r = 0; r < 4; r++) {
            int m = m0 + 64 * wr + 16 * mt + 4 * quad + r;
            int bb = m >> 11, s = m & (SEQ - 1);
            size_t hsrow = (size_t)(bb * NH + h) * SEQ + s;
            size_t rowbase = hsrow * HD;
            float vv[4];
            #pragma unroll
            for (int nt = 0; nt < 4; nt++) vv[nt] = acc[mt][nt][r] + bvv[nt];
            if (part == 0) {
                float sq = 0.f;
                #pragma unroll
                for (int nt = 0; nt < 4; nt++) {
                    float v = vv[nt];
                    sq += v * v;
                    float v2 = v * (2.0f * LOG2E);
                    ushort_t hb = f2bf(v2);
                    Qhi[rowbase + 16 * nt + ln] = hb;
                    Qlo[rowbase + 16 * nt + ln] = f2bf(v2 - bf2f(hb));
                }
                sq += __shfl_xor(sq, 1); sq += __shfl_xor(sq, 2);
                sq += __shfl_xor(sq, 4); sq += __shfl_xor(sq, 8);
                if (ln == 0) Qsq[hsrow] = sq * LOG2E - EXP_BIAS;
            } else if (part == 1) {
                float sq = 0.f;
                #pragma unroll
                for (int nt = 0; nt < 4; nt++) {
                    float v = vv[nt];
                    sq += v * v;
                    ushort_t hb = f2bf(v);
                    Khi[rowbase + 16 * nt + ln] = hb;
                    Klo[rowbase + 16 * nt + ln] = f2bf(v - bf2f(hb));
                }
                sq += __shfl_xor(sq, 1); sq += __shfl_xor(sq, 2);
                sq += __shfl_xor(sq, 4); sq += __shfl_xor(sq, 8);
                if (ln == 0) Ksq[hsrow] = sq * LOG2E;
            } else {
                #pragma unroll
                for (int nt = 0; nt < 4; nt++)
                    Vout[rowbase + 16 * nt + ln] = f2bf(vv[nt]);
            }
        }
    }
}

// ---------------------------------------------------------------------------
// MFMA flash attention (round-17): round-11 structure + VALU cuts:
//  - fold -(ksq+qsq) into the MFMA accumulator INIT (removes 32 subs/tile;
//    same sum, different fp32 order)
//  - raw v_exp via __builtin_amdgcn_exp2f (strips ocml fixups)
// ---------------------------------------------------------------------------
template<bool PRE>
__global__ __launch_bounds__(256, 4) void attn_mfma_kernel(
    const ushort_t* __restrict__ Qhi, const ushort_t* __restrict__ Qlo,
    const ushort_t* __restrict__ Khi, const ushort_t* __restrict__ Klo,
    const ushort_t* __restrict__ Vsrc,
    const float* __restrict__ Qsq, const float* __restrict__ Ksq,
    ushort_t* __restrict__ vals)
{
    __shared__ ushort_t KS[2 * 64 * 64];           // [hi 4096 | lo 4096]
    __shared__ ushort_t VtS [64 * 64];
    __shared__ ushort_t PsS [64 * 72];
    const int LO = 64 * 64;

    const int t    = threadIdx.x;
    const int w    = t >> 6, lane = t & 63;
    const int quad = (t >> 4) & 3, ln = t & 15;
    const int bh   = blockIdx.y;
    const int q0   = blockIdx.x * 64;
    const size_t base  = (size_t)bh * SEQ * HD;
    const size_t baseS = (size_t)bh * SEQ;

    short8v qhi[2], qlo[2];
    float nqsq4[4];
    {
        size_t ro = base + (size_t)(q0 + 16 * w + ln) * HD + quad * 8;
        qhi[0] = *(const short8v*)(Qhi + ro);
        qhi[1] = *(const short8v*)(Qhi + ro + 32);
        qlo[0] = *(const short8v*)(Qlo + ro);
        qlo[1] = *(const short8v*)(Qlo + ro + 32);
        float4v q4 = *(const float4v*)(Qsq + baseS + q0 + 16 * w + 4 * quad);
        #pragma unroll
        for (int r = 0; r < 4; r++) nqsq4[r] = -q4[r];
    }

    const ushort_t* gK[2]; ushort_t* lK[2];
    #pragma unroll
    for (int i = 0; i < 2; i++) {
        int c = 256 * i + 64 * w + lane;
        int key = c >> 3, dbp = c & 7;
        gK[i] = Khi + base + (size_t)key * HD + 8 * (dbp ^ (key & 7));
        lK[i] = &KS[(256 * i + 64 * w) * 8];
    }
    const size_t kloff = (size_t)(Klo - Khi);

    const ushort_t* gV[2]; ushort_t* lV[2];
    if constexpr (PRE) {
        #pragma unroll
        for (int i = 0; i < 2; i++) {
            int c = 256 * i + 64 * w + lane;
            int d = c >> 3, kc = c & 7;
            gV[i] = Vsrc + ((size_t)bh * 64 + d) * SEQ + 8 * (kc ^ (d & 7));
            lV[i] = &VtS[(256 * i + 64 * w) * 8];
        }
    }

    float4v accO[4];
    float lsum[4];
    #pragma unroll
    for (int nt = 0; nt < 4; nt++) accO[nt] = (float4v){0.f, 0.f, 0.f, 0.f};
    #pragma unroll
    for (int r = 0; r < 4; r++) lsum[r] = 0.f;

    for (int kt = 0; kt < SEQ; kt += 64) {
        __syncthreads();
        #pragma unroll
        for (int i = 0; i < 2; i++) {
            gll16(gK[i] + (size_t)kt * HD, lK[i]);
            gll16(gK[i] + (size_t)kt * HD + kloff, lK[i] + LO);
        }
        if constexpr (PRE) {
            #pragma unroll
            for (int i = 0; i < 2; i++)
                gll16(gV[i] + kt, lV[i]);
        } else {
            #pragma unroll
            for (int i = 0; i < 2; i++) {
                int c = t + 256 * i;
                int key = c >> 3, db = c & 7;
                short8v v8 = *(const short8v*)(Vsrc + base + (size_t)(kt + key) * HD + 8 * db);
                #pragma unroll
                for (int e = 0; e < 8; e++) {
                    int col = key ^ (e << 3);
                    VtS[(8 * db + e) * 64 + col] = (ushort_t)v8[e];
                }
            }
        }
        float nksq[4];
        #pragma unroll
        for (int nt = 0; nt < 4; nt++)
            nksq[nt] = -Ksq[baseS + kt + 16 * nt + ln];
        __syncthreads();

        // scores: init acc = -(ksq+qsq); MFMA accumulates 2*log2e*q.k on top
        float4v accS[4];
        #pragma unroll
        for (int nt = 0; nt < 4; nt++)
            #pragma unroll
            for (int r = 0; r < 4; r++) accS[nt][r] = nksq[nt] + nqsq4[r];

        #pragma unroll
        for (int nt = 0; nt < 4; nt++) {
            int keyrow = 16 * nt + ln;
            #pragma unroll
            for (int c = 0; c < 2; c++) {
                int db  = quad + 4 * c;
                int off = keyrow * 64 + ((db ^ (keyrow & 7)) << 3);
                short8v bh_ = *(short8v*)&KS[off];
                short8v bl_ = *(short8v*)&KS[LO + off];
                accS[nt] = __builtin_amdgcn_mfma_f32_16x16x32_bf16(qhi[c], bh_, accS[nt], 0, 0, 0);
                accS[nt] = __builtin_amdgcn_mfma_f32_16x16x32_bf16(qhi[c], bl_, accS[nt], 0, 0, 0);
                accS[nt] = __builtin_amdgcn_mfma_f32_16x16x32_bf16(qlo[c], bh_, accS[nt], 0, 0, 0);
            }
        }

        #pragma unroll
        for (int nt = 0; nt < 4; nt++) {
            float pv[4];
            #pragma unroll
            for (int r = 0; r < 4; r++) {
                float p = EXP2F(accS[nt][r]);
                lsum[r] += p;
                pv[r] = p;
            }
            unsigned int pk01, pk23;
            asm("v_cvt_pk_bf16_f32 %0, %1, %2" : "=v"(pk01) : "v"(pv[0]), "v"(pv[1]));
            asm("v_cvt_pk_bf16_f32 %0, %1, %2" : "=v"(pk23) : "v"(pv[2]), "v"(pv[3]));
            ushort_t* pp = &PsS[(16 * w + 4 * quad) * 72 + 16 * nt + ln];
            pp[0]       = (ushort_t)(pk01 & 0xffffu);
            pp[72]      = (ushort_t)(pk01 >> 16);
            pp[144]     = (ushort_t)(pk23 & 0xffffu);
            pp[216]     = (ushort_t)(pk23 >> 16);
        }
        __syncthreads();

        #pragma unroll
        for (int c = 0; c < 2; c++) {
            short8v aP = *(short8v*)&PsS[(16 * w + ln) * 72 + quad * 8 + 32 * c];
            #pragma unroll
            for (int nt = 0; nt < 4; nt++) {
                int drow = 16 * nt + ln;
                int db   = quad + 4 * c;
                int off  = drow * 64 + ((db ^ (drow & 7)) << 3);
                short8v bV = *(short8v*)&VtS[off];
                accO[nt] = __builtin_amdgcn_mfma_f32_16x16x32_bf16(aP, bV, accO[nt], 0, 0, 0);
            }
        }
    }

    const int bb = bh >> 4, h = bh & 15;
    float inv[4];
    #pragma unroll
    for (int r = 0; r < 4; r++) {
        float s = lsum[r];
        s += __shfl_xor(s, 1); s += __shfl_xor(s, 2);
        s += __shfl_xor(s, 4); s += __shfl_xor(s, 8);
        inv[r] = 1.f / s;
    }
    #pragma unroll
    for (int nt = 0; nt < 4; nt++)
        #pragma unroll
        for (int r = 0; r < 4; r++) {
            int row = q0 + 16 * w + 4 * quad + r;
            vals[(size_t)(bb * SEQ + row) * DMODEL + h * 64 + 16 * nt + ln] =
                f2bf(accO[nt][r] * inv[r]);
        }
}

// ---------------------------------------------------------------------------
// Out MFMA GEMM (round-16: double-buffered, prefetch-before-compute).
// ---------------------------------------------------------------------------
__global__ __launch_bounds__(256) void out_mfma_kernel(
    const ushort_t* __restrict__ Ab, const ushort_t* __restrict__ BT,
    const float* __restrict__ bias, float* __restrict__ out)
{
    __shared__ ushort_t AS[2 * 128 * 32], BSo[2 * 128 * 32];   // 16KB + 16KB
    const int BUF = 128 * 32;
    const int t = threadIdx.x;
    const int w = t >> 6;
    const int quad = (t >> 4) & 3, ln = t & 15;
    const int wr = (w >> 1), wc = w & 1;
    const int m0 = blockIdx.y * 128, n0 = blockIdx.x * 128;

    const ushort_t* gA[2]; const ushort_t* gB[2]; int lOff[2];
    #pragma unroll
    for (int i = 0; i < 2; i++) {
        int c = 256 * i + t;
        int r = c >> 2, kbp = c & 3;
        gA[i] = Ab + (size_t)(m0 + r) * 1024 + 8 * (kbp ^ sw4(r));
        gB[i] = BT + (size_t)(n0 + r) * 1024 + 8 * (kbp ^ sw4(r));
        lOff[i] = (256 * i + 64 * w) * 8;
    }
    int aoff[4], boff[4];
    #pragma unroll
    for (int i = 0; i < 4; i++) {
        int m_l = 64 * wr + 16 * i + ln;
        aoff[i] = m_l * 32 + ((quad ^ sw4(m_l)) << 3);
        int n_l = 64 * wc + 16 * i + ln;
        boff[i] = n_l * 32 + ((quad ^ sw4(n_l)) << 3);
    }

    float4v acc[4][4];
    #pragma unroll
    for (int i = 0; i < 4; i++)
        #pragma unroll
        for (int j = 0; j < 4; j++) acc[i][j] = (float4v){0.f, 0.f, 0.f, 0.f};

    auto stage = [&](int ks, int buf) {
        const int kk = 32 * ks;
        #pragma unroll
        for (int i = 0; i < 2; i++) {
            gll16(gA[i] + kk, &AS [buf * BUF] + lOff[i]);
            gll16(gB[i] + kk, &BSo[buf * BUF] + lOff[i]);
        }
    };

    const int NKS = DMODEL / 32;   // 32
    stage(0, 0);
    __syncthreads();               // buf0 staged (implicit vmcnt(0) drain)

    for (int ks = 0; ks < NKS; ks++) {
        const int buf = ks & 1;
        if (ks + 1 < NKS) stage(ks + 1, buf ^ 1);   // prefetch overlaps compute

        const ushort_t* Abuf = &AS [buf * BUF];
        const ushort_t* Bbuf = &BSo[buf * BUF];
        short8v a[4], b[4];
        #pragma unroll
        for (int i = 0; i < 4; i++) {
            a[i] = *(const short8v*)(Abuf + aoff[i]);
            b[i] = *(const short8v*)(Bbuf + boff[i]);
        }
        #pragma unroll
        for (int mt = 0; mt < 4; mt++)
            #pragma unroll
            for (int nt = 0; nt < 4; nt++)
                acc[mt][nt] = __builtin_amdgcn_mfma_f32_16x16x32_bf16(a[mt], b[nt], acc[mt][nt], 0, 0, 0);

        __syncthreads();           // drains prefetch vmcnt + this buf's reads
    }

    #pragma unroll
    for (int nt = 0; nt < 4; nt++) {
        int n = n0 + 64 * wc + 16 * nt + ln;
        float bv = bias[n];
        #pragma unroll
        for (int mt = 0; mt < 4; mt++)
            #pragma unroll
            for (int r = 0; r < 4; r++) {
                int m = m0 + 64 * wr + 16 * mt + 4 * quad + r;
                out[(size_t)m * DMODEL + n] = acc[mt][nt][r] + bv;
            }
    }
}

// ---------------------------------------------------------------------------
// Launch (round-8 layout; PRE if ws fits ~70.5 MiB, else round-7 fallback).
// ---------------------------------------------------------------------------
extern "C" void kernel_launch(void* const* d_in, const int* in_sizes, int n_in,
                              void* d_out, int out_size, void* d_ws, size_t ws_size,
                              hipStream_t stream) {
    const float* x     = (const float*)d_in[0];
    const float* W_qkv = (const float*)d_in[1];
    const float* b_qkv = (const float*)d_in[2];
    const float* W_o   = (const float*)d_in[3];
    const float* b_o   = (const float*)d_in[4];
    float* out = (float*)d_out;

    const size_t WQT = (size_t)N_QKV * DMODEL;
    const size_t WO  = (size_t)DMODEL * DMODEL;
    const size_t QE  = (size_t)NUM_B * NH * SEQ * HD;
    const size_t SQN = (size_t)NUM_B * NH * SEQ;

    const size_t NEED = (2 * WQT + WO + 5 * QE + 2 * QE) * 2 + 2 * SQN * 4;
    const bool pre = (ws_size >= NEED);

    ushort_t* ws     = (ushort_t*)d_ws;
    ushort_t* WqT_hi = ws;
    ushort_t* WqT_lo = WqT_hi + WQT;
    ushort_t* WoT    = WqT_lo + WQT;
    ushort_t* Qhi    = WoT + WO;
    ushort_t* Qlo    = Qhi + QE;
    ushort_t* Khi    = Qlo + QE;
    ushort_t* Klo    = Khi + QE;
    ushort_t* Vx     = Klo + QE;
    float*    Qsq; float* Ksq;
    ushort_t* valsb; ushort_t* Xhi = nullptr; ushort_t* Xlo = nullptr;

    if (pre) {
        Qsq   = (float*)(Vx + QE);
        Ksq   = Qsq + SQN;
        Xhi   = (ushort_t*)(Ksq + SQN);
        Xlo   = Xhi + QE;
        valsb = WqT_hi;
    } else {
        valsb = Vx + QE;
        Qsq   = (float*)(valsb + QE);
        Ksq   = Qsq + SQN;
    }

    prep_kernel<<<pre ? 2048 : 1024, 256, 0, stream>>>(
        W_qkv, W_o, x, WqT_hi, WqT_lo, WoT, Xhi, Xlo);
    if (pre) {
        qkv_uni_kernel<<<dim3(NH, M_TOT / 256), 512, 0, stream>>>(
            Xhi, Xlo, WqT_hi, WqT_lo, b_qkv, Qhi, Qlo, Khi, Klo, Vx, Qsq, Ksq);
        attn_mfma_kernel<true><<<dim3(SEQ / 64, NUM_B * NH), 256, 0, stream>>>(
            Qhi, Qlo, Khi, Klo, Vx, Qsq, Ksq, valsb);
    } else {
        qkv_mfma_kernel<false><<<dim3(N_QKV / 128, M_TOT / 128), 256, 0, stream>>>(
            x, nullptr, nullptr, WqT_hi, WqT_lo, b_qkv, Qhi, Qlo, Khi, Klo, Vx, Qsq, Ksq);
        attn_mfma_kernel<false><<<dim3(SEQ / 64, NUM_B * NH), 256, 0, stream>>>(
            Qhi, Qlo, Khi, Klo, Vx, Qsq, Ksq, valsb);
    }
    out_mfma_kernel<<<dim3(DMODEL / 128, M_TOT / 128), 256, 0, stream>>>(
        valsb, WoT, b_o, out);
}

// Round 11
// 272.531 us; speedup vs baseline: 1.1364x; 1.0003x over previous
//
#include <hip/hip_runtime.h>
#include <hip/hip_bf16.h>

// EuclideanAttention: B=2, S=2048, D=1024, H=16, Hd=64. fp32 in/out.
#define NUM_B   2
#define SEQ     2048
#define DMODEL  1024
#define NH      16
#define HD      64
#define M_TOT   (NUM_B * SEQ)      // 4096
#define N_QKV   (3 * DMODEL)       // 3072
#define LOG2E   1.4426950408889634f
#define EXP_BIAS 96.0f             // round-7 verified softmax bias

typedef __attribute__((ext_vector_type(8))) short short8v;
typedef __attribute__((ext_vector_type(4))) float float4v;
typedef unsigned short ushort_t;

#if __has_builtin(__builtin_amdgcn_exp2f)
#define EXP2F(x) __builtin_amdgcn_exp2f(x)
#else
#define EXP2F(x) exp2f(x)
#endif

__device__ __forceinline__ ushort_t f2bf(float x) {
    unsigned u = __builtin_bit_cast(unsigned, x);
    u = u + 0x7FFFu + ((u >> 16) & 1u);
    return (ushort_t)(u >> 16);
}
__device__ __forceinline__ float bf2f(ushort_t h) {
    unsigned u = ((unsigned)h) << 16;
    return __builtin_bit_cast(float, u);
}
__device__ __forceinline__ void gll16(const void* g, void* l) {
    __builtin_amdgcn_global_load_lds(
        (const __attribute__((address_space(1))) unsigned int*)g,
        (__attribute__((address_space(3))) unsigned int*)l, 16, 0, 0);
}
__device__ __forceinline__ int sw4(int r) { return (r & 3) ^ ((r >> 2) & 3); }

// ---------------------------------------------------------------------------
// Prep: W_qkv -> WqT hi/lo; W_o -> WoT; (PRE) X -> Xhi/Xlo bf16 split.
// ---------------------------------------------------------------------------
__global__ __launch_bounds__(256) void prep_kernel(
    const float* __restrict__ Wq, const float* __restrict__ Wo,
    const float* __restrict__ Xf,
    ushort_t* __restrict__ WqT_hi, ushort_t* __restrict__ WqT_lo,
    ushort_t* __restrict__ WoT,
    ushort_t* __restrict__ Xhi, ushort_t* __restrict__ Xlo)
{
    const int bid = blockIdx.x;
    const int t = threadIdx.x;

    if (bid >= 1024) {             // X split: 1024 blocks x 4096 elements
        size_t base = (size_t)(bid - 1024) * 4096 + t * 16;
        float xs[16];
        *(float4v*)&xs[0]  = *(const float4v*)(Xf + base);
        *(float4v*)&xs[4]  = *(const float4v*)(Xf + base + 4);
        *(float4v*)&xs[8]  = *(const float4v*)(Xf + base + 8);
        *(float4v*)&xs[12] = *(const float4v*)(Xf + base + 12);
        short8v h0, h1, l0, l1;
        #pragma unroll
        for (int e = 0; e < 8; e++) {
            ushort_t a = f2bf(xs[e]), b = f2bf(xs[8 + e]);
            h0[e] = (short)a; h1[e] = (short)b;
            l0[e] = (short)f2bf(xs[e] - bf2f(a));
            l1[e] = (short)f2bf(xs[8 + e] - bf2f(b));
        }
        *(short8v*)(Xhi + base) = h0; *(short8v*)(Xhi + base + 8) = h1;
        *(short8v*)(Xlo + base) = l0; *(short8v*)(Xlo + base + 8) = l1;
        return;
    }

    __shared__ float Tf[64][65];
    const float* src; ushort_t *dhi, *dlo; int N, k0, n0;
    if (bid < 768) {
        int kt = bid / 48, nt = bid % 48;
        src = Wq; N = N_QKV; dhi = WqT_hi; dlo = WqT_lo;
        k0 = kt * 64; n0 = nt * 64;
    } else {
        int tid = bid - 768;
        int kt = tid >> 4, nt = tid & 15;
        src = Wo; N = DMODEL; dhi = WoT; dlo = nullptr;
        k0 = kt * 64; n0 = nt * 64;
    }
    {
        int r = t >> 2, c0 = (t & 3) * 16;
        const float* srow = src + (size_t)(k0 + r) * N + n0 + c0;
        #pragma unroll
        for (int u = 0; u < 4; u++) {
            float4v f = *(const float4v*)(srow + 4 * u);
            #pragma unroll
            for (int e = 0; e < 4; e++) Tf[r][c0 + 4 * u + e] = f[e];
        }
    }
    __syncthreads();
    {
        int nl = t >> 2, kc = (t & 3) * 16;
        short8v h0, h1, l0, l1;
        #pragma unroll
        for (int e = 0; e < 8; e++) {
            float x0 = Tf[kc + e][nl];
            float x1 = Tf[kc + 8 + e][nl];
            ushort_t a = f2bf(x0), b = f2bf(x1);
            h0[e] = (short)a; h1[e] = (short)b;
            l0[e] = (short)f2bf(x0 - bf2f(a));
            l1[e] = (short)f2bf(x1 - bf2f(b));
        }
        ushort_t* o = dhi + (size_t)(n0 + nl) * 1024 + k0 + kc;
        *(short8v*)o = h0; *(short8v*)(o + 8) = h1;
        if (dlo) {
            ushort_t* o2 = dlo + (size_t)(n0 + nl) * 1024 + k0 + kc;
            *(short8v*)o2 = l0; *(short8v*)(o2 + 8) = l1;
        }
    }
}

// ---------------------------------------------------------------------------
// QKV GEMM (round-17 "uniform", round-8-verified): block = (head, 256 rows),
// grid 16x16 = 256 blocks = 1/CU; uniform 56 MFMA/wave/step. Unchanged.
// ---------------------------------------------------------------------------
__global__ __launch_bounds__(512, 2) void qkv_uni_kernel(
    const ushort_t* __restrict__ Xhi, const ushort_t* __restrict__ Xlo,
    const ushort_t* __restrict__ WqT_hi, const ushort_t* __restrict__ WqT_lo,
    const float* __restrict__ bias,
    ushort_t* __restrict__ Qhi, ushort_t* __restrict__ Qlo,
    ushort_t* __restrict__ Khi, ushort_t* __restrict__ Klo,
    ushort_t* __restrict__ Vout,
    float* __restrict__ Qsq, float* __restrict__ Ksq)
{
    const int SLAB_A = 8192, BUFA = 16384;   // halves
    const int SLAB_B = 6144, BUFB = 12288;   // halves
    __shared__ ushort_t AS[2 * BUFA];        // 64 KB
    __shared__ ushort_t BS[2 * BUFB];        // 48 KB

    const int t    = threadIdx.x;            // 0..511
    const int w    = t >> 6;                 // 8 waves
    const int quad = (t >> 4) & 3, ln = t & 15;
    const int wr = w >> 2, wc = w & 3;       // 2 (M-half) x 4 (col-chunk)
    const int h  = blockIdx.x;               // head 0..15
    const int m0 = blockIdx.y * 256;

    const ushort_t* gA[2]; int lOffA[2];
    #pragma unroll
    for (int i = 0; i < 2; i++) {
        int c = 512 * i + t;
        int r = c >> 2, kb = c & 3;
        gA[i] = Xhi + (size_t)(m0 + r) * 1024 + 8 * (kb ^ sw4(r));
        lOffA[i] = (512 * i + 64 * w) * 8;
    }
    const size_t xlo_off = (size_t)(Xlo - Xhi);

    const ushort_t* gBp[3]; int lOffB[3];
    #pragma unroll
    for (int i = 0; i < 3; i++) {
        int c = 512 * i + t;
        bool hi = c < 768;
        int cc = hi ? c : c - 768;
        int j = cc >> 2, kb = cc & 3;
        int jj = j >> 4, jl = j & 15;
        int wcq = jj / 3, part = jj % 3;
        int ng = 192 * h + 64 * part + 16 * wcq + jl;
        gBp[i] = (hi ? WqT_hi : WqT_lo) + (size_t)ng * 1024 + 8 * (kb ^ sw4(j));
        int cwb = (512 * i + 64 * w) - (hi ? 0 : 768);   // wave-uniform
        lOffB[i] = (hi ? 0 : SLAB_B) + cwb * 8;
    }

    int aoff[8], boff[3];
    #pragma unroll
    for (int mt = 0; mt < 8; mt++) {
        int m_l = 128 * wr + 16 * mt + ln;
        aoff[mt] = m_l * 32 + ((quad ^ sw4(m_l)) << 3);
    }
    #pragma unroll
    for (int p = 0; p < 3; p++) {
        int j = 48 * wc + 16 * p + ln;
        boff[p] = j * 32 + ((quad ^ sw4(j)) << 3);
    }

    float4v acc[8][3];
    #pragma unroll
    for (int i = 0; i < 8; i++)
        #pragma unroll
        for (int j = 0; j < 3; j++) acc[i][j] = (float4v){0.f, 0.f, 0.f, 0.f};

    auto stage = [&](int ks, int buf) {
        const int kk = 32 * ks;
        ushort_t* Ab = &AS[buf * BUFA];
        ushort_t* Bb = &BS[buf * BUFB];
        #pragma unroll
        for (int i = 0; i < 2; i++) {
            gll16(gA[i] + kk, Ab + lOffA[i]);
            gll16(gA[i] + kk + xlo_off, Ab + SLAB_A + lOffA[i]);
        }
        #pragma unroll
        for (int i = 0; i < 3; i++)
            gll16(gBp[i] + kk, Bb + lOffB[i]);
    };

    const int NKS = DMODEL / 32;   // 32 k-steps
    stage(0, 0);
    __syncthreads();               // buf0 staged (implicit vmcnt(0) drain)

    for (int ks = 0; ks < NKS; ks++) {
        const int buf = ks & 1;
        if (ks + 1 < NKS) stage(ks + 1, buf ^ 1);   // prefetch overlaps compute

        const ushort_t* Ab = &AS[buf * BUFA];
        const ushort_t* Bb = &BS[buf * BUFB];

        short8v bh0 = *(const short8v*)(Bb + boff[0]);
        short8v bh1 = *(const short8v*)(Bb + boff[1]);
        short8v bh2 = *(const short8v*)(Bb + boff[2]);
        short8v bl0 = *(const short8v*)(Bb + SLAB_B + boff[0]);
        short8v bl1 = *(const short8v*)(Bb + SLAB_B + boff[1]);

        #pragma unroll
        for (int mt = 0; mt < 8; mt++) {
            short8v aH = *(const short8v*)(Ab + aoff[mt]);
            short8v aL = *(const short8v*)(Ab + SLAB_A + aoff[mt]);
            acc[mt][0] = __builtin_amdgcn_mfma_f32_16x16x32_bf16(aH, bh0, acc[mt][0], 0, 0, 0);
            acc[mt][0] = __builtin_amdgcn_mfma_f32_16x16x32_bf16(aH, bl0, acc[mt][0], 0, 0, 0);
            acc[mt][0] = __builtin_amdgcn_mfma_f32_16x16x32_bf16(aL, bh0, acc[mt][0], 0, 0, 0);
            acc[mt][1] = __builtin_amdgcn_mfma_f32_16x16x32_bf16(aH, bh1, acc[mt][1], 0, 0, 0);
            acc[mt][1] = __builtin_amdgcn_mfma_f32_16x16x32_bf16(aH, bl1, acc[mt][1], 0, 0, 0);
            acc[mt][1] = __builtin_amdgcn_mfma_f32_16x16x32_bf16(aL, bh1, acc[mt][1], 0, 0, 0);
            acc[mt][2] = __builtin_amdgcn_mfma_f32_16x16x32_bf16(aH, bh2, acc[mt][2], 0, 0, 0);
        }
        __syncthreads();           // drains prefetch vmcnt + this buf's reads
    }

    // ---- epilogue ----
    const float bQ = bias[192 * h + 16 * wc + ln];
    const float bK = bias[192 * h + 64 + 16 * wc + ln];
    const float bV = bias[192 * h + 128 + 16 * wc + ln];
    const int d = 16 * wc + ln;
    float* sqbuf = (float*)AS;     // [2 sel][2 wr][4 wc][128] = 8 KB (reuse)

    #pragma unroll
    for (int mt = 0; mt < 8; mt++) {
        #pragma unroll
        for (int r = 0; r < 4; r++) {
            int m = m0 + 128 * wr + 16 * mt + 4 * quad + r;
            int bb = m >> 11, s = m & (SEQ - 1);
            size_t hsrow = (size_t)(bb * NH + h) * SEQ + s;
            size_t rowbase = hsrow * HD;

            float vQ = acc[mt][0][r] + bQ;
            float vK = acc[mt][1][r] + bK;
            float vV = acc[mt][2][r] + bV;

            float v2 = vQ * (2.0f * LOG2E);
            ushort_t hbq = f2bf(v2);
            Qhi[rowbase + d] = hbq;
            Qlo[rowbase + d] = f2bf(v2 - bf2f(hbq));
            float sqq = vQ * vQ;
            sqq += __shfl_xor(sqq, 1); sqq += __shfl_xor(sqq, 2);
            sqq += __shfl_xor(sqq, 4); sqq += __shfl_xor(sqq, 8);

            ushort_t hbk = f2bf(vK);
            Khi[rowbase + d] = hbk;
            Klo[rowbase + d] = f2bf(vK - bf2f(hbk));
            float sqk = vK * vK;
            sqk += __shfl_xor(sqk, 1); sqk += __shfl_xor(sqk, 2);
            sqk += __shfl_xor(sqk, 4); sqk += __shfl_xor(sqk, 8);

            Vout[((size_t)(bb * NH + h) * 64 + d) * SEQ + s] = f2bf(vV);

            if (ln == 0) {
                int rloc = 16 * mt + 4 * quad + r;
                sqbuf[((0 * 2 + wr) * 4 + wc) * 128 + rloc] = sqq;
                sqbuf[((1 * 2 + wr) * 4 + wc) * 128 + rloc] = sqk;
            }
        }
    }
    __syncthreads();
    {
        int sel = t >> 8, rid = t & 255;
        int wrr = rid >> 7, rloc = rid & 127;
        float s4 = sqbuf[((sel * 2 + wrr) * 4 + 0) * 128 + rloc]
                 + sqbuf[((sel * 2 + wrr) * 4 + 1) * 128 + rloc]
                 + sqbuf[((sel * 2 + wrr) * 4 + 2) * 128 + rloc]
                 + sqbuf[((sel * 2 + wrr) * 4 + 3) * 128 + rloc];
        int m = m0 + 128 * wrr + rloc;
        int bb = m >> 11, s = m & (SEQ - 1);
        size_t hsrow = (size_t)(bb * NH + h) * SEQ + s;
        if (sel == 0) Qsq[hsrow] = s4 * LOG2E - EXP_BIAS;
        else          Ksq[hsrow] = s4 * LOG2E;
    }
}

// ---------------------------------------------------------------------------
// QKV MFMA GEMM 128^2 (round-8 verified) — kept ONLY as !PRE fallback.
// ---------------------------------------------------------------------------
template<bool PRE>
__global__ __launch_bounds__(256) void qkv_mfma_kernel(
    const float* __restrict__ X,
    const ushort_t* __restrict__ Xhi, const ushort_t* __restrict__ Xlo,
    const ushort_t* __restrict__ WqT_hi, const ushort_t* __restrict__ WqT_lo,
    const float* __restrict__ bias,
    ushort_t* __restrict__ Qhi, ushort_t* __restrict__ Qlo,
    ushort_t* __restrict__ Khi, ushort_t* __restrict__ Klo,
    ushort_t* __restrict__ Vout,
    float* __restrict__ Qsq, float* __restrict__ Ksq)
{
    __shared__ ushort_t AS2[2 * 128 * 32];
    __shared__ ushort_t BS [2 * 128 * 32];
    const int LO = 128 * 32;
    const int t = threadIdx.x;
    const int w = t >> 6, lane = t & 63;
    const int quad = (t >> 4) & 3, ln = t & 15;
    const int wr = w >> 1, wc = w & 1;
    const int m0 = blockIdx.y * 128, n0 = blockIdx.x * 128;
    const int g = blockIdx.x * 2 + wc;
    const int h = g / 3, part = g % 3;

    const ushort_t* gA[2]; ushort_t* lA[2];
    const float* aptr = nullptr;
    ushort_t *ast_hi0, *ast_hi1, *ast_lo0, *ast_lo1;
    size_t xlo_off = 0;
    if constexpr (PRE) {
        #pragma unroll
        for (int i = 0; i < 2; i++) {
            int c = 256 * i + 64 * w + lane;
            int r = c >> 2, kbp = c & 3;
            gA[i] = Xhi + (size_t)(m0 + r) * 1024 + 8 * (kbp ^ sw4(r));
            lA[i] = &AS2[(256 * i + 64 * w) * 8];
        }
        xlo_off = (size_t)(Xlo - Xhi);
    } else {
        const int arow = t >> 1, akh = t & 1;
        aptr = X + (size_t)(m0 + arow) * DMODEL + 16 * akh;
        const int asw = sw4(arow);
        ast_hi0 = &AS2[arow * 32 + (((2 * akh) ^ asw) << 3)];
        ast_hi1 = &AS2[arow * 32 + (((2 * akh + 1) ^ asw) << 3)];
        ast_lo0 = &AS2[LO + arow * 32 + (((2 * akh) ^ asw) << 3)];
        ast_lo1 = &AS2[LO + arow * 32 + (((2 * akh + 1) ^ asw) << 3)];
    }

    const ushort_t* gB[2]; ushort_t* lB[2];
    #pragma unroll
    for (int i = 0; i < 2; i++) {
        int c = 256 * i + 64 * w + lane;
        int n = c >> 2, kbp = c & 3;
        gB[i] = WqT_hi + (size_t)(n0 + n) * 1024 + 8 * (kbp ^ sw4(n));
        lB[i] = &BS[(256 * i + 64 * w) * 8];
    }
    const size_t lo_goff = (size_t)(WqT_lo - WqT_hi);

    int aoff[4], boff[4];
    #pragma unroll
    for (int i = 0; i < 4; i++) {
        int m_l = 64 * wr + 16 * i + ln;
        aoff[i] = m_l * 32 + ((quad ^ sw4(m_l)) << 3);
        int n_l = 64 * wc + 16 * i + ln;
        boff[i] = n_l * 32 + ((quad ^ sw4(n_l)) << 3);
    }

    float4v acc[4][4];
    #pragma unroll
    for (int i = 0; i < 4; i++)
        #pragma unroll
        for (int j = 0; j < 4; j++) acc[i][j] = (float4v){0.f, 0.f, 0.f, 0.f};

    for (int k0 = 0; k0 < DMODEL; k0 += 32) {
        __syncthreads();
        #pragma unroll
        for (int i = 0; i < 2; i++) {
            gll16(gB[i] + k0, lB[i]);
            gll16(gB[i] + k0 + lo_goff, lB[i] + LO);
        }
        if constexpr (PRE) {
            #pragma unroll
            for (int i = 0; i < 2; i++) {
                gll16(gA[i] + k0, lA[i]);
                gll16(gA[i] + k0 + xlo_off, lA[i] + LO);
            }
        } else {
            float xs[16];
            *(float4v*)&xs[0]  = *(const float4v*)(aptr + k0);
            *(float4v*)&xs[4]  = *(const float4v*)(aptr + k0 + 4);
            *(float4v*)&xs[8]  = *(const float4v*)(aptr + k0 + 8);
            *(float4v*)&xs[12] = *(const float4v*)(aptr + k0 + 12);
            short8v h0, h1, l0, l1;
            #pragma unroll
            for (int e = 0; e < 8; e++) {
                ushort_t a = f2bf(xs[e]), b = f2bf(xs[8 + e]);
                h0[e] = (short)a; h1[e] = (short)b;
                l0[e] = (short)f2bf(xs[e] - bf2f(a));
                l1[e] = (short)f2bf(xs[8 + e] - bf2f(b));
            }
            *(short8v*)ast_hi0 = h0; *(short8v*)ast_hi1 = h1;
            *(short8v*)ast_lo0 = l0; *(short8v*)ast_lo1 = l1;
        }
        __syncthreads();

        short8v ah[4], al[4], bh[4], bl[4];
        #pragma unroll
        for (int i = 0; i < 4; i++) {
            ah[i] = *(short8v*)&AS2[aoff[i]];
            al[i] = *(short8v*)&AS2[LO + aoff[i]];
            bh[i] = *(short8v*)&BS[boff[i]];
            bl[i] = *(short8v*)&BS[LO + boff[i]];
        }
        if (part != 2) {
            #pragma unroll
            for (int mt = 0; mt < 4; mt++)
                #pragma unroll
                for (int nt = 0; nt < 4; nt++) {
                    acc[mt][nt] = __builtin_amdgcn_mfma_f32_16x16x32_bf16(ah[mt], bh[nt], acc[mt][nt], 0, 0, 0);
                    acc[mt][nt] = __builtin_amdgcn_mfma_f32_16x16x32_bf16(ah[mt], bl[nt], acc[mt][nt], 0, 0, 0);
                    acc[mt][nt] = __builtin_amdgcn_mfma_f32_16x16x32_bf16(al[mt], bh[nt], acc[mt][nt], 0, 0, 0);
                }
        } else {
            #pragma unroll
            for (int mt = 0; mt < 4; mt++)
                #pragma unroll
                for (int nt = 0; nt < 4; nt++)
                    acc[mt][nt] = __builtin_amdgcn_mfma_f32_16x16x32_bf16(ah[mt], bh[nt], acc[mt][nt], 0, 0, 0);
        }
    }

    float bvv[4];
    #pragma unroll
    for (int nt = 0; nt < 4; nt++) bvv[nt] = bias[64 * g + 16 * nt + ln];

    #pragma unroll
    for (int mt = 0; mt < 4; mt++) {
        #pragma unroll
        for (int r = 0; r < 4; r++) {
            int m = m0 + 64 * wr + 16 * mt + 4 * quad + r;
            int bb = m >> 11, s = m & (SEQ - 1);
            size_t hsrow = (size_t)(bb * NH + h) * SEQ + s;
            size_t rowbase = hsrow * HD;
            float vv[4];
            #pragma unroll
            for (int nt = 0; nt < 4; nt++) vv[nt] = acc[mt][nt][r] + bvv[nt];
            if (part == 0) {
                float sq = 0.f;
                #pragma unroll
                for (int nt = 0; nt < 4; nt++) {
                    float v = vv[nt];
                    sq += v * v;
                    float v2 = v * (2.0f * LOG2E);
                    ushort_t hb = f2bf(v2);
                    Qhi[rowbase + 16 * nt + ln] = hb;
                    Qlo[rowbase + 16 * nt + ln] = f2bf(v2 - bf2f(hb));
                }
                sq += __shfl_xor(sq, 1); sq += __shfl_xor(sq, 2);
                sq += __shfl_xor(sq, 4); sq += __shfl_xor(sq, 8);
                if (ln == 0) Qsq[hsrow] = sq * LOG2E - EXP_BIAS;
            } else if (part == 1) {
                float sq = 0.f;
                #pragma unroll
                for (int nt = 0; nt < 4; nt++) {
                    float v = vv[nt];
                    sq += v * v;
                    ushort_t hb = f2bf(v);
                    Khi[rowbase + 16 * nt + ln] = hb;
                    Klo[rowbase + 16 * nt + ln] = f2bf(v - bf2f(hb));
                }
                sq += __shfl_xor(sq, 1); sq += __shfl_xor(sq, 2);
                sq += __shfl_xor(sq, 4); sq += __shfl_xor(sq, 8);
                if (ln == 0) Ksq[hsrow] = sq * LOG2E;
            } else {
                #pragma unroll
                for (int nt = 0; nt < 4; nt++)
                    Vout[rowbase + 16 * nt + ln] = f2bf(vv[nt]);
            }
        }
    }
}

// ---------------------------------------------------------------------------
// MFMA flash attention (round-17, round-8-VERIFIED 96.3us): folded -(ksq+qsq)
// accumulator init + EXP2F + cvt_pk pack; 3-barrier stage/drain structure.
// Round-18's split staging (2-barrier, inter-barrier gll16) FAILED the
// determinism tripwire -> REVERTED to this exact passing form. Any future
// latency-hiding retry must be A/B'd as a separate verification lane.
// ---------------------------------------------------------------------------
template<bool PRE>
__global__ __launch_bounds__(256, 4) void attn_mfma_kernel(
    const ushort_t* __restrict__ Qhi, const ushort_t* __restrict__ Qlo,
    const ushort_t* __restrict__ Khi, const ushort_t* __restrict__ Klo,
    const ushort_t* __restrict__ Vsrc,
    const float* __restrict__ Qsq, const float* __restrict__ Ksq,
    ushort_t* __restrict__ vals)
{
    __shared__ ushort_t KS[2 * 64 * 64];           // [hi 4096 | lo 4096]
    __shared__ ushort_t VtS [64 * 64];
    __shared__ ushort_t PsS [64 * 72];
    const int LO = 64 * 64;

    const int t    = threadIdx.x;
    const int w    = t >> 6, lane = t & 63;
    const int quad = (t >> 4) & 3, ln = t & 15;
    const int bh   = blockIdx.y;
    const int q0   = blockIdx.x * 64;
    const size_t base  = (size_t)bh * SEQ * HD;
    const size_t baseS = (size_t)bh * SEQ;

    short8v qhi[2], qlo[2];
    float nqsq4[4];
    {
        size_t ro = base + (size_t)(q0 + 16 * w + ln) * HD + quad * 8;
        qhi[0] = *(const short8v*)(Qhi + ro);
        qhi[1] = *(const short8v*)(Qhi + ro + 32);
        qlo[0] = *(const short8v*)(Qlo + ro);
        qlo[1] = *(const short8v*)(Qlo + ro + 32);
        float4v q4 = *(const float4v*)(Qsq + baseS + q0 + 16 * w + 4 * quad);
        #pragma unroll
        for (int r = 0; r < 4; r++) nqsq4[r] = -q4[r];
    }

    const ushort_t* gK[2]; ushort_t* lK[2];
    #pragma unroll
    for (int i = 0; i < 2; i++) {
        int c = 256 * i + 64 * w + lane;
        int key = c >> 3, dbp = c & 7;
        gK[i] = Khi + base + (size_t)key * HD + 8 * (dbp ^ (key & 7));
        lK[i] = &KS[(256 * i + 64 * w) * 8];
    }
    const size_t kloff = (size_t)(Klo - Khi);

    const ushort_t* gV[2]; ushort_t* lV[2];
    if constexpr (PRE) {
        #pragma unroll
        for (int i = 0; i < 2; i++) {
            int c = 256 * i + 64 * w + lane;
            int d = c >> 3, kc = c & 7;
            gV[i] = Vsrc + ((size_t)bh * 64 + d) * SEQ + 8 * (kc ^ (d & 7));
            lV[i] = &VtS[(256 * i + 64 * w) * 8];
        }
    }

    float4v accO[4];
    float lsum[4];
    #pragma unroll
    for (int nt = 0; nt < 4; nt++) accO[nt] = (float4v){0.f, 0.f, 0.f, 0.f};
    #pragma unroll
    for (int r = 0; r < 4; r++) lsum[r] = 0.f;

    for (int kt = 0; kt < SEQ; kt += 64) {
        __syncthreads();
        #pragma unroll
        for (int i = 0; i < 2; i++) {
            gll16(gK[i] + (size_t)kt * HD, lK[i]);
            gll16(gK[i] + (size_t)kt * HD + kloff, lK[i] + LO);
        }
        if constexpr (PRE) {
            #pragma unroll
            for (int i = 0; i < 2; i++)
                gll16(gV[i] + kt, lV[i]);
        } else {
            #pragma unroll
            for (int i = 0; i < 2; i++) {
                int c = t + 256 * i;
                int key = c >> 3, db = c & 7;
                short8v v8 = *(const short8v*)(Vsrc + base + (size_t)(kt + key) * HD + 8 * db);
                #pragma unroll
                for (int e = 0; e < 8; e++) {
                    int col = key ^ (e << 3);
                    VtS[(8 * db + e) * 64 + col] = (ushort_t)v8[e];
                }
            }
        }
        float nksq[4];
        #pragma unroll
        for (int nt = 0; nt < 4; nt++)
            nksq[nt] = -Ksq[baseS + kt + 16 * nt + ln];
        __syncthreads();

        // scores: init acc = -(ksq+qsq); MFMA accumulates 2*log2e*q.k on top
        float4v accS[4];
        #pragma unroll
        for (int nt = 0; nt < 4; nt++)
            #pragma unroll
            for (int r = 0; r < 4; r++) accS[nt][r] = nksq[nt] + nqsq4[r];

        #pragma unroll
        for (int nt = 0; nt < 4; nt++) {
            int keyrow = 16 * nt + ln;
            #pragma unroll
            for (int c = 0; c < 2; c++) {
                int db  = quad + 4 * c;
                int off = keyrow * 64 + ((db ^ (keyrow & 7)) << 3);
                short8v bh_ = *(short8v*)&KS[off];
                short8v bl_ = *(short8v*)&KS[LO + off];
                accS[nt] = __builtin_amdgcn_mfma_f32_16x16x32_bf16(qhi[c], bh_, accS[nt], 0, 0, 0);
                accS[nt] = __builtin_amdgcn_mfma_f32_16x16x32_bf16(qhi[c], bl_, accS[nt], 0, 0, 0);
                accS[nt] = __builtin_amdgcn_mfma_f32_16x16x32_bf16(qlo[c], bh_, accS[nt], 0, 0, 0);
            }
        }

        #pragma unroll
        for (int nt = 0; nt < 4; nt++) {
            float pv[4];
            #pragma unroll
            for (int r = 0; r < 4; r++) {
                float p = EXP2F(accS[nt][r]);
                lsum[r] += p;
                pv[r] = p;
            }
            unsigned int pk01, pk23;
            asm("v_cvt_pk_bf16_f32 %0, %1, %2" : "=v"(pk01) : "v"(pv[0]), "v"(pv[1]));
            asm("v_cvt_pk_bf16_f32 %0, %1, %2" : "=v"(pk23) : "v"(pv[2]), "v"(pv[3]));
            ushort_t* pp = &PsS[(16 * w + 4 * quad) * 72 + 16 * nt + ln];
            pp[0]       = (ushort_t)(pk01 & 0xffffu);
            pp[72]      = (ushort_t)(pk01 >> 16);
            pp[144]     = (ushort_t)(pk23 & 0xffffu);
            pp[216]     = (ushort_t)(pk23 >> 16);
        }
        __syncthreads();

        #pragma unroll
        for (int c = 0; c < 2; c++) {
            short8v aP = *(short8v*)&PsS[(16 * w + ln) * 72 + quad * 8 + 32 * c];
            #pragma unroll
            for (int nt = 0; nt < 4; nt++) {
                int drow = 16 * nt + ln;
                int db   = quad + 4 * c;
                int off  = drow * 64 + ((db ^ (drow & 7)) << 3);
                short8v bV = *(short8v*)&VtS[off];
                accO[nt] = __builtin_amdgcn_mfma_f32_16x16x32_bf16(aP, bV, accO[nt], 0, 0, 0);
            }
        }
    }

    const int bb = bh >> 4, h = bh & 15;
    float inv[4];
    #pragma unroll
    for (int r = 0; r < 4; r++) {
        float s = lsum[r];
        s += __shfl_xor(s, 1); s += __shfl_xor(s, 2);
        s += __shfl_xor(s, 4); s += __shfl_xor(s, 8);
        inv[r] = 1.f / s;
    }
    #pragma unroll
    for (int nt = 0; nt < 4; nt++)
        #pragma unroll
        for (int r = 0; r < 4; r++) {
            int row = q0 + 16 * w + 4 * quad + r;
            vals[(size_t)(bb * SEQ + row) * DMODEL + h * 64 + 16 * nt + ln] =
                f2bf(accO[nt][r] * inv[r]);
        }
}

// ---------------------------------------------------------------------------
// Out MFMA GEMM (round-16: double-buffered, prefetch-before-compute).
// ---------------------------------------------------------------------------
__global__ __launch_bounds__(256) void out_mfma_kernel(
    const ushort_t* __restrict__ Ab, const ushort_t* __restrict__ BT,
    const float* __restrict__ bias, float* __restrict__ out)
{
    __shared__ ushort_t AS[2 * 128 * 32], BSo[2 * 128 * 32];   // 16KB + 16KB
    const int BUF = 128 * 32;
    const int t = threadIdx.x;
    const int w = t >> 6;
    const int quad = (t >> 4) & 3, ln = t & 15;
    const int wr = (w >> 1), wc = w & 1;
    const int m0 = blockIdx.y * 128, n0 = blockIdx.x * 128;

    const ushort_t* gA[2]; const ushort_t* gB[2]; int lOff[2];
    #pragma unroll
    for (int i = 0; i < 2; i++) {
        int c = 256 * i + t;
        int r = c >> 2, kbp = c & 3;
        gA[i] = Ab + (size_t)(m0 + r) * 1024 + 8 * (kbp ^ sw4(r));
        gB[i] = BT + (size_t)(n0 + r) * 1024 + 8 * (kbp ^ sw4(r));
        lOff[i] = (256 * i + 64 * w) * 8;
    }
    int aoff[4], boff[4];
    #pragma unroll
    for (int i = 0; i < 4; i++) {
        int m_l = 64 * wr + 16 * i + ln;
        aoff[i] = m_l * 32 + ((quad ^ sw4(m_l)) << 3);
        int n_l = 64 * wc + 16 * i + ln;
        boff[i] = n_l * 32 + ((quad ^ sw4(n_l)) << 3);
    }

    float4v acc[4][4];
    #pragma unroll
    for (int i = 0; i < 4; i++)
        #pragma unroll
        for (int j = 0; j < 4; j++) acc[i][j] = (float4v){0.f, 0.f, 0.f, 0.f};

    auto stage = [&](int ks, int buf) {
        const int kk = 32 * ks;
        #pragma unroll
        for (int i = 0; i < 2; i++) {
            gll16(gA[i] + kk, &AS [buf * BUF] + lOff[i]);
            gll16(gB[i] + kk, &BSo[buf * BUF] + lOff[i]);
        }
    };

    const int NKS = DMODEL / 32;   // 32
    stage(0, 0);
    __syncthreads();               // buf0 staged (implicit vmcnt(0) drain)

    for (int ks = 0; ks < NKS; ks++) {
        const int buf = ks & 1;
        if (ks + 1 < NKS) stage(ks + 1, buf ^ 1);   // prefetch overlaps compute

        const ushort_t* Abuf = &AS [buf * BUF];
        const ushort_t* Bbuf = &BSo[buf * BUF];
        short8v a[4], b[4];
        #pragma unroll
        for (int i = 0; i < 4; i++) {
            a[i] = *(const short8v*)(Abuf + aoff[i]);
            b[i] = *(const short8v*)(Bbuf + boff[i]);
        }
        #pragma unroll
        for (int mt = 0; mt < 4; mt++)
            #pragma unroll
            for (int nt = 0; nt < 4; nt++)
                acc[mt][nt] = __builtin_amdgcn_mfma_f32_16x16x32_bf16(a[mt], b[nt], acc[mt][nt], 0, 0, 0);

        __syncthreads();           // drains prefetch vmcnt + this buf's reads
    }

    #pragma unroll
    for (int nt = 0; nt < 4; nt++) {
        int n = n0 + 64 * wc + 16 * nt + ln;
        float bv = bias[n];
        #pragma unroll
        for (int mt = 0; mt < 4; mt++)
            #pragma unroll
            for (int r = 0; r < 4; r++) {
                int m = m0 + 64 * wr + 16 * mt + 4 * quad + r;
                out[(size_t)m * DMODEL + n] = acc[mt][nt][r] + bv;
            }
    }
}

// ---------------------------------------------------------------------------
// Launch (round-8 layout; PRE if ws fits ~70.5 MiB, else round-7 fallback).
// ---------------------------------------------------------------------------
extern "C" void kernel_launch(void* const* d_in, const int* in_sizes, int n_in,
                              void* d_out, int out_size, void* d_ws, size_t ws_size,
                              hipStream_t stream) {
    const float* x     = (const float*)d_in[0];
    const float* W_qkv = (const float*)d_in[1];
    const float* b_qkv = (const float*)d_in[2];
    const float* W_o   = (const float*)d_in[3];
    const float* b_o   = (const float*)d_in[4];
    float* out = (float*)d_out;

    const size_t WQT = (size_t)N_QKV * DMODEL;
    const size_t WO  = (size_t)DMODEL * DMODEL;
    const size_t QE  = (size_t)NUM_B * NH * SEQ * HD;
    const size_t SQN = (size_t)NUM_B * NH * SEQ;

    const size_t NEED = (2 * WQT + WO + 5 * QE + 2 * QE) * 2 + 2 * SQN * 4;
    const bool pre = (ws_size >= NEED);

    ushort_t* ws     = (ushort_t*)d_ws;
    ushort_t* WqT_hi = ws;
    ushort_t* WqT_lo = WqT_hi + WQT;
    ushort_t* WoT    = WqT_lo + WQT;
    ushort_t* Qhi    = WoT + WO;
    ushort_t* Qlo    = Qhi + QE;
    ushort_t* Khi    = Qlo + QE;
    ushort_t* Klo    = Khi + QE;
    ushort_t* Vx     = Klo + QE;
    float*    Qsq; float* Ksq;
    ushort_t* valsb; ushort_t* Xhi = nullptr; ushort_t* Xlo = nullptr;

    if (pre) {
        Qsq   = (float*)(Vx + QE);
        Ksq   = Qsq + SQN;
        Xhi   = (ushort_t*)(Ksq + SQN);
        Xlo   = Xhi + QE;
        valsb = WqT_hi;
    } else {
        valsb = Vx + QE;
        Qsq   = (float*)(valsb + QE);
        Ksq   = Qsq + SQN;
    }

    prep_kernel<<<pre ? 2048 : 1024, 256, 0, stream>>>(
        W_qkv, W_o, x, WqT_hi, WqT_lo, WoT, Xhi, Xlo);
    if (pre) {
        qkv_uni_kernel<<<dim3(NH, M_TOT / 256), 512, 0, stream>>>(
            Xhi, Xlo, WqT_hi, WqT_lo, b_qkv, Qhi, Qlo, Khi, Klo, Vx, Qsq, Ksq);
        attn_mfma_kernel<true><<<dim3(SEQ / 64, NUM_B * NH), 256, 0, stream>>>(
            Qhi, Qlo, Khi, Klo, Vx, Qsq, Ksq, valsb);
    } else {
        qkv_mfma_kernel<false><<<dim3(N_QKV / 128, M_TOT / 128), 256, 0, stream>>>(
            x, nullptr, nullptr, WqT_hi, WqT_lo, b_qkv, Qhi, Qlo, Khi, Klo, Vx, Qsq, Ksq);
        attn_mfma_kernel<false><<<dim3(SEQ / 64, NUM_B * NH), 256, 0, stream>>>(
            Qhi, Qlo, Khi, Klo, Vx, Qsq, Ksq, valsb);
    }
    out_mfma_kernel<<<dim3(DMODEL / 128, M_TOT / 128), 256, 0, stream>>>(
        valsb, WoT, b_o, out);
}

// Round 12
// 269.272 us; speedup vs baseline: 1.1502x; 1.0121x over previous
//
#include <hip/hip_runtime.h>
#include <hip/hip_bf16.h>

// EuclideanAttention: B=2, S=2048, D=1024, H=16, Hd=64. fp32 in/out.
#define NUM_B   2
#define SEQ     2048
#define DMODEL  1024
#define NH      16
#define HD      64
#define M_TOT   (NUM_B * SEQ)      // 4096
#define N_QKV   (3 * DMODEL)       // 3072
#define LOG2E   1.4426950408889634f
#define EXP_BIAS 96.0f             // round-7 verified softmax bias

typedef __attribute__((ext_vector_type(8))) short short8v;
typedef __attribute__((ext_vector_type(4))) float float4v;
typedef unsigned short ushort_t;

#if __has_builtin(__builtin_amdgcn_exp2f)
#define EXP2F(x) __builtin_amdgcn_exp2f(x)
#else
#define EXP2F(x) exp2f(x)
#endif

__device__ __forceinline__ ushort_t f2bf(float x) {
    unsigned u = __builtin_bit_cast(unsigned, x);
    u = u + 0x7FFFu + ((u >> 16) & 1u);
    return (ushort_t)(u >> 16);
}
__device__ __forceinline__ float bf2f(ushort_t h) {
    unsigned u = ((unsigned)h) << 16;
    return __builtin_bit_cast(float, u);
}
__device__ __forceinline__ void gll16(const void* g, void* l) {
    __builtin_amdgcn_global_load_lds(
        (const __attribute__((address_space(1))) unsigned int*)g,
        (__attribute__((address_space(3))) unsigned int*)l, 16, 0, 0);
}
__device__ __forceinline__ int sw4(int r) { return (r & 3) ^ ((r >> 2) & 3); }

// ---------------------------------------------------------------------------
// Prep: W_qkv -> WqT hi/lo; W_o -> WoT; (PRE) X -> Xhi/Xlo bf16 split.
// ---------------------------------------------------------------------------
__global__ __launch_bounds__(256) void prep_kernel(
    const float* __restrict__ Wq, const float* __restrict__ Wo,
    const float* __restrict__ Xf,
    ushort_t* __restrict__ WqT_hi, ushort_t* __restrict__ WqT_lo,
    ushort_t* __restrict__ WoT,
    ushort_t* __restrict__ Xhi, ushort_t* __restrict__ Xlo)
{
    const int bid = blockIdx.x;
    const int t = threadIdx.x;

    if (bid >= 1024) {             // X split: 1024 blocks x 4096 elements
        size_t base = (size_t)(bid - 1024) * 4096 + t * 16;
        float xs[16];
        *(float4v*)&xs[0]  = *(const float4v*)(Xf + base);
        *(float4v*)&xs[4]  = *(const float4v*)(Xf + base + 4);
        *(float4v*)&xs[8]  = *(const float4v*)(Xf + base + 8);
        *(float4v*)&xs[12] = *(const float4v*)(Xf + base + 12);
        short8v h0, h1, l0, l1;
        #pragma unroll
        for (int e = 0; e < 8; e++) {
            ushort_t a = f2bf(xs[e]), b = f2bf(xs[8 + e]);
            h0[e] = (short)a; h1[e] = (short)b;
            l0[e] = (short)f2bf(xs[e] - bf2f(a));
            l1[e] = (short)f2bf(xs[8 + e] - bf2f(b));
        }
        *(short8v*)(Xhi + base) = h0; *(short8v*)(Xhi + base + 8) = h1;
        *(short8v*)(Xlo + base) = l0; *(short8v*)(Xlo + base + 8) = l1;
        return;
    }

    __shared__ float Tf[64][65];
    const float* src; ushort_t *dhi, *dlo; int N, k0, n0;
    if (bid < 768) {
        int kt = bid / 48, nt = bid % 48;
        src = Wq; N = N_QKV; dhi = WqT_hi; dlo = WqT_lo;
        k0 = kt * 64; n0 = nt * 64;
    } else {
        int tid = bid - 768;
        int kt = tid >> 4, nt = tid & 15;
        src = Wo; N = DMODEL; dhi = WoT; dlo = nullptr;
        k0 = kt * 64; n0 = nt * 64;
    }
    {
        int r = t >> 2, c0 = (t & 3) * 16;
        const float* srow = src + (size_t)(k0 + r) * N + n0 + c0;
        #pragma unroll
        for (int u = 0; u < 4; u++) {
            float4v f = *(const float4v*)(srow + 4 * u);
            #pragma unroll
            for (int e = 0; e < 4; e++) Tf[r][c0 + 4 * u + e] = f[e];
        }
    }
    __syncthreads();
    {
        int nl = t >> 2, kc = (t & 3) * 16;
        short8v h0, h1, l0, l1;
        #pragma unroll
        for (int e = 0; e < 8; e++) {
            float x0 = Tf[kc + e][nl];
            float x1 = Tf[kc + 8 + e][nl];
            ushort_t a = f2bf(x0), b = f2bf(x1);
            h0[e] = (short)a; h1[e] = (short)b;
            l0[e] = (short)f2bf(x0 - bf2f(a));
            l1[e] = (short)f2bf(x1 - bf2f(b));
        }
        ushort_t* o = dhi + (size_t)(n0 + nl) * 1024 + k0 + kc;
        *(short8v*)o = h0; *(short8v*)(o + 8) = h1;
        if (dlo) {
            ushort_t* o2 = dlo + (size_t)(n0 + nl) * 1024 + k0 + kc;
            *(short8v*)o2 = l0; *(short8v*)(o2 + 8) = l1;
        }
    }
}

// ---------------------------------------------------------------------------
// QKV GEMM, round 19 "uniform/2-res": M-tile 256 -> 128 so LDS 112 -> 80 KB
// and TWO blocks fit per CU (2x80 = 160KB pool; m132 precedent).
// Round-11 counters: qkv_uni 8.1K cyc/step at 1 blk/CU regardless of MFMA
// count (448 vs 768) -> step time is the exposed barrier/drain/LDS critical
// path, not compute. TLP is the one untried lever (it paid twice on attn).
// Grid 16x32 = 512 blocks, __launch_bounds__(512,4) for 2-block residency.
// Schedule/B-staging/swizzles identical to the round-8-verified form.
// ---------------------------------------------------------------------------
__global__ __launch_bounds__(512, 4) void qkv_uni_kernel(
    const ushort_t* __restrict__ Xhi, const ushort_t* __restrict__ Xlo,
    const ushort_t* __restrict__ WqT_hi, const ushort_t* __restrict__ WqT_lo,
    const float* __restrict__ bias,
    ushort_t* __restrict__ Qhi, ushort_t* __restrict__ Qlo,
    ushort_t* __restrict__ Khi, ushort_t* __restrict__ Klo,
    ushort_t* __restrict__ Vout,
    float* __restrict__ Qsq, float* __restrict__ Ksq)
{
    const int SLAB_A = 4096, BUFA = 8192;    // halves (128 rows x 32 k)
    const int SLAB_B = 6144, BUFB = 12288;   // halves (192 rows x 32 k)
    __shared__ ushort_t AS[2 * BUFA];        // 32 KB
    __shared__ ushort_t BS[2 * BUFB];        // 48 KB

    const int t    = threadIdx.x;            // 0..511
    const int w    = t >> 6;                 // 8 waves
    const int quad = (t >> 4) & 3, ln = t & 15;
    const int wr = w >> 2, wc = w & 3;       // 2 (M-half, 64 rows) x 4 (col)
    const int h  = blockIdx.x;               // head 0..15
    const int m0 = blockIdx.y * 128;

    // ---- A staging: 128 rows x 4 chunks = 512 chunks = 1 pass ----
    const ushort_t* gA;
    {
        int r = t >> 2, kb = t & 3;
        gA = Xhi + (size_t)(m0 + r) * 1024 + 8 * (kb ^ sw4(r));
    }
    const int lOffA = (64 * w) * 8;          // wave-uniform LDS base (halves)
    const size_t xlo_off = (size_t)(Xlo - Xhi);

    // ---- B staging: 1536 chunks = hi[768] then lo[768]; 3 passes x 512 ----
    const ushort_t* gBp[3]; int lOffB[3];
    #pragma unroll
    for (int i = 0; i < 3; i++) {
        int c = 512 * i + t;
        bool hi = c < 768;
        int cc = hi ? c : c - 768;
        int j = cc >> 2, kb = cc & 3;
        int jj = j >> 4, jl = j & 15;
        int wcq = jj / 3, part = jj % 3;
        int ng = 192 * h + 64 * part + 16 * wcq + jl;
        gBp[i] = (hi ? WqT_hi : WqT_lo) + (size_t)ng * 1024 + 8 * (kb ^ sw4(j));
        int cwb = (512 * i + 64 * w) - (hi ? 0 : 768);   // wave-uniform
        lOffB[i] = (hi ? 0 : SLAB_B) + cwb * 8;
    }

    // ---- fragment read offsets ----
    int aoff[4], boff[3];
    #pragma unroll
    for (int mt = 0; mt < 4; mt++) {
        int m_l = 64 * wr + 16 * mt + ln;
        aoff[mt] = m_l * 32 + ((quad ^ sw4(m_l)) << 3);
    }
    #pragma unroll
    for (int p = 0; p < 3; p++) {
        int j = 48 * wc + 16 * p + ln;
        boff[p] = j * 32 + ((quad ^ sw4(j)) << 3);
    }

    float4v acc[4][3];
    #pragma unroll
    for (int i = 0; i < 4; i++)
        #pragma unroll
        for (int j = 0; j < 3; j++) acc[i][j] = (float4v){0.f, 0.f, 0.f, 0.f};

    auto stage = [&](int ks, int buf) {
        const int kk = 32 * ks;
        ushort_t* Ab = &AS[buf * BUFA];
        ushort_t* Bb = &BS[buf * BUFB];
        gll16(gA + kk, Ab + lOffA);
        gll16(gA + kk + xlo_off, Ab + SLAB_A + lOffA);
        #pragma unroll
        for (int i = 0; i < 3; i++)
            gll16(gBp[i] + kk, Bb + lOffB[i]);
    };

    const int NKS = DMODEL / 32;   // 32 k-steps
    stage(0, 0);
    __syncthreads();               // buf0 staged (implicit vmcnt(0) drain)

    for (int ks = 0; ks < NKS; ks++) {
        const int buf = ks & 1;
        if (ks + 1 < NKS) stage(ks + 1, buf ^ 1);   // prefetch overlaps compute

        const ushort_t* Ab = &AS[buf * BUFA];
        const ushort_t* Bb = &BS[buf * BUFB];

        short8v bh0 = *(const short8v*)(Bb + boff[0]);
        short8v bh1 = *(const short8v*)(Bb + boff[1]);
        short8v bh2 = *(const short8v*)(Bb + boff[2]);
        short8v bl0 = *(const short8v*)(Bb + SLAB_B + boff[0]);
        short8v bl1 = *(const short8v*)(Bb + SLAB_B + boff[1]);

        #pragma unroll
        for (int mt = 0; mt < 4; mt++) {
            short8v aH = *(const short8v*)(Ab + aoff[mt]);
            short8v aL = *(const short8v*)(Ab + SLAB_A + aoff[mt]);
            acc[mt][0] = __builtin_amdgcn_mfma_f32_16x16x32_bf16(aH, bh0, acc[mt][0], 0, 0, 0);
            acc[mt][0] = __builtin_amdgcn_mfma_f32_16x16x32_bf16(aH, bl0, acc[mt][0], 0, 0, 0);
            acc[mt][0] = __builtin_amdgcn_mfma_f32_16x16x32_bf16(aL, bh0, acc[mt][0], 0, 0, 0);
            acc[mt][1] = __builtin_amdgcn_mfma_f32_16x16x32_bf16(aH, bh1, acc[mt][1], 0, 0, 0);
            acc[mt][1] = __builtin_amdgcn_mfma_f32_16x16x32_bf16(aH, bl1, acc[mt][1], 0, 0, 0);
            acc[mt][1] = __builtin_amdgcn_mfma_f32_16x16x32_bf16(aL, bh1, acc[mt][1], 0, 0, 0);
            acc[mt][2] = __builtin_amdgcn_mfma_f32_16x16x32_bf16(aH, bh2, acc[mt][2], 0, 0, 0);
        }
        __syncthreads();           // drains prefetch vmcnt + this buf's reads
    }

    // ---- epilogue: wave owns head h, 64 rows (m0 + 64*wr ..), col-chunk wc
    const float bQ = bias[192 * h + 16 * wc + ln];
    const float bK = bias[192 * h + 64 + 16 * wc + ln];
    const float bV = bias[192 * h + 128 + 16 * wc + ln];
    const int d = 16 * wc + ln;
    float* sqbuf = (float*)AS;     // [2 sel][2 wr][4 wc][64] = 4 KB (reuse)

    #pragma unroll
    for (int mt = 0; mt < 4; mt++) {
        #pragma unroll
        for (int r = 0; r < 4; r++) {
            int m = m0 + 64 * wr + 16 * mt + 4 * quad + r;
            int bb = m >> 11, s = m & (SEQ - 1);
            size_t hsrow = (size_t)(bb * NH + h) * SEQ + s;
            size_t rowbase = hsrow * HD;

            float vQ = acc[mt][0][r] + bQ;
            float vK = acc[mt][1][r] + bK;
            float vV = acc[mt][2][r] + bV;

            float v2 = vQ * (2.0f * LOG2E);
            ushort_t hbq = f2bf(v2);
            Qhi[rowbase + d] = hbq;
            Qlo[rowbase + d] = f2bf(v2 - bf2f(hbq));
            float sqq = vQ * vQ;
            sqq += __shfl_xor(sqq, 1); sqq += __shfl_xor(sqq, 2);
            sqq += __shfl_xor(sqq, 4); sqq += __shfl_xor(sqq, 8);

            ushort_t hbk = f2bf(vK);
            Khi[rowbase + d] = hbk;
            Klo[rowbase + d] = f2bf(vK - bf2f(hbk));
            float sqk = vK * vK;
            sqk += __shfl_xor(sqk, 1); sqk += __shfl_xor(sqk, 2);
            sqk += __shfl_xor(sqk, 4); sqk += __shfl_xor(sqk, 8);

            Vout[((size_t)(bb * NH + h) * 64 + d) * SEQ + s] = f2bf(vV);

            if (ln == 0) {
                int rloc = 16 * mt + 4 * quad + r;    // 0..63
                sqbuf[((0 * 2 + wr) * 4 + wc) * 64 + rloc] = sqq;
                sqbuf[((1 * 2 + wr) * 4 + wc) * 64 + rloc] = sqk;
            }
        }
    }
    __syncthreads();
    if (t < 256) {
        int sel = t >> 7, rid = t & 127;      // sel 0..1, rid 0..127
        int wrr = rid >> 6, rloc = rid & 63;
        float s4 = sqbuf[((sel * 2 + wrr) * 4 + 0) * 64 + rloc]
                 + sqbuf[((sel * 2 + wrr) * 4 + 1) * 64 + rloc]
                 + sqbuf[((sel * 2 + wrr) * 4 + 2) * 64 + rloc]
                 + sqbuf[((sel * 2 + wrr) * 4 + 3) * 64 + rloc];
        int m = m0 + 64 * wrr + rloc;
        int bb = m >> 11, s = m & (SEQ - 1);
        size_t hsrow = (size_t)(bb * NH + h) * SEQ + s;
        if (sel == 0) Qsq[hsrow] = s4 * LOG2E - EXP_BIAS;
        else          Ksq[hsrow] = s4 * LOG2E;
    }
}

// ---------------------------------------------------------------------------
// QKV MFMA GEMM 128^2 (round-8 verified) — kept ONLY as !PRE fallback.
// ---------------------------------------------------------------------------
template<bool PRE>
__global__ __launch_bounds__(256) void qkv_mfma_kernel(
    const float* __restrict__ X,
    const ushort_t* __restrict__ Xhi, const ushort_t* __restrict__ Xlo,
    const ushort_t* __restrict__ WqT_hi, const ushort_t* __restrict__ WqT_lo,
    const float* __restrict__ bias,
    ushort_t* __restrict__ Qhi, ushort_t* __restrict__ Qlo,
    ushort_t* __restrict__ Khi, ushort_t* __restrict__ Klo,
    ushort_t* __restrict__ Vout,
    float* __restrict__ Qsq, float* __restrict__ Ksq)
{
    __shared__ ushort_t AS2[2 * 128 * 32];
    __shared__ ushort_t BS [2 * 128 * 32];
    const int LO = 128 * 32;
    const int t = threadIdx.x;
    const int w = t >> 6, lane = t & 63;
    const int quad = (t >> 4) & 3, ln = t & 15;
    const int wr = w >> 1, wc = w & 1;
    const int m0 = blockIdx.y * 128, n0 = blockIdx.x * 128;
    const int g = blockIdx.x * 2 + wc;
    const int h = g / 3, part = g % 3;

    const ushort_t* gA[2]; ushort_t* lA[2];
    const float* aptr = nullptr;
    ushort_t *ast_hi0, *ast_hi1, *ast_lo0, *ast_lo1;
    size_t xlo_off = 0;
    if constexpr (PRE) {
        #pragma unroll
        for (int i = 0; i < 2; i++) {
            int c = 256 * i + 64 * w + lane;
            int r = c >> 2, kbp = c & 3;
            gA[i] = Xhi + (size_t)(m0 + r) * 1024 + 8 * (kbp ^ sw4(r));
            lA[i] = &AS2[(256 * i + 64 * w) * 8];
        }
        xlo_off = (size_t)(Xlo - Xhi);
    } else {
        const int arow = t >> 1, akh = t & 1;
        aptr = X + (size_t)(m0 + arow) * DMODEL + 16 * akh;
        const int asw = sw4(arow);
        ast_hi0 = &AS2[arow * 32 + (((2 * akh) ^ asw) << 3)];
        ast_hi1 = &AS2[arow * 32 + (((2 * akh + 1) ^ asw) << 3)];
        ast_lo0 = &AS2[LO + arow * 32 + (((2 * akh) ^ asw) << 3)];
        ast_lo1 = &AS2[LO + arow * 32 + (((2 * akh + 1) ^ asw) << 3)];
    }

    const ushort_t* gB[2]; ushort_t* lB[2];
    #pragma unroll
    for (int i = 0; i < 2; i++) {
        int c = 256 * i + 64 * w + lane;
        int n = c >> 2, kbp = c & 3;
        gB[i] = WqT_hi + (size_t)(n0 + n) * 1024 + 8 * (kbp ^ sw4(n));
        lB[i] = &BS[(256 * i + 64 * w) * 8];
    }
    const size_t lo_goff = (size_t)(WqT_lo - WqT_hi);

    int aoff[4], boff[4];
    #pragma unroll
    for (int i = 0; i < 4; i++) {
        int m_l = 64 * wr + 16 * i + ln;
        aoff[i] = m_l * 32 + ((quad ^ sw4(m_l)) << 3);
        int n_l = 64 * wc + 16 * i + ln;
        boff[i] = n_l * 32 + ((quad ^ sw4(n_l)) << 3);
    }

    float4v acc[4][4];
    #pragma unroll
    for (int i = 0; i < 4; i++)
        #pragma unroll
        for (int j = 0; j < 4; j++) acc[i][j] = (float4v){0.f, 0.f, 0.f, 0.f};

    for (int k0 = 0; k0 < DMODEL; k0 += 32) {
        __syncthreads();
        #pragma unroll
        for (int i = 0; i < 2; i++) {
            gll16(gB[i] + k0, lB[i]);
            gll16(gB[i] + k0 + lo_goff, lB[i] + LO);
        }
        if constexpr (PRE) {
            #pragma unroll
            for (int i = 0; i < 2; i++) {
                gll16(gA[i] + k0, lA[i]);
                gll16(gA[i] + k0 + xlo_off, lA[i] + LO);
            }
        } else {
            float xs[16];
            *(float4v*)&xs[0]  = *(const float4v*)(aptr + k0);
            *(float4v*)&xs[4]  = *(const float4v*)(aptr + k0 + 4);
            *(float4v*)&xs[8]  = *(const float4v*)(aptr + k0 + 8);
            *(float4v*)&xs[12] = *(const float4v*)(aptr + k0 + 12);
            short8v h0, h1, l0, l1;
            #pragma unroll
            for (int e = 0; e < 8; e++) {
                ushort_t a = f2bf(xs[e]), b = f2bf(xs[8 + e]);
                h0[e] = (short)a; h1[e] = (short)b;
                l0[e] = (short)f2bf(xs[e] - bf2f(a));
                l1[e] = (short)f2bf(xs[8 + e] - bf2f(b));
            }
            *(short8v*)ast_hi0 = h0; *(short8v*)ast_hi1 = h1;
            *(short8v*)ast_lo0 = l0; *(short8v*)ast_lo1 = l1;
        }
        __syncthreads();

        short8v ah[4], al[4], bh[4], bl[4];
        #pragma unroll
        for (int i = 0; i < 4; i++) {
            ah[i] = *(short8v*)&AS2[aoff[i]];
            al[i] = *(short8v*)&AS2[LO + aoff[i]];
            bh[i] = *(short8v*)&BS[boff[i]];
            bl[i] = *(short8v*)&BS[LO + boff[i]];
        }
        if (part != 2) {
            #pragma unroll
            for (int mt = 0; mt < 4; mt++)
                #pragma unroll
                for (int nt = 0; nt < 4; nt++) {
                    acc[mt][nt] = __builtin_amdgcn_mfma_f32_16x16x32_bf16(ah[mt], bh[nt], acc[mt][nt], 0, 0, 0);
                    acc[mt][nt] = __builtin_amdgcn_mfma_f32_16x16x32_bf16(ah[mt], bl[nt], acc[mt][nt], 0, 0, 0);
                    acc[mt][nt] = __builtin_amdgcn_mfma_f32_16x16x32_bf16(al[mt], bh[nt], acc[mt][nt], 0, 0, 0);
                }
        } else {
            #pragma unroll
            for (int mt = 0; mt < 4; mt++)
                #pragma unroll
                for (int nt = 0; nt < 4; nt++)
                    acc[mt][nt] = __builtin_amdgcn_mfma_f32_16x16x32_bf16(ah[mt], bh[nt], acc[mt][nt], 0, 0, 0);
        }
    }

    float bvv[4];
    #pragma unroll
    for (int nt = 0; nt < 4; nt++) bvv[nt] = bias[64 * g + 16 * nt + ln];

    #pragma unroll
    for (int mt = 0; mt < 4; mt++) {
        #pragma unroll
        for (int r = 0; r < 4; r++) {
            int m = m0 + 64 * wr + 16 * mt + 4 * quad + r;
            int bb = m >> 11, s = m & (SEQ - 1);
            size_t hsrow = (size_t)(bb * NH + h) * SEQ + s;
            size_t rowbase = hsrow * HD;
            float vv[4];
            #pragma unroll
            for (int nt = 0; nt < 4; nt++) vv[nt] = acc[mt][nt][r] + bvv[nt];
            if (part == 0) {
                float sq = 0.f;
                #pragma unroll
                for (int nt = 0; nt < 4; nt++) {
                    float v = vv[nt];
                    sq += v * v;
                    float v2 = v * (2.0f * LOG2E);
                    ushort_t hb = f2bf(v2);
                    Qhi[rowbase + 16 * nt + ln] = hb;
                    Qlo[rowbase + 16 * nt + ln] = f2bf(v2 - bf2f(hb));
                }
                sq += __shfl_xor(sq, 1); sq += __shfl_xor(sq, 2);
                sq += __shfl_xor(sq, 4); sq += __shfl_xor(sq, 8);
                if (ln == 0) Qsq[hsrow] = sq * LOG2E - EXP_BIAS;
            } else if (part == 1) {
                float sq = 0.f;
                #pragma unroll
                for (int nt = 0; nt < 4; nt++) {
                    float v = vv[nt];
                    sq += v * v;
                    ushort_t hb = f2bf(v);
                    Khi[rowbase + 16 * nt + ln] = hb;
                    Klo[rowbase + 16 * nt + ln] = f2bf(v - bf2f(hb));
                }
                sq += __shfl_xor(sq, 1); sq += __shfl_xor(sq, 2);
                sq += __shfl_xor(sq, 4); sq += __shfl_xor(sq, 8);
                if (ln == 0) Ksq[hsrow] = sq * LOG2E;
            } else {
                #pragma unroll
                for (int nt = 0; nt < 4; nt++)
                    Vout[rowbase + 16 * nt + ln] = f2bf(vv[nt]);
            }
        }
    }
}

// ---------------------------------------------------------------------------
// MFMA flash attention (round-17, round-8/11-VERIFIED): folded -(ksq+qsq)
// accumulator init + EXP2F + cvt_pk pack; 3-barrier structure. Unchanged.
// ---------------------------------------------------------------------------
template<bool PRE>
__global__ __launch_bounds__(256, 4) void attn_mfma_kernel(
    const ushort_t* __restrict__ Qhi, const ushort_t* __restrict__ Qlo,
    const ushort_t* __restrict__ Khi, const ushort_t* __restrict__ Klo,
    const ushort_t* __restrict__ Vsrc,
    const float* __restrict__ Qsq, const float* __restrict__ Ksq,
    ushort_t* __restrict__ vals)
{
    __shared__ ushort_t KS[2 * 64 * 64];           // [hi 4096 | lo 4096]
    __shared__ ushort_t VtS [64 * 64];
    __shared__ ushort_t PsS [64 * 72];
    const int LO = 64 * 64;

    const int t    = threadIdx.x;
    const int w    = t >> 6, lane = t & 63;
    const int quad = (t >> 4) & 3, ln = t & 15;
    const int bh   = blockIdx.y;
    const int q0   = blockIdx.x * 64;
    const size_t base  = (size_t)bh * SEQ * HD;
    const size_t baseS = (size_t)bh * SEQ;

    short8v qhi[2], qlo[2];
    float nqsq4[4];
    {
        size_t ro = base + (size_t)(q0 + 16 * w + ln) * HD + quad * 8;
        qhi[0] = *(const short8v*)(Qhi + ro);
        qhi[1] = *(const short8v*)(Qhi + ro + 32);
        qlo[0] = *(const short8v*)(Qlo + ro);
        qlo[1] = *(const short8v*)(Qlo + ro + 32);
        float4v q4 = *(const float4v*)(Qsq + baseS + q0 + 16 * w + 4 * quad);
        #pragma unroll
        for (int r = 0; r < 4; r++) nqsq4[r] = -q4[r];
    }

    const ushort_t* gK[2]; ushort_t* lK[2];
    #pragma unroll
    for (int i = 0; i < 2; i++) {
        int c = 256 * i + 64 * w + lane;
        int key = c >> 3, dbp = c & 7;
        gK[i] = Khi + base + (size_t)key * HD + 8 * (dbp ^ (key & 7));
        lK[i] = &KS[(256 * i + 64 * w) * 8];
    }
    const size_t kloff = (size_t)(Klo - Khi);

    const ushort_t* gV[2]; ushort_t* lV[2];
    if constexpr (PRE) {
        #pragma unroll
        for (int i = 0; i < 2; i++) {
            int c = 256 * i + 64 * w + lane;
            int d = c >> 3, kc = c & 7;
            gV[i] = Vsrc + ((size_t)bh * 64 + d) * SEQ + 8 * (kc ^ (d & 7));
            lV[i] = &VtS[(256 * i + 64 * w) * 8];
        }
    }

    float4v accO[4];
    float lsum[4];
    #pragma unroll
    for (int nt = 0; nt < 4; nt++) accO[nt] = (float4v){0.f, 0.f, 0.f, 0.f};
    #pragma unroll
    for (int r = 0; r < 4; r++) lsum[r] = 0.f;

    for (int kt = 0; kt < SEQ; kt += 64) {
        __syncthreads();
        #pragma unroll
        for (int i = 0; i < 2; i++) {
            gll16(gK[i] + (size_t)kt * HD, lK[i]);
            gll16(gK[i] + (size_t)kt * HD + kloff, lK[i] + LO);
        }
        if constexpr (PRE) {
            #pragma unroll
            for (int i = 0; i < 2; i++)
                gll16(gV[i] + kt, lV[i]);
        } else {
            #pragma unroll
            for (int i = 0; i < 2; i++) {
                int c = t + 256 * i;
                int key = c >> 3, db = c & 7;
                short8v v8 = *(const short8v*)(Vsrc + base + (size_t)(kt + key) * HD + 8 * db);
                #pragma unroll
                for (int e = 0; e < 8; e++) {
                    int col = key ^ (e << 3);
                    VtS[(8 * db + e) * 64 + col] = (ushort_t)v8[e];
                }
            }
        }
        float nksq[4];
        #pragma unroll
        for (int nt = 0; nt < 4; nt++)
            nksq[nt] = -Ksq[baseS + kt + 16 * nt + ln];
        __syncthreads();

        // scores: init acc = -(ksq+qsq); MFMA accumulates 2*log2e*q.k on top
        float4v accS[4];
        #pragma unroll
        for (int nt = 0; nt < 4; nt++)
            #pragma unroll
            for (int r = 0; r < 4; r++) accS[nt][r] = nksq[nt] + nqsq4[r];

        #pragma unroll
        for (int nt = 0; nt < 4; nt++) {
            int keyrow = 16 * nt + ln;
            #pragma unroll
            for (int c = 0; c < 2; c++) {
                int db  = quad + 4 * c;
                int off = keyrow * 64 + ((db ^ (keyrow & 7)) << 3);
                short8v bh_ = *(short8v*)&KS[off];
                short8v bl_ = *(short8v*)&KS[LO + off];
                accS[nt] = __builtin_amdgcn_mfma_f32_16x16x32_bf16(qhi[c], bh_, accS[nt], 0, 0, 0);
                accS[nt] = __builtin_amdgcn_mfma_f32_16x16x32_bf16(qhi[c], bl_, accS[nt], 0, 0, 0);
                accS[nt] = __builtin_amdgcn_mfma_f32_16x16x32_bf16(qlo[c], bh_, accS[nt], 0, 0, 0);
            }
        }

        #pragma unroll
        for (int nt = 0; nt < 4; nt++) {
            float pv[4];
            #pragma unroll
            for (int r = 0; r < 4; r++) {
                float p = EXP2F(accS[nt][r]);
                lsum[r] += p;
                pv[r] = p;
            }
            unsigned int pk01, pk23;
            asm("v_cvt_pk_bf16_f32 %0, %1, %2" : "=v"(pk01) : "v"(pv[0]), "v"(pv[1]));
            asm("v_cvt_pk_bf16_f32 %0, %1, %2" : "=v"(pk23) : "v"(pv[2]), "v"(pv[3]));
            ushort_t* pp = &PsS[(16 * w + 4 * quad) * 72 + 16 * nt + ln];
            pp[0]       = (ushort_t)(pk01 & 0xffffu);
            pp[72]      = (ushort_t)(pk01 >> 16);
            pp[144]     = (ushort_t)(pk23 & 0xffffu);
            pp[216]     = (ushort_t)(pk23 >> 16);
        }
        __syncthreads();

        #pragma unroll
        for (int c = 0; c < 2; c++) {
            short8v aP = *(short8v*)&PsS[(16 * w + ln) * 72 + quad * 8 + 32 * c];
            #pragma unroll
            for (int nt = 0; nt < 4; nt++) {
                int drow = 16 * nt + ln;
                int db   = quad + 4 * c;
                int off  = drow * 64 + ((db ^ (drow & 7)) << 3);
                short8v bV = *(short8v*)&VtS[off];
                accO[nt] = __builtin_amdgcn_mfma_f32_16x16x32_bf16(aP, bV, accO[nt], 0, 0, 0);
            }
        }
    }

    const int bb = bh >> 4, h = bh & 15;
    float inv[4];
    #pragma unroll
    for (int r = 0; r < 4; r++) {
        float s = lsum[r];
        s += __shfl_xor(s, 1); s += __shfl_xor(s, 2);
        s += __shfl_xor(s, 4); s += __shfl_xor(s, 8);
        inv[r] = 1.f / s;
    }
    #pragma unroll
    for (int nt = 0; nt < 4; nt++)
        #pragma unroll
        for (int r = 0; r < 4; r++) {
            int row = q0 + 16 * w + 4 * quad + r;
            vals[(size_t)(bb * SEQ + row) * DMODEL + h * 64 + 16 * nt + ln] =
                f2bf(accO[nt][r] * inv[r]);
        }
}

// ---------------------------------------------------------------------------
// Out MFMA GEMM (round-16: double-buffered, prefetch-before-compute).
// ---------------------------------------------------------------------------
__global__ __launch_bounds__(256) void out_mfma_kernel(
    const ushort_t* __restrict__ Ab, const ushort_t* __restrict__ BT,
    const float* __restrict__ bias, float* __restrict__ out)
{
    __shared__ ushort_t AS[2 * 128 * 32], BSo[2 * 128 * 32];   // 16KB + 16KB
    const int BUF = 128 * 32;
    const int t = threadIdx.x;
    const int w = t >> 6;
    const int quad = (t >> 4) & 3, ln = t & 15;
    const int wr = (w >> 1), wc = w & 1;
    const int m0 = blockIdx.y * 128, n0 = blockIdx.x * 128;

    const ushort_t* gA[2]; const ushort_t* gB[2]; int lOff[2];
    #pragma unroll
    for (int i = 0; i < 2; i++) {
        int c = 256 * i + t;
        int r = c >> 2, kbp = c & 3;
        gA[i] = Ab + (size_t)(m0 + r) * 1024 + 8 * (kbp ^ sw4(r));
        gB[i] = BT + (size_t)(n0 + r) * 1024 + 8 * (kbp ^ sw4(r));
        lOff[i] = (256 * i + 64 * w) * 8;
    }
    int aoff[4], boff[4];
    #pragma unroll
    for (int i = 0; i < 4; i++) {
        int m_l = 64 * wr + 16 * i + ln;
        aoff[i] = m_l * 32 + ((quad ^ sw4(m_l)) << 3);
        int n_l = 64 * wc + 16 * i + ln;
        boff[i] = n_l * 32 + ((quad ^ sw4(n_l)) << 3);
    }

    float4v acc[4][4];
    #pragma unroll
    for (int i = 0; i < 4; i++)
        #pragma unroll
        for (int j = 0; j < 4; j++) acc[i][j] = (float4v){0.f, 0.f, 0.f, 0.f};

    auto stage = [&](int ks, int buf) {
        const int kk = 32 * ks;
        #pragma unroll
        for (int i = 0; i < 2; i++) {
            gll16(gA[i] + kk, &AS [buf * BUF] + lOff[i]);
            gll16(gB[i] + kk, &BSo[buf * BUF] + lOff[i]);
        }
    };

    const int NKS = DMODEL / 32;   // 32
    stage(0, 0);
    __syncthreads();               // buf0 staged (implicit vmcnt(0) drain)

    for (int ks = 0; ks < NKS; ks++) {
        const int buf = ks & 1;
        if (ks + 1 < NKS) stage(ks + 1, buf ^ 1);   // prefetch overlaps compute

        const ushort_t* Abuf = &AS [buf * BUF];
        const ushort_t* Bbuf = &BSo[buf * BUF];
        short8v a[4], b[4];
        #pragma unroll
        for (int i = 0; i < 4; i++) {
            a[i] = *(const short8v*)(Abuf + aoff[i]);
            b[i] = *(const short8v*)(Bbuf + boff[i]);
        }
        #pragma unroll
        for (int mt = 0; mt < 4; mt++)
            #pragma unroll
            for (int nt = 0; nt < 4; nt++)
                acc[mt][nt] = __builtin_amdgcn_mfma_f32_16x16x32_bf16(a[mt], b[nt], acc[mt][nt], 0, 0, 0);

        __syncthreads();           // drains prefetch vmcnt + this buf's reads
    }

    #pragma unroll
    for (int nt = 0; nt < 4; nt++) {
        int n = n0 + 64 * wc + 16 * nt + ln;
        float bv = bias[n];
        #pragma unroll
        for (int mt = 0; mt < 4; mt++)
            #pragma unroll
            for (int r = 0; r < 4; r++) {
                int m = m0 + 64 * wr + 16 * mt + 4 * quad + r;
                out[(size_t)m * DMODEL + n] = acc[mt][nt][r] + bv;
            }
    }
}

// ---------------------------------------------------------------------------
// Launch (round-8 layout; PRE if ws fits ~70.5 MiB, else round-7 fallback).
// ---------------------------------------------------------------------------
extern "C" void kernel_launch(void* const* d_in, const int* in_sizes, int n_in,
                              void* d_out, int out_size, void* d_ws, size_t ws_size,
                              hipStream_t stream) {
    const float* x     = (const float*)d_in[0];
    const float* W_qkv = (const float*)d_in[1];
    const float* b_qkv = (const float*)d_in[2];
    const float* W_o   = (const float*)d_in[3];
    const float* b_o   = (const float*)d_in[4];
    float* out = (float*)d_out;

    const size_t WQT = (size_t)N_QKV * DMODEL;
    const size_t WO  = (size_t)DMODEL * DMODEL;
    const size_t QE  = (size_t)NUM_B * NH * SEQ * HD;
    const size_t SQN = (size_t)NUM_B * NH * SEQ;

    const size_t NEED = (2 * WQT + WO + 5 * QE + 2 * QE) * 2 + 2 * SQN * 4;
    const bool pre = (ws_size >= NEED);

    ushort_t* ws     = (ushort_t*)d_ws;
    ushort_t* WqT_hi = ws;
    ushort_t* WqT_lo = WqT_hi + WQT;
    ushort_t* WoT    = WqT_lo + WQT;
    ushort_t* Qhi    = WoT + WO;
    ushort_t* Qlo    = Qhi + QE;
    ushort_t* Khi    = Qlo + QE;
    ushort_t* Klo    = Khi + QE;
    ushort_t* Vx     = Klo + QE;
    float*    Qsq; float* Ksq;
    ushort_t* valsb; ushort_t* Xhi = nullptr; ushort_t* Xlo = nullptr;

    if (pre) {
        Qsq   = (float*)(Vx + QE);
        Ksq   = Qsq + SQN;
        Xhi   = (ushort_t*)(Ksq + SQN);
        Xlo   = Xhi + QE;
        valsb = WqT_hi;
    } else {
        valsb = Vx + QE;
        Qsq   = (float*)(valsb + QE);
        Ksq   = Qsq + SQN;
    }

    prep_kernel<<<pre ? 2048 : 1024, 256, 0, stream>>>(
        W_qkv, W_o, x, WqT_hi, WqT_lo, WoT, Xhi, Xlo);
    if (pre) {
        qkv_uni_kernel<<<dim3(NH, M_TOT / 128), 512, 0, stream>>>(
            Xhi, Xlo, WqT_hi, WqT_lo, b_qkv, Qhi, Qlo, Khi, Klo, Vx, Qsq, Ksq);
        attn_mfma_kernel<true><<<dim3(SEQ / 64, NUM_B * NH), 256, 0, stream>>>(
            Qhi, Qlo, Khi, Klo, Vx, Qsq, Ksq, valsb);
    } else {
        qkv_mfma_kernel<false><<<dim3(N_QKV / 128, M_TOT / 128), 256, 0, stream>>>(
            x, nullptr, nullptr, WqT_hi, WqT_lo, b_qkv, Qhi, Qlo, Khi, Klo, Vx, Qsq, Ksq);
        attn_mfma_kernel<false><<<dim3(SEQ / 64, NUM_B * NH), 256, 0, stream>>>(
            Qhi, Qlo, Khi, Klo, Vx, Qsq, Ksq, valsb);
    }
    out_mfma_kernel<<<dim3(DMODEL / 128, M_TOT / 128), 256, 0, stream>>>(
        valsb, WoT, b_o, out);
}

// Round 13
// 265.079 us; speedup vs baseline: 1.1684x; 1.0158x over previous
//
#include <hip/hip_runtime.h>
#include <hip/hip_bf16.h>

// EuclideanAttention: B=2, S=2048, D=1024, H=16, Hd=64. fp32 in/out.
#define NUM_B   2
#define SEQ     2048
#define DMODEL  1024
#define NH      16
#define HD      64
#define M_TOT   (NUM_B * SEQ)      // 4096
#define N_QKV   (3 * DMODEL)       // 3072
#define LOG2E   1.4426950408889634f
#define EXP_BIAS 96.0f             // round-7 verified softmax bias

typedef __attribute__((ext_vector_type(8))) short short8v;
typedef __attribute__((ext_vector_type(4))) float float4v;
typedef unsigned short ushort_t;

#if __has_builtin(__builtin_amdgcn_exp2f)
#define EXP2F(x) __builtin_amdgcn_exp2f(x)
#else
#define EXP2F(x) exp2f(x)
#endif

__device__ __forceinline__ ushort_t f2bf(float x) {
    unsigned u = __builtin_bit_cast(unsigned, x);
    u = u + 0x7FFFu + ((u >> 16) & 1u);
    return (ushort_t)(u >> 16);
}
__device__ __forceinline__ float bf2f(ushort_t h) {
    unsigned u = ((unsigned)h) << 16;
    return __builtin_bit_cast(float, u);
}
__device__ __forceinline__ void gll16(const void* g, void* l) {
    __builtin_amdgcn_global_load_lds(
        (const __attribute__((address_space(1))) unsigned int*)g,
        (__attribute__((address_space(3))) unsigned int*)l, 16, 0, 0);
}
__device__ __forceinline__ int sw4(int r) { return (r & 3) ^ ((r >> 2) & 3); }

// ---------------------------------------------------------------------------
// Prep: W_qkv -> WqT hi/lo; W_o -> WoT; (PRE) X -> Xhi/Xlo bf16 split.
// ---------------------------------------------------------------------------
__global__ __launch_bounds__(256) void prep_kernel(
    const float* __restrict__ Wq, const float* __restrict__ Wo,
    const float* __restrict__ Xf,
    ushort_t* __restrict__ WqT_hi, ushort_t* __restrict__ WqT_lo,
    ushort_t* __restrict__ WoT,
    ushort_t* __restrict__ Xhi, ushort_t* __restrict__ Xlo)
{
    const int bid = blockIdx.x;
    const int t = threadIdx.x;

    if (bid >= 1024) {             // X split: 1024 blocks x 4096 elements
        size_t base = (size_t)(bid - 1024) * 4096 + t * 16;
        float xs[16];
        *(float4v*)&xs[0]  = *(const float4v*)(Xf + base);
        *(float4v*)&xs[4]  = *(const float4v*)(Xf + base + 4);
        *(float4v*)&xs[8]  = *(const float4v*)(Xf + base + 8);
        *(float4v*)&xs[12] = *(const float4v*)(Xf + base + 12);
        short8v h0, h1, l0, l1;
        #pragma unroll
        for (int e = 0; e < 8; e++) {
            ushort_t a = f2bf(xs[e]), b = f2bf(xs[8 + e]);
            h0[e] = (short)a; h1[e] = (short)b;
            l0[e] = (short)f2bf(xs[e] - bf2f(a));
            l1[e] = (short)f2bf(xs[8 + e] - bf2f(b));
        }
        *(short8v*)(Xhi + base) = h0; *(short8v*)(Xhi + base + 8) = h1;
        *(short8v*)(Xlo + base) = l0; *(short8v*)(Xlo + base + 8) = l1;
        return;
    }

    __shared__ float Tf[64][65];
    const float* src; ushort_t *dhi, *dlo; int N, k0, n0;
    if (bid < 768) {
        int kt = bid / 48, nt = bid % 48;
        src = Wq; N = N_QKV; dhi = WqT_hi; dlo = WqT_lo;
        k0 = kt * 64; n0 = nt * 64;
    } else {
        int tid = bid - 768;
        int kt = tid >> 4, nt = tid & 15;
        src = Wo; N = DMODEL; dhi = WoT; dlo = nullptr;
        k0 = kt * 64; n0 = nt * 64;
    }
    {
        int r = t >> 2, c0 = (t & 3) * 16;
        const float* srow = src + (size_t)(k0 + r) * N + n0 + c0;
        #pragma unroll
        for (int u = 0; u < 4; u++) {
            float4v f = *(const float4v*)(srow + 4 * u);
            #pragma unroll
            for (int e = 0; e < 4; e++) Tf[r][c0 + 4 * u + e] = f[e];
        }
    }
    __syncthreads();
    {
        int nl = t >> 2, kc = (t & 3) * 16;
        short8v h0, h1, l0, l1;
        #pragma unroll
        for (int e = 0; e < 8; e++) {
            float x0 = Tf[kc + e][nl];
            float x1 = Tf[kc + 8 + e][nl];
            ushort_t a = f2bf(x0), b = f2bf(x1);
            h0[e] = (short)a; h1[e] = (short)b;
            l0[e] = (short)f2bf(x0 - bf2f(a));
            l1[e] = (short)f2bf(x1 - bf2f(b));
        }
        ushort_t* o = dhi + (size_t)(n0 + nl) * 1024 + k0 + kc;
        *(short8v*)o = h0; *(short8v*)(o + 8) = h1;
        if (dlo) {
            ushort_t* o2 = dlo + (size_t)(n0 + nl) * 1024 + k0 + kc;
            *(short8v*)o2 = l0; *(short8v*)(o2 + 8) = l1;
        }
    }
}

// ---------------------------------------------------------------------------
// QKV GEMM (round-19 "uniform/2-res", round-12-verified): M-tile 128,
// 80 KB LDS -> 2 blocks/CU. Unchanged.
// ---------------------------------------------------------------------------
__global__ __launch_bounds__(512, 4) void qkv_uni_kernel(
    const ushort_t* __restrict__ Xhi, const ushort_t* __restrict__ Xlo,
    const ushort_t* __restrict__ WqT_hi, const ushort_t* __restrict__ WqT_lo,
    const float* __restrict__ bias,
    ushort_t* __restrict__ Qhi, ushort_t* __restrict__ Qlo,
    ushort_t* __restrict__ Khi, ushort_t* __restrict__ Klo,
    ushort_t* __restrict__ Vout,
    float* __restrict__ Qsq, float* __restrict__ Ksq)
{
    const int SLAB_A = 4096, BUFA = 8192;    // halves (128 rows x 32 k)
    const int SLAB_B = 6144, BUFB = 12288;   // halves (192 rows x 32 k)
    __shared__ ushort_t AS[2 * BUFA];        // 32 KB
    __shared__ ushort_t BS[2 * BUFB];        // 48 KB

    const int t    = threadIdx.x;            // 0..511
    const int w    = t >> 6;                 // 8 waves
    const int quad = (t >> 4) & 3, ln = t & 15;
    const int wr = w >> 2, wc = w & 3;       // 2 (M-half, 64 rows) x 4 (col)
    const int h  = blockIdx.x;               // head 0..15
    const int m0 = blockIdx.y * 128;

    // ---- A staging: 128 rows x 4 chunks = 512 chunks = 1 pass ----
    const ushort_t* gA;
    {
        int r = t >> 2, kb = t & 3;
        gA = Xhi + (size_t)(m0 + r) * 1024 + 8 * (kb ^ sw4(r));
    }
    const int lOffA = (64 * w) * 8;          // wave-uniform LDS base (halves)
    const size_t xlo_off = (size_t)(Xlo - Xhi);

    // ---- B staging: 1536 chunks = hi[768] then lo[768]; 3 passes x 512 ----
    const ushort_t* gBp[3]; int lOffB[3];
    #pragma unroll
    for (int i = 0; i < 3; i++) {
        int c = 512 * i + t;
        bool hi = c < 768;
        int cc = hi ? c : c - 768;
        int j = cc >> 2, kb = cc & 3;
        int jj = j >> 4, jl = j & 15;
        int wcq = jj / 3, part = jj % 3;
        int ng = 192 * h + 64 * part + 16 * wcq + jl;
        gBp[i] = (hi ? WqT_hi : WqT_lo) + (size_t)ng * 1024 + 8 * (kb ^ sw4(j));
        int cwb = (512 * i + 64 * w) - (hi ? 0 : 768);   // wave-uniform
        lOffB[i] = (hi ? 0 : SLAB_B) + cwb * 8;
    }

    // ---- fragment read offsets ----
    int aoff[4], boff[3];
    #pragma unroll
    for (int mt = 0; mt < 4; mt++) {
        int m_l = 64 * wr + 16 * mt + ln;
        aoff[mt] = m_l * 32 + ((quad ^ sw4(m_l)) << 3);
    }
    #pragma unroll
    for (int p = 0; p < 3; p++) {
        int j = 48 * wc + 16 * p + ln;
        boff[p] = j * 32 + ((quad ^ sw4(j)) << 3);
    }

    float4v acc[4][3];
    #pragma unroll
    for (int i = 0; i < 4; i++)
        #pragma unroll
        for (int j = 0; j < 3; j++) acc[i][j] = (float4v){0.f, 0.f, 0.f, 0.f};

    auto stage = [&](int ks, int buf) {
        const int kk = 32 * ks;
        ushort_t* Ab = &AS[buf * BUFA];
        ushort_t* Bb = &BS[buf * BUFB];
        gll16(gA + kk, Ab + lOffA);
        gll16(gA + kk + xlo_off, Ab + SLAB_A + lOffA);
        #pragma unroll
        for (int i = 0; i < 3; i++)
            gll16(gBp[i] + kk, Bb + lOffB[i]);
    };

    const int NKS = DMODEL / 32;   // 32 k-steps
    stage(0, 0);
    __syncthreads();               // buf0 staged (implicit vmcnt(0) drain)

    for (int ks = 0; ks < NKS; ks++) {
        const int buf = ks & 1;
        if (ks + 1 < NKS) stage(ks + 1, buf ^ 1);   // prefetch overlaps compute

        const ushort_t* Ab = &AS[buf * BUFA];
        const ushort_t* Bb = &BS[buf * BUFB];

        short8v bh0 = *(const short8v*)(Bb + boff[0]);
        short8v bh1 = *(const short8v*)(Bb + boff[1]);
        short8v bh2 = *(const short8v*)(Bb + boff[2]);
        short8v bl0 = *(const short8v*)(Bb + SLAB_B + boff[0]);
        short8v bl1 = *(const short8v*)(Bb + SLAB_B + boff[1]);

        #pragma unroll
        for (int mt = 0; mt < 4; mt++) {
            short8v aH = *(const short8v*)(Ab + aoff[mt]);
            short8v aL = *(const short8v*)(Ab + SLAB_A + aoff[mt]);
            acc[mt][0] = __builtin_amdgcn_mfma_f32_16x16x32_bf16(aH, bh0, acc[mt][0], 0, 0, 0);
            acc[mt][0] = __builtin_amdgcn_mfma_f32_16x16x32_bf16(aH, bl0, acc[mt][0], 0, 0, 0);
            acc[mt][0] = __builtin_amdgcn_mfma_f32_16x16x32_bf16(aL, bh0, acc[mt][0], 0, 0, 0);
            acc[mt][1] = __builtin_amdgcn_mfma_f32_16x16x32_bf16(aH, bh1, acc[mt][1], 0, 0, 0);
            acc[mt][1] = __builtin_amdgcn_mfma_f32_16x16x32_bf16(aH, bl1, acc[mt][1], 0, 0, 0);
            acc[mt][1] = __builtin_amdgcn_mfma_f32_16x16x32_bf16(aL, bh1, acc[mt][1], 0, 0, 0);
            acc[mt][2] = __builtin_amdgcn_mfma_f32_16x16x32_bf16(aH, bh2, acc[mt][2], 0, 0, 0);
        }
        __syncthreads();           // drains prefetch vmcnt + this buf's reads
    }

    // ---- epilogue: wave owns head h, 64 rows (m0 + 64*wr ..), col-chunk wc
    const float bQ = bias[192 * h + 16 * wc + ln];
    const float bK = bias[192 * h + 64 + 16 * wc + ln];
    const float bV = bias[192 * h + 128 + 16 * wc + ln];
    const int d = 16 * wc + ln;
    float* sqbuf = (float*)AS;     // [2 sel][2 wr][4 wc][64] = 4 KB (reuse)

    #pragma unroll
    for (int mt = 0; mt < 4; mt++) {
        #pragma unroll
        for (int r = 0; r < 4; r++) {
            int m = m0 + 64 * wr + 16 * mt + 4 * quad + r;
            int bb = m >> 11, s = m & (SEQ - 1);
            size_t hsrow = (size_t)(bb * NH + h) * SEQ + s;
            size_t rowbase = hsrow * HD;

            float vQ = acc[mt][0][r] + bQ;
            float vK = acc[mt][1][r] + bK;
            float vV = acc[mt][2][r] + bV;

            float v2 = vQ * (2.0f * LOG2E);
            ushort_t hbq = f2bf(v2);
            Qhi[rowbase + d] = hbq;
            Qlo[rowbase + d] = f2bf(v2 - bf2f(hbq));
            float sqq = vQ * vQ;
            sqq += __shfl_xor(sqq, 1); sqq += __shfl_xor(sqq, 2);
            sqq += __shfl_xor(sqq, 4); sqq += __shfl_xor(sqq, 8);

            ushort_t hbk = f2bf(vK);
            Khi[rowbase + d] = hbk;
            Klo[rowbase + d] = f2bf(vK - bf2f(hbk));
            float sqk = vK * vK;
            sqk += __shfl_xor(sqk, 1); sqk += __shfl_xor(sqk, 2);
            sqk += __shfl_xor(sqk, 4); sqk += __shfl_xor(sqk, 8);

            Vout[((size_t)(bb * NH + h) * 64 + d) * SEQ + s] = f2bf(vV);

            if (ln == 0) {
                int rloc = 16 * mt + 4 * quad + r;    // 0..63
                sqbuf[((0 * 2 + wr) * 4 + wc) * 64 + rloc] = sqq;
                sqbuf[((1 * 2 + wr) * 4 + wc) * 64 + rloc] = sqk;
            }
        }
    }
    __syncthreads();
    if (t < 256) {
        int sel = t >> 7, rid = t & 127;      // sel 0..1, rid 0..127
        int wrr = rid >> 6, rloc = rid & 63;
        float s4 = sqbuf[((sel * 2 + wrr) * 4 + 0) * 64 + rloc]
                 + sqbuf[((sel * 2 + wrr) * 4 + 1) * 64 + rloc]
                 + sqbuf[((sel * 2 + wrr) * 4 + 2) * 64 + rloc]
                 + sqbuf[((sel * 2 + wrr) * 4 + 3) * 64 + rloc];
        int m = m0 + 64 * wrr + rloc;
        int bb = m >> 11, s = m & (SEQ - 1);
        size_t hsrow = (size_t)(bb * NH + h) * SEQ + s;
        if (sel == 0) Qsq[hsrow] = s4 * LOG2E - EXP_BIAS;
        else          Ksq[hsrow] = s4 * LOG2E;
    }
}

// ---------------------------------------------------------------------------
// QKV MFMA GEMM 128^2 (round-8 verified) — kept ONLY as !PRE fallback.
// ---------------------------------------------------------------------------
template<bool PRE>
__global__ __launch_bounds__(256) void qkv_mfma_kernel(
    const float* __restrict__ X,
    const ushort_t* __restrict__ Xhi, const ushort_t* __restrict__ Xlo,
    const ushort_t* __restrict__ WqT_hi, const ushort_t* __restrict__ WqT_lo,
    const float* __restrict__ bias,
    ushort_t* __restrict__ Qhi, ushort_t* __restrict__ Qlo,
    ushort_t* __restrict__ Khi, ushort_t* __restrict__ Klo,
    ushort_t* __restrict__ Vout,
    float* __restrict__ Qsq, float* __restrict__ Ksq)
{
    __shared__ ushort_t AS2[2 * 128 * 32];
    __shared__ ushort_t BS [2 * 128 * 32];
    const int LO = 128 * 32;
    const int t = threadIdx.x;
    const int w = t >> 6, lane = t & 63;
    const int quad = (t >> 4) & 3, ln = t & 15;
    const int wr = w >> 1, wc = w & 1;
    const int m0 = blockIdx.y * 128, n0 = blockIdx.x * 128;
    const int g = blockIdx.x * 2 + wc;
    const int h = g / 3, part = g % 3;

    const ushort_t* gA[2]; ushort_t* lA[2];
    const float* aptr = nullptr;
    ushort_t *ast_hi0, *ast_hi1, *ast_lo0, *ast_lo1;
    size_t xlo_off = 0;
    if constexpr (PRE) {
        #pragma unroll
        for (int i = 0; i < 2; i++) {
            int c = 256 * i + 64 * w + lane;
            int r = c >> 2, kbp = c & 3;
            gA[i] = Xhi + (size_t)(m0 + r) * 1024 + 8 * (kbp ^ sw4(r));
            lA[i] = &AS2[(256 * i + 64 * w) * 8];
        }
        xlo_off = (size_t)(Xlo - Xhi);
    } else {
        const int arow = t >> 1, akh = t & 1;
        aptr = X + (size_t)(m0 + arow) * DMODEL + 16 * akh;
        const int asw = sw4(arow);
        ast_hi0 = &AS2[arow * 32 + (((2 * akh) ^ asw) << 3)];
        ast_hi1 = &AS2[arow * 32 + (((2 * akh + 1) ^ asw) << 3)];
        ast_lo0 = &AS2[LO + arow * 32 + (((2 * akh) ^ asw) << 3)];
        ast_lo1 = &AS2[LO + arow * 32 + (((2 * akh + 1) ^ asw) << 3)];
    }

    const ushort_t* gB[2]; ushort_t* lB[2];
    #pragma unroll
    for (int i = 0; i < 2; i++) {
        int c = 256 * i + 64 * w + lane;
        int n = c >> 2, kbp = c & 3;
        gB[i] = WqT_hi + (size_t)(n0 + n) * 1024 + 8 * (kbp ^ sw4(n));
        lB[i] = &BS[(256 * i + 64 * w) * 8];
    }
    const size_t lo_goff = (size_t)(WqT_lo - WqT_hi);

    int aoff[4], boff[4];
    #pragma unroll
    for (int i = 0; i < 4; i++) {
        int m_l = 64 * wr + 16 * i + ln;
        aoff[i] = m_l * 32 + ((quad ^ sw4(m_l)) << 3);
        int n_l = 64 * wc + 16 * i + ln;
        boff[i] = n_l * 32 + ((quad ^ sw4(n_l)) << 3);
    }

    float4v acc[4][4];
    #pragma unroll
    for (int i = 0; i < 4; i++)
        #pragma unroll
        for (int j = 0; j < 4; j++) acc[i][j] = (float4v){0.f, 0.f, 0.f, 0.f};

    for (int k0 = 0; k0 < DMODEL; k0 += 32) {
        __syncthreads();
        #pragma unroll
        for (int i = 0; i < 2; i++) {
            gll16(gB[i] + k0, lB[i]);
            gll16(gB[i] + k0 + lo_goff, lB[i] + LO);
        }
        if constexpr (PRE) {
            #pragma unroll
            for (int i = 0; i < 2; i++) {
                gll16(gA[i] + k0, lA[i]);
                gll16(gA[i] + k0 + xlo_off, lA[i] + LO);
            }
        } else {
            float xs[16];
            *(float4v*)&xs[0]  = *(const float4v*)(aptr + k0);
            *(float4v*)&xs[4]  = *(const float4v*)(aptr + k0 + 4);
            *(float4v*)&xs[8]  = *(const float4v*)(aptr + k0 + 8);
            *(float4v*)&xs[12] = *(const float4v*)(aptr + k0 + 12);
            short8v h0, h1, l0, l1;
            #pragma unroll
            for (int e = 0; e < 8; e++) {
                ushort_t a = f2bf(xs[e]), b = f2bf(xs[8 + e]);
                h0[e] = (short)a; h1[e] = (short)b;
                l0[e] = (short)f2bf(xs[e] - bf2f(a));
                l1[e] = (short)f2bf(xs[8 + e] - bf2f(b));
            }
            *(short8v*)ast_hi0 = h0; *(short8v*)ast_hi1 = h1;
            *(short8v*)ast_lo0 = l0; *(short8v*)ast_lo1 = l1;
        }
        __syncthreads();

        short8v ah[4], al[4], bh[4], bl[4];
        #pragma unroll
        for (int i = 0; i < 4; i++) {
            ah[i] = *(short8v*)&AS2[aoff[i]];
            al[i] = *(short8v*)&AS2[LO + aoff[i]];
            bh[i] = *(short8v*)&BS[boff[i]];
            bl[i] = *(short8v*)&BS[LO + boff[i]];
        }
        if (part != 2) {
            #pragma unroll
            for (int mt = 0; mt < 4; mt++)
                #pragma unroll
                for (int nt = 0; nt < 4; nt++) {
                    acc[mt][nt] = __builtin_amdgcn_mfma_f32_16x16x32_bf16(ah[mt], bh[nt], acc[mt][nt], 0, 0, 0);
                    acc[mt][nt] = __builtin_amdgcn_mfma_f32_16x16x32_bf16(ah[mt], bl[nt], acc[mt][nt], 0, 0, 0);
                    acc[mt][nt] = __builtin_amdgcn_mfma_f32_16x16x32_bf16(al[mt], bh[nt], acc[mt][nt], 0, 0, 0);
                }
        } else {
            #pragma unroll
            for (int mt = 0; mt < 4; mt++)
                #pragma unroll
                for (int nt = 0; nt < 4; nt++)
                    acc[mt][nt] = __builtin_amdgcn_mfma_f32_16x16x32_bf16(ah[mt], bh[nt], acc[mt][nt], 0, 0, 0);
        }
    }

    float bvv[4];
    #pragma unroll
    for (int nt = 0; nt < 4; nt++) bvv[nt] = bias[64 * g + 16 * nt + ln];

    #pragma unroll
    for (int mt = 0; mt < 4; mt++) {
        #pragma unroll
        for (int r = 0; r < 4; r++) {
            int m = m0 + 64 * wr + 16 * mt + 4 * quad + r;
            int bb = m >> 11, s = m & (SEQ - 1);
            size_t hsrow = (size_t)(bb * NH + h) * SEQ + s;
            size_t rowbase = hsrow * HD;
            float vv[4];
            #pragma unroll
            for (int nt = 0; nt < 4; nt++) vv[nt] = acc[mt][nt][r] + bvv[nt];
            if (part == 0) {
                float sq = 0.f;
                #pragma unroll
                for (int nt = 0; nt < 4; nt++) {
                    float v = vv[nt];
                    sq += v * v;
                    float v2 = v * (2.0f * LOG2E);
                    ushort_t hb = f2bf(v2);
                    Qhi[rowbase + 16 * nt + ln] = hb;
                    Qlo[rowbase + 16 * nt + ln] = f2bf(v2 - bf2f(hb));
                }
                sq += __shfl_xor(sq, 1); sq += __shfl_xor(sq, 2);
                sq += __shfl_xor(sq, 4); sq += __shfl_xor(sq, 8);
                if (ln == 0) Qsq[hsrow] = sq * LOG2E - EXP_BIAS;
            } else if (part == 1) {
                float sq = 0.f;
                #pragma unroll
                for (int nt = 0; nt < 4; nt++) {
                    float v = vv[nt];
                    sq += v * v;
                    ushort_t hb = f2bf(v);
                    Khi[rowbase + 16 * nt + ln] = hb;
                    Klo[rowbase + 16 * nt + ln] = f2bf(v - bf2f(hb));
                }
                sq += __shfl_xor(sq, 1); sq += __shfl_xor(sq, 2);
                sq += __shfl_xor(sq, 4); sq += __shfl_xor(sq, 8);
                if (ln == 0) Ksq[hsrow] = sq * LOG2E;
            } else {
                #pragma unroll
                for (int nt = 0; nt < 4; nt++)
                    Vout[rowbase + 16 * nt + ln] = f2bf(vv[nt]);
            }
        }
    }
}

// ---------------------------------------------------------------------------
// MFMA flash attention, round 20: round-17 structure MINUS the post-softmax
// barrier. PsS is WAVE-LOCAL: wave w writes rows 16w..16w+15 (row =
// 16w+4quad+{0..3}) and PV reads rows 16w+ln, ln in [0,16) — same stripe,
// disjoint across waves. Within a wave the ds_write instruction precedes the
// ds_read in program order and the LDS pipe is in-order per wave, so the
// softmax->PV ordering needs no block barrier. All cross-iteration hazards
// (PsS WAR, KS/VtS WAR) remain covered by the loop-top __syncthreads (each
// wave's reads retire via lgkmcnt(0) before it enters the barrier).
// 3 -> 2 barriers/tile; softmax-VALU of one wave can overlap PV-MFMA of
// another within the block.
// ---------------------------------------------------------------------------
template<bool PRE>
__global__ __launch_bounds__(256, 4) void attn_mfma_kernel(
    const ushort_t* __restrict__ Qhi, const ushort_t* __restrict__ Qlo,
    const ushort_t* __restrict__ Khi, const ushort_t* __restrict__ Klo,
    const ushort_t* __restrict__ Vsrc,
    const float* __restrict__ Qsq, const float* __restrict__ Ksq,
    ushort_t* __restrict__ vals)
{
    __shared__ ushort_t KS[2 * 64 * 64];           // [hi 4096 | lo 4096]
    __shared__ ushort_t VtS [64 * 64];
    __shared__ ushort_t PsS [64 * 72];
    const int LO = 64 * 64;

    const int t    = threadIdx.x;
    const int w    = t >> 6, lane = t & 63;
    const int quad = (t >> 4) & 3, ln = t & 15;
    const int bh   = blockIdx.y;
    const int q0   = blockIdx.x * 64;
    const size_t base  = (size_t)bh * SEQ * HD;
    const size_t baseS = (size_t)bh * SEQ;

    short8v qhi[2], qlo[2];
    float nqsq4[4];
    {
        size_t ro = base + (size_t)(q0 + 16 * w + ln) * HD + quad * 8;
        qhi[0] = *(const short8v*)(Qhi + ro);
        qhi[1] = *(const short8v*)(Qhi + ro + 32);
        qlo[0] = *(const short8v*)(Qlo + ro);
        qlo[1] = *(const short8v*)(Qlo + ro + 32);
        float4v q4 = *(const float4v*)(Qsq + baseS + q0 + 16 * w + 4 * quad);
        #pragma unroll
        for (int r = 0; r < 4; r++) nqsq4[r] = -q4[r];
    }

    const ushort_t* gK[2]; ushort_t* lK[2];
    #pragma unroll
    for (int i = 0; i < 2; i++) {
        int c = 256 * i + 64 * w + lane;
        int key = c >> 3, dbp = c & 7;
        gK[i] = Khi + base + (size_t)key * HD + 8 * (dbp ^ (key & 7));
        lK[i] = &KS[(256 * i + 64 * w) * 8];
    }
    const size_t kloff = (size_t)(Klo - Khi);

    const ushort_t* gV[2]; ushort_t* lV[2];
    if constexpr (PRE) {
        #pragma unroll
        for (int i = 0; i < 2; i++) {
            int c = 256 * i + 64 * w + lane;
            int d = c >> 3, kc = c & 7;
            gV[i] = Vsrc + ((size_t)bh * 64 + d) * SEQ + 8 * (kc ^ (d & 7));
            lV[i] = &VtS[(256 * i + 64 * w) * 8];
        }
    }

    float4v accO[4];
    float lsum[4];
    #pragma unroll
    for (int nt = 0; nt < 4; nt++) accO[nt] = (float4v){0.f, 0.f, 0.f, 0.f};
    #pragma unroll
    for (int r = 0; r < 4; r++) lsum[r] = 0.f;

    for (int kt = 0; kt < SEQ; kt += 64) {
        __syncthreads();
        #pragma unroll
        for (int i = 0; i < 2; i++) {
            gll16(gK[i] + (size_t)kt * HD, lK[i]);
            gll16(gK[i] + (size_t)kt * HD + kloff, lK[i] + LO);
        }
        if constexpr (PRE) {
            #pragma unroll
            for (int i = 0; i < 2; i++)
                gll16(gV[i] + kt, lV[i]);
        } else {
            #pragma unroll
            for (int i = 0; i < 2; i++) {
                int c = t + 256 * i;
                int key = c >> 3, db = c & 7;
                short8v v8 = *(const short8v*)(Vsrc + base + (size_t)(kt + key) * HD + 8 * db);
                #pragma unroll
                for (int e = 0; e < 8; e++) {
                    int col = key ^ (e << 3);
                    VtS[(8 * db + e) * 64 + col] = (ushort_t)v8[e];
                }
            }
        }
        float nksq[4];
        #pragma unroll
        for (int nt = 0; nt < 4; nt++)
            nksq[nt] = -Ksq[baseS + kt + 16 * nt + ln];
        __syncthreads();

        // scores: init acc = -(ksq+qsq); MFMA accumulates 2*log2e*q.k on top
        float4v accS[4];
        #pragma unroll
        for (int nt = 0; nt < 4; nt++)
            #pragma unroll
            for (int r = 0; r < 4; r++) accS[nt][r] = nksq[nt] + nqsq4[r];

        #pragma unroll
        for (int nt = 0; nt < 4; nt++) {
            int keyrow = 16 * nt + ln;
            #pragma unroll
            for (int c = 0; c < 2; c++) {
                int db  = quad + 4 * c;
                int off = keyrow * 64 + ((db ^ (keyrow & 7)) << 3);
                short8v bh_ = *(short8v*)&KS[off];
                short8v bl_ = *(short8v*)&KS[LO + off];
                accS[nt] = __builtin_amdgcn_mfma_f32_16x16x32_bf16(qhi[c], bh_, accS[nt], 0, 0, 0);
                accS[nt] = __builtin_amdgcn_mfma_f32_16x16x32_bf16(qhi[c], bl_, accS[nt], 0, 0, 0);
                accS[nt] = __builtin_amdgcn_mfma_f32_16x16x32_bf16(qlo[c], bh_, accS[nt], 0, 0, 0);
            }
        }

        #pragma unroll
        for (int nt = 0; nt < 4; nt++) {
            float pv[4];
            #pragma unroll
            for (int r = 0; r < 4; r++) {
                float p = EXP2F(accS[nt][r]);
                lsum[r] += p;
                pv[r] = p;
            }
            unsigned int pk01, pk23;
            asm("v_cvt_pk_bf16_f32 %0, %1, %2" : "=v"(pk01) : "v"(pv[0]), "v"(pv[1]));
            asm("v_cvt_pk_bf16_f32 %0, %1, %2" : "=v"(pk23) : "v"(pv[2]), "v"(pv[3]));
            ushort_t* pp = &PsS[(16 * w + 4 * quad) * 72 + 16 * nt + ln];
            pp[0]       = (ushort_t)(pk01 & 0xffffu);
            pp[72]      = (ushort_t)(pk01 >> 16);
            pp[144]     = (ushort_t)(pk23 & 0xffffu);
            pp[216]     = (ushort_t)(pk23 >> 16);
        }
        // NO barrier: PsS rows are wave-private (see header comment).

        #pragma unroll
        for (int c = 0; c < 2; c++) {
            short8v aP = *(short8v*)&PsS[(16 * w + ln) * 72 + quad * 8 + 32 * c];
            #pragma unroll
            for (int nt = 0; nt < 4; nt++) {
                int drow = 16 * nt + ln;
                int db   = quad + 4 * c;
                int off  = drow * 64 + ((db ^ (drow & 7)) << 3);
                short8v bV = *(short8v*)&VtS[off];
                accO[nt] = __builtin_amdgcn_mfma_f32_16x16x32_bf16(aP, bV, accO[nt], 0, 0, 0);
            }
        }
    }

    const int bb = bh >> 4, h = bh & 15;
    float inv[4];
    #pragma unroll
    for (int r = 0; r < 4; r++) {
        float s = lsum[r];
        s += __shfl_xor(s, 1); s += __shfl_xor(s, 2);
        s += __shfl_xor(s, 4); s += __shfl_xor(s, 8);
        inv[r] = 1.f / s;
    }
    #pragma unroll
    for (int nt = 0; nt < 4; nt++)
        #pragma unroll
        for (int r = 0; r < 4; r++) {
            int row = q0 + 16 * w + 4 * quad + r;
            vals[(size_t)(bb * SEQ + row) * DMODEL + h * 64 + 16 * nt + ln] =
                f2bf(accO[nt][r] * inv[r]);
        }
}

// ---------------------------------------------------------------------------
// Out MFMA GEMM (round-16: double-buffered, prefetch-before-compute).
// ---------------------------------------------------------------------------
__global__ __launch_bounds__(256) void out_mfma_kernel(
    const ushort_t* __restrict__ Ab, const ushort_t* __restrict__ BT,
    const float* __restrict__ bias, float* __restrict__ out)
{
    __shared__ ushort_t AS[2 * 128 * 32], BSo[2 * 128 * 32];   // 16KB + 16KB
    const int BUF = 128 * 32;
    const int t = threadIdx.x;
    const int w = t >> 6;
    const int quad = (t >> 4) & 3, ln = t & 15;
    const int wr = (w >> 1), wc = w & 1;
    const int m0 = blockIdx.y * 128, n0 = blockIdx.x * 128;

    const ushort_t* gA[2]; const ushort_t* gB[2]; int lOff[2];
    #pragma unroll
    for (int i = 0; i < 2; i++) {
        int c = 256 * i + t;
        int r = c >> 2, kbp = c & 3;
        gA[i] = Ab + (size_t)(m0 + r) * 1024 + 8 * (kbp ^ sw4(r));
        gB[i] = BT + (size_t)(n0 + r) * 1024 + 8 * (kbp ^ sw4(r));
        lOff[i] = (256 * i + 64 * w) * 8;
    }
    int aoff[4], boff[4];
    #pragma unroll
    for (int i = 0; i < 4; i++) {
        int m_l = 64 * wr + 16 * i + ln;
        aoff[i] = m_l * 32 + ((quad ^ sw4(m_l)) << 3);
        int n_l = 64 * wc + 16 * i + ln;
        boff[i] = n_l * 32 + ((quad ^ sw4(n_l)) << 3);
    }

    float4v acc[4][4];
    #pragma unroll
    for (int i = 0; i < 4; i++)
        #pragma unroll
        for (int j = 0; j < 4; j++) acc[i][j] = (float4v){0.f, 0.f, 0.f, 0.f};

    auto stage = [&](int ks, int buf) {
        const int kk = 32 * ks;
        #pragma unroll
        for (int i = 0; i < 2; i++) {
            gll16(gA[i] + kk, &AS [buf * BUF] + lOff[i]);
            gll16(gB[i] + kk, &BSo[buf * BUF] + lOff[i]);
        }
    };

    const int NKS = DMODEL / 32;   // 32
    stage(0, 0);
    __syncthreads();               // buf0 staged (implicit vmcnt(0) drain)

    for (int ks = 0; ks < NKS; ks++) {
        const int buf = ks & 1;
        if (ks + 1 < NKS) stage(ks + 1, buf ^ 1);   // prefetch overlaps compute

        const ushort_t* Abuf = &AS [buf * BUF];
        const ushort_t* Bbuf = &BSo[buf * BUF];
        short8v a[4], b[4];
        #pragma unroll
        for (int i = 0; i < 4; i++) {
            a[i] = *(const short8v*)(Abuf + aoff[i]);
            b[i] = *(const short8v*)(Bbuf + boff[i]);
        }
        #pragma unroll
        for (int mt = 0; mt < 4; mt++)
            #pragma unroll
            for (int nt = 0; nt < 4; nt++)
                acc[mt][nt] = __builtin_amdgcn_mfma_f32_16x16x32_bf16(a[mt], b[nt], acc[mt][nt], 0, 0, 0);

        __syncthreads();           // drains prefetch vmcnt + this buf's reads
    }

    #pragma unroll
    for (int nt = 0; nt < 4; nt++) {
        int n = n0 + 64 * wc + 16 * nt + ln;
        float bv = bias[n];
        #pragma unroll
        for (int mt = 0; mt < 4; mt++)
            #pragma unroll
            for (int r = 0; r < 4; r++) {
                int m = m0 + 64 * wr + 16 * mt + 4 * quad + r;
                out[(size_t)m * DMODEL + n] = acc[mt][nt][r] + bv;
            }
    }
}

// ---------------------------------------------------------------------------
// Launch (round-8 layout; PRE if ws fits ~70.5 MiB, else round-7 fallback).
// ---------------------------------------------------------------------------
extern "C" void kernel_launch(void* const* d_in, const int* in_sizes, int n_in,
                              void* d_out, int out_size, void* d_ws, size_t ws_size,
                              hipStream_t stream) {
    const float* x     = (const float*)d_in[0];
    const float* W_qkv = (const float*)d_in[1];
    const float* b_qkv = (const float*)d_in[2];
    const float* W_o   = (const float*)d_in[3];
    const float* b_o   = (const float*)d_in[4];
    float* out = (float*)d_out;

    const size_t WQT = (size_t)N_QKV * DMODEL;
    const size_t WO  = (size_t)DMODEL * DMODEL;
    const size_t QE  = (size_t)NUM_B * NH * SEQ * HD;
    const size_t SQN = (size_t)NUM_B * NH * SEQ;

    const size_t NEED = (2 * WQT + WO + 5 * QE + 2 * QE) * 2 + 2 * SQN * 4;
    const bool pre = (ws_size >= NEED);

    ushort_t* ws     = (ushort_t*)d_ws;
    ushort_t* WqT_hi = ws;
    ushort_t* WqT_lo = WqT_hi + WQT;
    ushort_t* WoT    = WqT_lo + WQT;
    ushort_t* Qhi    = WoT + WO;
    ushort_t* Qlo    = Qhi + QE;
    ushort_t* Khi    = Qlo + QE;
    ushort_t* Klo    = Khi + QE;
    ushort_t* Vx     = Klo + QE;
    float*    Qsq; float* Ksq;
    ushort_t* valsb; ushort_t* Xhi = nullptr; ushort_t* Xlo = nullptr;

    if (pre) {
        Qsq   = (float*)(Vx + QE);
        Ksq   = Qsq + SQN;
        Xhi   = (ushort_t*)(Ksq + SQN);
        Xlo   = Xhi + QE;
        valsb = WqT_hi;
    } else {
        valsb = Vx + QE;
        Qsq   = (float*)(valsb + QE);
        Ksq   = Qsq + SQN;
    }

    prep_kernel<<<pre ? 2048 : 1024, 256, 0, stream>>>(
        W_qkv, W_o, x, WqT_hi, WqT_lo, WoT, Xhi, Xlo);
    if (pre) {
        qkv_uni_kernel<<<dim3(NH, M_TOT / 128), 512, 0, stream>>>(
            Xhi, Xlo, WqT_hi, WqT_lo, b_qkv, Qhi, Qlo, Khi, Klo, Vx, Qsq, Ksq);
        attn_mfma_kernel<true><<<dim3(SEQ / 64, NUM_B * NH), 256, 0, stream>>>(
            Qhi, Qlo, Khi, Klo, Vx, Qsq, Ksq, valsb);
    } else {
        qkv_mfma_kernel<false><<<dim3(N_QKV / 128, M_TOT / 128), 256, 0, stream>>>(
            x, nullptr, nullptr, WqT_hi, WqT_lo, b_qkv, Qhi, Qlo, Khi, Klo, Vx, Qsq, Ksq);
        attn_mfma_kernel<false><<<dim3(SEQ / 64, NUM_B * NH), 256, 0, stream>>>(
            Qhi, Qlo, Khi, Klo, Vx, Qsq, Ksq, valsb);
    }
    out_mfma_kernel<<<dim3(DMODEL / 128, M_TOT / 128), 256, 0, stream>>>(
        valsb, WoT, b_o, out);
}